// Round 16
// baseline (397.488 us; speedup 1.0000x reference)
//
#include <hip/hip_runtime.h>
#include <math.h>

// B=32, L=512 (incl CLS), D=256, H=8, dh=32, N_LAYERS=3, D_FF=1024, tokens=16384
// Length-aware: rows past lengths[b] are provably dead (CLS-only output,
// exactly-zero attention weights for padded columns) -> tiles skipped.

typedef __attribute__((ext_vector_type(4))) float f32x4;
typedef __attribute__((ext_vector_type(8))) short bf16x8;

__device__ __forceinline__ unsigned short f2bf(float f) {
    unsigned u = __builtin_bit_cast(unsigned, f);
    u += 0x7fff + ((u >> 16) & 1);
    return (unsigned short)(u >> 16);
}
__device__ __forceinline__ unsigned cvt_pk_bf16(float a, float b) {
    unsigned r;
    asm("v_cvt_pk_bf16_f32 %0, %1, %2" : "=v"(r) : "v"(a), "v"(b));
    return r;
}
__device__ __forceinline__ float gelu_f(float v) {
    return v * 0.5f * (1.0f + erff(v * 0.70710678118654752f));
}
__device__ __forceinline__ void gload16(const void* g, void* l) {
    __builtin_amdgcn_global_load_lds(
        (const __attribute__((address_space(1))) unsigned int*)g,
        (__attribute__((address_space(3))) unsigned int*)l, 16, 0, 0);
}

// ---------------------------------------------------------------------------
// Mega setup kernel: all weight cvts + pe transposes + sinusoid + xb.
__global__ __launch_bounds__(256) void setup_kernel(
    const float* __restrict__ wq, unsigned short* __restrict__ wq_o,   // 576
    const float* __restrict__ wo, unsigned short* __restrict__ wo_o,   // 192
    const float* __restrict__ w1, unsigned short* __restrict__ w1_o,   // 768
    const float* __restrict__ w2, unsigned short* __restrict__ w2_o,   // 768
    const float* __restrict__ win, unsigned short* __restrict__ win_o, // 16
    const float* __restrict__ peW, unsigned short* __restrict__ w256,  // 64
    float* __restrict__ W20t,                                          // 20
    const float* __restrict__ x, unsigned short* __restrict__ xb,      // 2048
    unsigned short* __restrict__ S)                                    // 256
{
    int blk = blockIdx.x, t = threadIdx.x;
    if (blk < 2304) {  // plain f32->bf16 cvts
        const float* s; unsigned short* d; int base;
        if (blk < 576)       { s = wq; d = wq_o; base = blk; }
        else if (blk < 768)  { s = wo; d = wo_o; base = blk - 576; }
        else if (blk < 1536) { s = w1; d = w1_o; base = blk - 768; }
        else                 { s = w2; d = w2_o; base = blk - 1536; }
        int i = (base * 256 + t) * 4;
        float4 v = *(const float4*)(s + i);
        unsigned long long pk = (unsigned long long)f2bf(v.x)
            | ((unsigned long long)f2bf(v.y) << 16)
            | ((unsigned long long)f2bf(v.z) << 32)
            | ((unsigned long long)f2bf(v.w) << 48);
        *(unsigned long long*)(d + i) = pk;
    } else if (blk < 2320) {  // win
        int i = ((blk - 2304) * 256 + t) * 4;
        float4 v = *(const float4*)(win + i);
        unsigned long long pk = (unsigned long long)f2bf(v.x)
            | ((unsigned long long)f2bf(v.y) << 16)
            | ((unsigned long long)f2bf(v.z) << 32)
            | ((unsigned long long)f2bf(v.w) << 48);
        *(unsigned long long*)(win_o + i) = pk;
    } else if (blk < 2384) {  // peW first-256 feats -> bf16 [256][256]
        int i = ((blk - 2320) * 256 + t) * 4;
        int d = i >> 8, f = i & 255;
        float4 v = *(const float4*)(peW + d * 276 + f);
        unsigned long long pk = (unsigned long long)f2bf(v.x)
            | ((unsigned long long)f2bf(v.y) << 16)
            | ((unsigned long long)f2bf(v.z) << 32)
            | ((unsigned long long)f2bf(v.w) << 48);
        *(unsigned long long*)(w256 + i) = pk;
    } else if (blk < 2404) {  // W20t[f][d] = peW[d][256+f]
        int j = (blk - 2384) * 256 + t;
        int f = j >> 8, dd = j & 255;
        W20t[j] = peW[dd * 276 + 256 + f];
    } else if (blk < 4452) {  // xb
        int idx = (blk - 2404) * 256 + t;
        int tok = idx >> 5, c2 = idx & 31;
        int b = tok >> 9, l = tok & 511;
        unsigned r = 0;
        if (l > 0) {
            float2 v = *(const float2*)(x + ((size_t)b * 511 + l - 1) * 64 + 2 * c2);
            r = cvt_pk_bf16(v.x, v.y);
        }
        *(unsigned*)(xb + (size_t)tok * 64 + 2 * c2) = r;
    } else {  // sinusoid table
        int p = (blk - 4452) * 256 + t;
        int l = p >> 7, k = p & 127;
        float div = expf((float)(2 * k) * -0.035977892078032f);
        float a = (float)l * div;
        *(unsigned*)(S + l * 256 + 2 * k) = cvt_pk_bf16(sinf(a), cosf(a));
    }
}

// ---------------------------------------------------------------------------
// prep_lite: arrays for ALL tokens; h/u only for live 8-row groups.
__global__ __launch_bounds__(256) void prep_lite_kernel(
    const float* __restrict__ c_local, const float* __restrict__ c_sink,
    const float* __restrict__ bb, const float* __restrict__ cls_tok,
    const float* __restrict__ PEpos, const float* __restrict__ W20t,
    const float* __restrict__ pe_g, const float* __restrict__ pe_bb,
    const float* __restrict__ pe_gain_p, const float* __restrict__ corr_floor_p,
    const int* __restrict__ lengths, const float* __restrict__ ln1g,
    const float* __restrict__ ln1b,
    float* __restrict__ h, float* __restrict__ clb, float* __restrict__ csfb,
    float* __restrict__ padfb, unsigned short* __restrict__ u)
{
    __shared__ float zs[8][20];
    __shared__ __align__(16) float pes[8][256];
    __shared__ float mn[8], rsd[8];
    const int t = threadIdx.x;
    const int tok0 = blockIdx.x * 8;
    const int b = tok0 >> 9;
    const int len_b = lengths[b];
    const float cf = *corr_floor_p;
    const float gain = *pe_gain_p;

    float clv[8], csv[8];
    bool mk[8];
#pragma unroll
    for (int k = 0; k < 8; ++k) {
        int l = (tok0 + k) & 511;
        if (l == 0) { clv[k] = 1.f; csv[k] = 1.f; mk[k] = false; }
        else {
            float a = c_local[b * 511 + l - 1];
            float s = c_sink[b * 511 + l - 1];
            clv[k] = fminf(fmaxf(a, 0.f), 1.f);
            csv[k] = fminf(fmaxf(s, 0.f), 1.f);
            mk[k] = (l - 1) >= len_b;
        }
    }
    if (t < 8) {
        int tok = tok0 + t;
        clb[tok] = clv[t];
        csfb[tok] = cf + (1.f - cf) * csv[t];
        padfb[tok] = mk[t] ? 1.f : 0.f;
    }
    // dead group: mask arrays written above are all that's needed
    if ((tok0 & 511) > len_b) return;
    if (t < 20) {
#pragma unroll
        for (int k = 0; k < 8; ++k) {
            float cl = clv[k], cs = csv[k];
            float v;
            if (t == 0) v = cl;
            else if (t == 1) v = cs;
            else if (t == 2) v = cl * cs;
            else if (t == 3) v = fabsf(cl - cs);
            else if (t < 12) {
                float c = (float)(t - 4) * (1.f / 7.f);
                float dd = (cl - c) / 0.200001f;
                v = expf(-0.5f * dd * dd);
            } else {
                float c = (float)(t - 12) * (1.f / 7.f);
                float dd = (cs - c) / 0.200001f;
                v = expf(-0.5f * dd * dd);
            }
            zs[k][t] = v;
        }
    }
    __syncthreads();

    float acc[8];
#pragma unroll
    for (int k = 0; k < 8; ++k)
        acc[k] = PEpos[((tok0 + k) & 511) * 256 + t];
    for (int f = 0; f < 20; ++f) {
        float wv = W20t[f * 256 + t];
#pragma unroll
        for (int k = 0; k < 8; ++k) acc[k] += zs[k][f] * wv;
    }
#pragma unroll
    for (int k = 0; k < 8; ++k) pes[k][t] = acc[k];
    __syncthreads();

    {
        int w = t >> 6, lane = t & 63;
#pragma unroll
        for (int p = 0; p < 2; ++p) {
            int k = w + p * 4;
            float4 v = *(const float4*)&pes[k][lane * 4];
            float s = v.x + v.y + v.z + v.w;
            float sq = v.x * v.x + v.y * v.y + v.z * v.z + v.w * v.w;
#pragma unroll
            for (int off = 32; off; off >>= 1) {
                s += __shfl_xor(s, off);
                sq += __shfl_xor(sq, off);
            }
            if (lane == 0) {
                float mean = s * (1.f / 256.f);
                mn[k] = mean;
                rsd[k] = rsqrtf(sq * (1.f / 256.f) - mean * mean + 1e-5f);
            }
        }
    }
    __syncthreads();
    float gv = pe_g[t], bv = pe_bb[t];
    float hv[8];
#pragma unroll
    for (int k = 0; k < 8; ++k) {
        int l = (tok0 + k) & 511;
        float base = (l == 0) ? cls_tok[t] : bb[(size_t)(tok0 + k) * 256 + t];
        float pe = (pes[k][t] - mn[k]) * rsd[k] * gv + bv;
        pe *= gain;
        if (mk[k]) pe = 0.f;
        hv[k] = base + pe;
        h[(size_t)(tok0 + k) * 256 + t] = hv[k];
    }
    __syncthreads();
#pragma unroll
    for (int k = 0; k < 8; ++k) pes[k][t] = hv[k];
    __syncthreads();
    {
        int w = t >> 6, lane = t & 63;
#pragma unroll
        for (int p = 0; p < 2; ++p) {
            int k = w + p * 4;
            float4 v = *(const float4*)&pes[k][lane * 4];
            float s = v.x + v.y + v.z + v.w;
            float sq = v.x * v.x + v.y * v.y + v.z * v.z + v.w * v.w;
#pragma unroll
            for (int off = 32; off; off >>= 1) {
                s += __shfl_xor(s, off);
                sq += __shfl_xor(sq, off);
            }
            if (lane == 0) {
                float mean = s * (1.f / 256.f);
                mn[k] = mean;
                rsd[k] = rsqrtf(sq * (1.f / 256.f) - mean * mean + 1e-5f);
            }
        }
    }
    __syncthreads();
    float g1 = ln1g[t], b1 = ln1b[t];
#pragma unroll
    for (int k = 0; k < 8; ++k)
        u[(size_t)(tok0 + k) * 256 + t] = f2bf((hv[k] - mn[k]) * rsd[k] * g1 + b1);
}

// ---------------------------------------------------------------------------
// bf16 MFMA GEMM, 128x64 tile (proven): C[M,N] = A @ W^T + bias (f32 store).
// Optional length-skip (lengths != nullptr, 128-aligned M tiles).
__global__ __launch_bounds__(256) void gemm_bf16_kernel(
    const unsigned short* __restrict__ A, const unsigned short* __restrict__ W,
    const float* __restrict__ bias, float* __restrict__ hres,
    const int* __restrict__ lengths, int M, int N, int K)
{
    __shared__ __align__(16) unsigned short As[128 * 64];
    __shared__ __align__(16) unsigned short Bs[64 * 64];
    const int m0 = blockIdx.y * 128, n0 = blockIdx.x * 64;
    if (lengths && (m0 & 511) > lengths[m0 >> 9]) return;
    const int t = threadIdx.x;
    const int wid = t >> 6, lane = t & 63;
    const int lo = lane & 15, hi = lane >> 4;
    const int wm = wid >> 1, wn = wid & 1;
    const int lrow = lane >> 3, lc = lane & 7;
    f32x4 acc[4][2] = {};
    for (int k0 = 0; k0 < K; k0 += 64) {
        __syncthreads();
#pragma unroll
        for (int is = 0; is < 4; ++is) {
            int r = wid * 32 + is * 8 + lrow;
            const unsigned short* g = A + (size_t)(m0 + r) * K + k0 + ((lc ^ (r & 7)) * 8);
            gload16(g, &As[(wid * 32 + is * 8) * 64]);
        }
#pragma unroll
        for (int is = 0; is < 2; ++is) {
            int r = wid * 16 + is * 8 + lrow;
            const unsigned short* g = W + (size_t)(n0 + r) * K + k0 + ((lc ^ (r & 7)) * 8);
            gload16(g, &Bs[(wid * 16 + is * 8) * 64]);
        }
        __syncthreads();
#pragma unroll
        for (int kh = 0; kh < 2; ++kh) {
            bf16x8 bfr[2];
#pragma unroll
            for (int nf = 0; nf < 2; ++nf) {
                int r = wn * 32 + nf * 16 + lo;
                bfr[nf] = *(const bf16x8*)&Bs[r * 64 + (((kh * 4 + hi) ^ (r & 7)) * 8)];
            }
#pragma unroll
            for (int mf = 0; mf < 4; ++mf) {
                int r = wm * 64 + mf * 16 + lo;
                bf16x8 afr = *(const bf16x8*)&As[r * 64 + (((kh * 4 + hi) ^ (r & 7)) * 8)];
                acc[mf][0] = __builtin_amdgcn_mfma_f32_16x16x32_bf16(afr, bfr[0], acc[mf][0], 0, 0, 0);
                acc[mf][1] = __builtin_amdgcn_mfma_f32_16x16x32_bf16(afr, bfr[1], acc[mf][1], 0, 0, 0);
            }
        }
    }
#pragma unroll
    for (int mf = 0; mf < 4; ++mf) {
        const int mbase = m0 + wm * 64 + mf * 16 + hi * 4;
#pragma unroll
        for (int nf = 0; nf < 2; ++nf) {
            const int n = n0 + wn * 32 + nf * 16 + lo;
            const float bv = bias[n];
            f32x4 v = acc[mf][nf];
#pragma unroll
            for (int rg = 0; rg < 4; ++rg)
                hres[(size_t)(mbase + rg) * N + n] = v[rg] + bv;
        }
    }
}

// ---------------------------------------------------------------------------
// bf16 MFMA GEMM, 64x128 tile (4 waves 2x2, each 32x64): QKV (EPI=0),
// FF1 GELU (EPI=2). 64-aligned length-skip; LDS 24 KB -> better residency.
template <int EPI>
__global__ __launch_bounds__(256) void gemm64_kernel(
    const unsigned short* __restrict__ A, const unsigned short* __restrict__ W,
    const float* __restrict__ bias, const int* __restrict__ lengths,
    unsigned short* __restrict__ o0, unsigned short* __restrict__ o1,
    unsigned short* __restrict__ o2, int M, int N, int K)
{
    __shared__ __align__(16) unsigned short As[64 * 64];
    __shared__ __align__(16) unsigned short Bs[128 * 64];
    const int m0 = blockIdx.y * 64, n0 = blockIdx.x * 128;
    if ((m0 & 511) > lengths[m0 >> 9]) return;   // dead tile
    const int t = threadIdx.x;
    const int wid = t >> 6, lane = t & 63;
    const int lo = lane & 15, hi = lane >> 4;
    const int wm = wid >> 1, wn = wid & 1;
    const int lrow = lane >> 3, lc = lane & 7;
    f32x4 acc[2][4] = {};
    for (int k0 = 0; k0 < K; k0 += 64) {
        __syncthreads();
#pragma unroll
        for (int is = 0; is < 2; ++is) {
            int r = wid * 16 + is * 8 + lrow;
            const unsigned short* g = A + (size_t)(m0 + r) * K + k0 + ((lc ^ (r & 7)) * 8);
            gload16(g, &As[(wid * 16 + is * 8) * 64]);
        }
#pragma unroll
        for (int is = 0; is < 4; ++is) {
            int r = wid * 32 + is * 8 + lrow;
            const unsigned short* g = W + (size_t)(n0 + r) * K + k0 + ((lc ^ (r & 7)) * 8);
            gload16(g, &Bs[(wid * 32 + is * 8) * 64]);
        }
        __syncthreads();
#pragma unroll
        for (int kh = 0; kh < 2; ++kh) {
            bf16x8 bfr[4];
#pragma unroll
            for (int nf = 0; nf < 4; ++nf) {
                int r = wn * 64 + nf * 16 + lo;
                bfr[nf] = *(const bf16x8*)&Bs[r * 64 + (((kh * 4 + hi) ^ (r & 7)) * 8)];
            }
#pragma unroll
            for (int mf = 0; mf < 2; ++mf) {
                int r = wm * 32 + mf * 16 + lo;
                bf16x8 afr = *(const bf16x8*)&As[r * 64 + (((kh * 4 + hi) ^ (r & 7)) * 8)];
#pragma unroll
                for (int nf = 0; nf < 4; ++nf)
                    acc[mf][nf] = __builtin_amdgcn_mfma_f32_16x16x32_bf16(afr, bfr[nf], acc[mf][nf], 0, 0, 0);
            }
        }
    }
#pragma unroll
    for (int mf = 0; mf < 2; ++mf) {
        const int mbase = m0 + wm * 32 + mf * 16 + hi * 4;
#pragma unroll
        for (int nf = 0; nf < 4; ++nf) {
            const int n = n0 + wn * 64 + nf * 16 + lo;
            const float bv = bias[n];
            f32x4 v = acc[mf][nf];
            if constexpr (EPI == 0) {
                unsigned short* dst = (n < 256) ? o0 : ((n < 512) ? o1 : o2);
                const float qsc = (n < 256)
                    ? (0.17677669529663687f * 1.4426950408889634f) : 1.f;
                const int c = n & 255;
#pragma unroll
                for (int rg = 0; rg < 4; ++rg)
                    dst[(size_t)(mbase + rg) * 256 + c] = f2bf((v[rg] + bv) * qsc);
            } else {
#pragma unroll
                for (int rg = 0; rg < 4; ++rg)
                    o0[(size_t)(mbase + rg) * N + n] = f2bf(gelu_f(v[rg] + bv));
            }
        }
    }
}

// ---------------------------------------------------------------------------
// Fused residual-GEMM + LayerNorm (proven 32x256 tile), length-aware.
// OUT=0: h += GEMM; u = LN(h).  OUT=1: final FF2 -> out-LN CLS rows only.
template <int OUT>
__global__ __launch_bounds__(512) void gemm_res_ln_kernel(
    const unsigned short* __restrict__ A, const unsigned short* __restrict__ W,
    const float* __restrict__ bias, float* __restrict__ hres,
    const float* __restrict__ g, const float* __restrict__ bvec,
    const int* __restrict__ lengths,
    unsigned short* __restrict__ u, float* __restrict__ outp, int K)
{
    __shared__ __align__(16) unsigned short As[32 * 64];
    __shared__ __align__(16) unsigned short Bs[256 * 64];
    __shared__ float red[32][4][2];
    const int m0 = blockIdx.x * 32;
    if ((m0 & 511) > lengths[m0 >> 9]) return;   // dead tile
    const int t = threadIdx.x;
    const int wid = t >> 6, lane = t & 63;
    const int lo = lane & 15, hi = lane >> 4;
    const int wm = wid >> 2, wn = wid & 3;
    const int lrow = lane >> 3, lc = lane & 7;
    f32x4 acc[4] = {};
    for (int k0 = 0; k0 < K; k0 += 64) {
        __syncthreads();
        if (wid < 4) {
            int r = wid * 8 + lrow;
            gload16(A + (size_t)(m0 + r) * K + k0 + ((lc ^ (r & 7)) * 8),
                    &As[(wid * 8) * 64]);
        }
#pragma unroll
        for (int is = 0; is < 4; ++is) {
            int r = wid * 32 + is * 8 + lrow;
            gload16(W + (size_t)r * K + k0 + ((lc ^ (r & 7)) * 8),
                    &Bs[(wid * 32 + is * 8) * 64]);
        }
        __syncthreads();
#pragma unroll
        for (int kh = 0; kh < 2; ++kh) {
            bf16x8 bfr[4];
#pragma unroll
            for (int nf = 0; nf < 4; ++nf) {
                int r = wn * 64 + nf * 16 + lo;
                bfr[nf] = *(const bf16x8*)&Bs[r * 64 + (((kh * 4 + hi) ^ (r & 7)) * 8)];
            }
            {
                int r = wm * 16 + lo;
                bf16x8 afr = *(const bf16x8*)&As[r * 64 + (((kh * 4 + hi) ^ (r & 7)) * 8)];
#pragma unroll
                for (int nf = 0; nf < 4; ++nf)
                    acc[nf] = __builtin_amdgcn_mfma_f32_16x16x32_bf16(afr, bfr[nf], acc[nf], 0, 0, 0);
            }
        }
    }
#pragma unroll
    for (int nf = 0; nf < 4; ++nf) {
        const int n = wn * 64 + nf * 16 + lo;
        const float bv = bias[n];
        const int rbase = m0 + wm * 16 + hi * 4;
#pragma unroll
        for (int rg = 0; rg < 4; ++rg) {
            size_t idx = (size_t)(rbase + rg) * 256 + n;
            float hv = acc[nf][rg] + bv + hres[idx];
            if constexpr (OUT == 0) hres[idx] = hv;
            acc[nf][rg] = hv;
        }
    }
#pragma unroll
    for (int rg = 0; rg < 4; ++rg) {
        float s = ((acc[0][rg] + acc[1][rg]) + (acc[2][rg] + acc[3][rg]));
        float sq = ((acc[0][rg] * acc[0][rg] + acc[1][rg] * acc[1][rg]) +
                    (acc[2][rg] * acc[2][rg] + acc[3][rg] * acc[3][rg]));
#pragma unroll
        for (int off = 1; off < 16; off <<= 1) {
            s += __shfl_xor(s, off);
            sq += __shfl_xor(sq, off);
        }
        if (lo == 0) {
            int rl = wm * 16 + hi * 4 + rg;
            red[rl][wn][0] = s;
            red[rl][wn][1] = sq;
        }
    }
    __syncthreads();
#pragma unroll
    for (int rg = 0; rg < 4; ++rg) {
        const int rl = wm * 16 + hi * 4 + rg;
        float s = (red[rl][0][0] + red[rl][1][0]) + (red[rl][2][0] + red[rl][3][0]);
        float sq = (red[rl][0][1] + red[rl][1][1]) + (red[rl][2][1] + red[rl][3][1]);
        float mean = s * (1.f / 256.f);
        float rs = rsqrtf(sq * (1.f / 256.f) - mean * mean + 1e-5f);
        if constexpr (OUT == 1) {
            const int row = m0 + rl;
            if ((row & 511) == 0) {
#pragma unroll
                for (int nf = 0; nf < 4; ++nf) {
                    const int n = wn * 64 + nf * 16 + lo;
                    outp[(size_t)(row >> 9) * 256 + n] =
                        (acc[nf][rg] - mean) * rs * g[n] + bvec[n];
                }
            }
        } else {
#pragma unroll
            for (int nf = 0; nf < 4; ++nf) {
                const int n = wn * 64 + nf * 16 + lo;
                u[(size_t)(m0 + rl) * 256 + n] =
                    f2bf((acc[nf][rg] - mean) * rs * g[n] + bvec[n]);
            }
        }
    }
}

// ---------------------------------------------------------------------------
// MFMA flash attention v10: kv range split across the 4 waves. Block =
// (b, head, 16 q-rows), grid 8192. Per jt tile each wave computes ONE ktp
// quarter (k16 = wid*32); no-max softmax partials (acc, lsum) are ADDITIVE,
// combined via one LDS reduction at the end (reuses Kl space). Math body
// identical to proven v9.
__global__ __launch_bounds__(256) void attn_mfma_kernel(
    const unsigned short* __restrict__ Qb, const unsigned short* __restrict__ Kb,
    const unsigned short* __restrict__ Vb, const float* __restrict__ clb,
    const float* __restrict__ csfb, const float* __restrict__ padfb,
    const float* __restrict__ alpha_p, const float* __restrict__ beta_p,
    const int* __restrict__ lengths, unsigned short* __restrict__ Ob)
{
    __shared__ __align__(16) unsigned short Kl[128 * 40];   // 10240 B (also reduce buf)
    __shared__ __align__(16) unsigned short Vt[32 * 132];   // 8448 B
    __shared__ __align__(16) float csfj[128];               // 512 B
    const int t = threadIdx.x;
    const int swz = ((blockIdx.x & 7) << 10) | (blockIdx.x >> 3);  // XCD chunking
    const int bh = swz >> 5, hf = swz & 31;
    const int b = bh >> 3, hd = bh & 7;
    const int len_b = lengths[b];
    if (hf * 16 > len_b) return;                 // dead q-tile
    const int njt = (len_b + 128) >> 7;          // ceil((len_b+1)/128)
    const size_t base = ((size_t)b * 512) * 256 + hd * 32;
    const int w = t >> 6, lane = t & 63, lo = lane & 15, hi = lane >> 4;
    const float L2E = 1.4426950408889634f;
    const float kb = L2E * (*beta_p);
    const float ka = L2E * (*alpha_p);
    const float* clg = clb + b * 512;

    const int i0 = hf * 16;
    const int iq = i0 + lo;
    const bf16x8 qf = *(const bf16x8*)(Qb + base + (size_t)iq * 256 + hi * 8);
    const float csb = fmaxf(kb * csfb[b * 512 + iq], 1e-3f);
    f32x4 acc0 = {0.f, 0.f, 0.f, 0.f}, acc1 = {0.f, 0.f, 0.f, 0.f};
    float lsum = 0.f;

    for (int jt = 0; jt < njt; ++jt) {
        __syncthreads();
        for (int idx = t; idx < 512; idx += 256) {       // K tile: 128 rows
            int row = idx >> 2, c4 = idx & 3;
            *(uint4*)&Kl[row * 40 + c4 * 8] =
                *(const uint4*)(Kb + base + (size_t)(jt * 128 + row) * 256 + c4 * 8);
        }
        for (int idx = t; idx < 512; idx += 256) {       // V^T via v_perm
            int pr = idx & 63, c4 = idx >> 6;
            const unsigned* vp0 = (const unsigned*)
                (Vb + base + (size_t)(jt * 128 + 2 * pr) * 256 + c4 * 4);
            const unsigned* vp1 = (const unsigned*)
                (Vb + base + (size_t)(jt * 128 + 2 * pr + 1) * 256 + c4 * 4);
            unsigned v0lo = vp0[0], v0hi = vp0[1];
            unsigned v1lo = vp1[0], v1hi = vp1[1];
            *(unsigned*)&Vt[(c4 * 4 + 0) * 132 + 2 * pr] =
                __builtin_amdgcn_perm(v1lo, v0lo, 0x05040100u);
            *(unsigned*)&Vt[(c4 * 4 + 1) * 132 + 2 * pr] =
                __builtin_amdgcn_perm(v1lo, v0lo, 0x07060302u);
            *(unsigned*)&Vt[(c4 * 4 + 2) * 132 + 2 * pr] =
                __builtin_amdgcn_perm(v1hi, v0hi, 0x05040100u);
            *(unsigned*)&Vt[(c4 * 4 + 3) * 132 + 2 * pr] =
                __builtin_amdgcn_perm(v1hi, v0hi, 0x07060302u);
        }
        if (t < 128) {                                   // csf with pad folded
            int j = jt * 128 + t;
            float cv = csfb[b * 512 + j];
            csfj[t] = (padfb[b * 512 + j] > 0.5f) ? -100000.f : cv;
        }
        __syncthreads();
        {
            const int k16 = w * 32;               // this wave's kv quarter
            const int gj = jt * 128 + k16;        // global j base
            bf16x8 kf0 = *(const bf16x8*)&Kl[(k16 + lo) * 40 + hi * 8];
            bf16x8 kf1 = *(const bf16x8*)&Kl[(k16 + 16 + lo) * 40 + hi * 8];
            union U16 { unsigned long long q[2]; unsigned wd[4]; bf16x8 v; } vu0, vu1, pu;
            vu0.q[0] = *(const unsigned long long*)&Vt[lo * 132 + k16 + hi * 4];
            vu0.q[1] = *(const unsigned long long*)&Vt[lo * 132 + k16 + 16 + hi * 4];
            vu1.q[0] = *(const unsigned long long*)&Vt[(16 + lo) * 132 + k16 + hi * 4];
            vu1.q[1] = *(const unsigned long long*)&Vt[(16 + lo) * 132 + k16 + 16 + hi * 4];
            f32x4 csf0 = *(const f32x4*)&csfj[k16 + hi * 4];
            f32x4 csf1 = *(const f32x4*)&csfj[k16 + 16 + hi * 4];
            f32x4 c0, c1;
#pragma unroll
            for (int e = 0; e < 4; ++e) {
                c0[e] = csb * csf0[e];
                c1[e] = csb * csf1[e];
            }
            f32x4 s0 = __builtin_amdgcn_mfma_f32_16x16x32_bf16(kf0, qf, c0, 0, 0, 0);
            f32x4 s1 = __builtin_amdgcn_mfma_f32_16x16x32_bf16(kf1, qf, c1, 0, 0, 0);
            float p[8];
#pragma unroll
            for (int r = 0; r < 4; ++r) p[r] = exp2f(s0[r]);
#pragma unroll
            for (int r = 0; r < 4; ++r) p[4 + r] = exp2f(s1[r]);
            if (gj <= i0 + 16 && gj + 32 >= i0) {
#pragma unroll
                for (int r = 0; r < 8; ++r) {
                    int jr = gj + ((r & 4) ? 16 : 0) + hi * 4 + (r & 3);
                    int dij = jr - iq;
                    if (dij == 1 || dij == -1) {
                        float ce = (jr >= 1 && iq <= 510) ? clg[jr] : clg[iq];
                        p[r] *= exp2f(ka * ce);
                    }
                }
            }
            lsum += ((p[0] + p[1]) + (p[2] + p[3])) + ((p[4] + p[5]) + (p[6] + p[7]));
            pu.wd[0] = cvt_pk_bf16(p[0], p[1]);
            pu.wd[1] = cvt_pk_bf16(p[2], p[3]);
            pu.wd[2] = cvt_pk_bf16(p[4], p[5]);
            pu.wd[3] = cvt_pk_bf16(p[6], p[7]);
            acc0 = __builtin_amdgcn_mfma_f32_16x16x32_bf16(vu0.v, pu.v, acc0, 0, 0, 0);
            acc1 = __builtin_amdgcn_mfma_f32_16x16x32_bf16(vu1.v, pu.v, acc1, 0, 0, 0);
        }
    }
    // cross-wave reduction of additive partials (reuse Kl as f32 buffer)
    __syncthreads();
    {
        float* red = (float*)Kl;
        const int slot = (w * 64 + lane) * 9;
#pragma unroll
        for (int c = 0; c < 4; ++c) { red[slot + c] = acc0[c]; red[slot + 4 + c] = acc1[c]; }
        red[slot + 8] = lsum;
    }
    __syncthreads();
    if (w == 0) {
        float* red = (float*)Kl;
#pragma unroll
        for (int wv = 1; wv < 4; ++wv) {
            const int s2 = (wv * 64 + lane) * 9;
#pragma unroll
            for (int c = 0; c < 4; ++c) { acc0[c] += red[s2 + c]; acc1[c] += red[s2 + 4 + c]; }
            lsum += red[s2 + 8];
        }
        float ls = lsum;
        ls += __shfl_xor(ls, 16);
        ls += __shfl_xor(ls, 32);
        const float inv = 1.f / fmaxf(ls, 1e-35f);
        unsigned long long oa =
              (unsigned long long)cvt_pk_bf16(acc0[0] * inv, acc0[1] * inv)
            | ((unsigned long long)cvt_pk_bf16(acc0[2] * inv, acc0[3] * inv) << 32);
        unsigned long long ob2 =
              (unsigned long long)cvt_pk_bf16(acc1[0] * inv, acc1[1] * inv)
            | ((unsigned long long)cvt_pk_bf16(acc1[2] * inv, acc1[3] * inv) << 32);
        *(unsigned long long*)(Ob + base + (size_t)iq * 256 + hi * 4) = oa;
        *(unsigned long long*)(Ob + base + (size_t)iq * 256 + 16 + hi * 4) = ob2;
    }
}

// ---------------------------------------------------------------------------
extern "C" void kernel_launch(void* const* d_in, const int* in_sizes, int n_in,
                              void* d_out, int out_size, void* d_ws, size_t ws_size,
                              hipStream_t stream) {
    const float* x         = (const float*)d_in[0];
    const float* c_local   = (const float*)d_in[1];
    const float* c_sink    = (const float*)d_in[2];
    const float* W_in      = (const float*)d_in[3];
    const float* b_in      = (const float*)d_in[4];
    const float* cls_token = (const float*)d_in[5];
    const float* pe_proj_W = (const float*)d_in[6];
    const float* pe_proj_b = (const float*)d_in[7];
    const float* pe_ln_g   = (const float*)d_in[8];
    const float* pe_ln_b   = (const float*)d_in[9];
    const float* pe_gain   = (const float*)d_in[10];
    const float* attn_Wqkv = (const float*)d_in[11];
    const float* attn_bqkv = (const float*)d_in[12];
    const float* attn_Wo   = (const float*)d_in[13];
    const float* attn_bo   = (const float*)d_in[14];
    const float* ff_W1     = (const float*)d_in[15];
    const float* ff_b1     = (const float*)d_in[16];
    const float* ff_W2     = (const float*)d_in[17];
    const float* ff_b2     = (const float*)d_in[18];
    const float* ln1_g     = (const float*)d_in[19];
    const float* ln1_b     = (const float*)d_in[20];
    const float* ln2_g     = (const float*)d_in[21];
    const float* ln2_b     = (const float*)d_in[22];
    const float* alpha     = (const float*)d_in[23];
    const float* beta      = (const float*)d_in[24];
    const float* corr_fl   = (const float*)d_in[25];
    const float* out_ln_g  = (const float*)d_in[26];
    const float* out_ln_b  = (const float*)d_in[27];
    const int*   lengths   = (const int*)d_in[28];
    float* out = (float*)d_out;

    // float region (same slots as round-15 passing layout)
    float* h     = (float*)d_ws;              // 4,194,304
    float* clb   = h + 4194304;               // 16384
    float* csfb  = clb + 16384;
    float* padfb = csfb + 16384;
    float* W20t  = padfb + 16384;             // 5120 (in old peWt slot)
    float* PEpos = W20t + 70656;              // 131072
    float* bbf   = PEpos + 131072;            // old 8,388,608-float region
    // bf16 region — weights AFTER the full 16,777,216-short f-span at Q_bf
    unsigned short* u_bf = (unsigned short*)(bbf + 8388608);
    unsigned short* xb_bf = u_bf;             // alias: xb dead before layer loop
    unsigned short* Q_bf = u_bf + 4194304;
    unsigned short* K_bf = Q_bf + 4194304;
    unsigned short* V_bf = K_bf + 4194304;
    unsigned short* f_bf = Q_bf;              // alias: spans Q..Q+16777216
    unsigned short* o_bf = u_bf;              // alias (lifetimes disjoint)
    unsigned short* wq_bf = Q_bf + 16777216;  // after f's span
    unsigned short* wo_bf = wq_bf + 589824;
    unsigned short* w1_bf = wo_bf + 196608;
    unsigned short* w2_bf = w1_bf + 786432;
    unsigned short* win_bf = w2_bf + 786432;  // 16384
    unsigned short* S_bf   = win_bf + 16384;  // 131072 (sinusoid table)
    unsigned short* w256_bf = S_bf + 131072;  // 65536

    setup_kernel<<<4708, 256, 0, stream>>>(
        attn_Wqkv, wq_bf, attn_Wo, wo_bf, ff_W1, w1_bf, ff_W2, w2_bf,
        W_in, win_bf, pe_proj_W, w256_bf, W20t, x, xb_bf, S_bf);
    gemm_bf16_kernel<<<dim3(4, 4), 256, 0, stream>>>(
        S_bf, w256_bf, pe_proj_b, PEpos, nullptr, 512, 256, 256);
    gemm_bf16_kernel<<<dim3(4, 128), 256, 0, stream>>>(
        xb_bf, win_bf, b_in, bbf, lengths, 16384, 256, 64);
    prep_lite_kernel<<<2048, 256, 0, stream>>>(
        c_local, c_sink, bbf, cls_token, PEpos, W20t,
        pe_ln_g, pe_ln_b, pe_gain, corr_fl, lengths, ln1_g, ln1_b,
        h, clb, csfb, padfb, u_bf);

    for (int l = 0; l < 3; ++l) {
        gemm64_kernel<0><<<dim3(6, 256), 256, 0, stream>>>(
            u_bf, wq_bf + (size_t)l * 196608, attn_bqkv + 768 * l, lengths,
            Q_bf, K_bf, V_bf, 16384, 768, 256);
        attn_mfma_kernel<<<8192, 256, 0, stream>>>(Q_bf, K_bf, V_bf, clb, csfb,
                                                   padfb, alpha, beta, lengths, o_bf);
        gemm_res_ln_kernel<0><<<512, 512, 0, stream>>>(
            o_bf, wo_bf + (size_t)l * 65536, attn_bo + 256 * l, h,
            ln2_g + 256 * l, ln2_b + 256 * l, lengths, u_bf, nullptr, 256);
        gemm64_kernel<2><<<dim3(8, 256), 256, 0, stream>>>(
            u_bf, w1_bf + (size_t)l * 262144, ff_b1 + 1024 * l, lengths,
            f_bf, nullptr, nullptr, 16384, 1024, 256);
        if (l < 2) {
            gemm_res_ln_kernel<0><<<512, 512, 0, stream>>>(
                f_bf, w2_bf + (size_t)l * 262144, ff_b2 + 256 * l, h,
                ln1_g + 256 * (l + 1), ln1_b + 256 * (l + 1), lengths, u_bf, nullptr, 1024);
        } else {
            gemm_res_ln_kernel<1><<<512, 512, 0, stream>>>(
                f_bf, w2_bf + (size_t)l * 262144, ff_b2 + 256 * l, h,
                out_ln_g, out_ln_b, lengths, nullptr, out, 1024);
        }
    }
}

// Round 17
// 339.729 us; speedup vs baseline: 1.1700x; 1.1700x over previous
//
#include <hip/hip_runtime.h>
#include <math.h>

// B=32, L=512 (incl CLS), D=256, H=8, dh=32, N_LAYERS=3, D_FF=1024, tokens=16384
// Length-aware: rows past lengths[b] are provably dead (CLS-only output,
// exactly-zero attention weights for padded columns) -> tiles skipped.

typedef __attribute__((ext_vector_type(4))) float f32x4;
typedef __attribute__((ext_vector_type(8))) short bf16x8;

__device__ __forceinline__ unsigned short f2bf(float f) {
    unsigned u = __builtin_bit_cast(unsigned, f);
    u += 0x7fff + ((u >> 16) & 1);
    return (unsigned short)(u >> 16);
}
__device__ __forceinline__ unsigned cvt_pk_bf16(float a, float b) {
    unsigned r;
    asm("v_cvt_pk_bf16_f32 %0, %1, %2" : "=v"(r) : "v"(a), "v"(b));
    return r;
}
__device__ __forceinline__ float gelu_f(float v) {
    return v * 0.5f * (1.0f + erff(v * 0.70710678118654752f));
}
__device__ __forceinline__ void gload16(const void* g, void* l) {
    __builtin_amdgcn_global_load_lds(
        (const __attribute__((address_space(1))) unsigned int*)g,
        (__attribute__((address_space(3))) unsigned int*)l, 16, 0, 0);
}

// ---------------------------------------------------------------------------
// Mega setup kernel: all weight cvts + pe transposes + sinusoid + xb.
__global__ __launch_bounds__(256) void setup_kernel(
    const float* __restrict__ wq, unsigned short* __restrict__ wq_o,   // 576
    const float* __restrict__ wo, unsigned short* __restrict__ wo_o,   // 192
    const float* __restrict__ w1, unsigned short* __restrict__ w1_o,   // 768
    const float* __restrict__ w2, unsigned short* __restrict__ w2_o,   // 768
    const float* __restrict__ win, unsigned short* __restrict__ win_o, // 16
    const float* __restrict__ peW, unsigned short* __restrict__ w256,  // 64
    float* __restrict__ W20t,                                          // 20
    const float* __restrict__ x, unsigned short* __restrict__ xb,      // 2048
    unsigned short* __restrict__ S)                                    // 256
{
    int blk = blockIdx.x, t = threadIdx.x;
    if (blk < 2304) {  // plain f32->bf16 cvts
        const float* s; unsigned short* d; int base;
        if (blk < 576)       { s = wq; d = wq_o; base = blk; }
        else if (blk < 768)  { s = wo; d = wo_o; base = blk - 576; }
        else if (blk < 1536) { s = w1; d = w1_o; base = blk - 768; }
        else                 { s = w2; d = w2_o; base = blk - 1536; }
        int i = (base * 256 + t) * 4;
        float4 v = *(const float4*)(s + i);
        unsigned long long pk = (unsigned long long)f2bf(v.x)
            | ((unsigned long long)f2bf(v.y) << 16)
            | ((unsigned long long)f2bf(v.z) << 32)
            | ((unsigned long long)f2bf(v.w) << 48);
        *(unsigned long long*)(d + i) = pk;
    } else if (blk < 2320) {  // win
        int i = ((blk - 2304) * 256 + t) * 4;
        float4 v = *(const float4*)(win + i);
        unsigned long long pk = (unsigned long long)f2bf(v.x)
            | ((unsigned long long)f2bf(v.y) << 16)
            | ((unsigned long long)f2bf(v.z) << 32)
            | ((unsigned long long)f2bf(v.w) << 48);
        *(unsigned long long*)(win_o + i) = pk;
    } else if (blk < 2384) {  // peW first-256 feats -> bf16 [256][256]
        int i = ((blk - 2320) * 256 + t) * 4;
        int d = i >> 8, f = i & 255;
        float4 v = *(const float4*)(peW + d * 276 + f);
        unsigned long long pk = (unsigned long long)f2bf(v.x)
            | ((unsigned long long)f2bf(v.y) << 16)
            | ((unsigned long long)f2bf(v.z) << 32)
            | ((unsigned long long)f2bf(v.w) << 48);
        *(unsigned long long*)(w256 + i) = pk;
    } else if (blk < 2404) {  // W20t[f][d] = peW[d][256+f]
        int j = (blk - 2384) * 256 + t;
        int f = j >> 8, dd = j & 255;
        W20t[j] = peW[dd * 276 + 256 + f];
    } else if (blk < 4452) {  // xb
        int idx = (blk - 2404) * 256 + t;
        int tok = idx >> 5, c2 = idx & 31;
        int b = tok >> 9, l = tok & 511;
        unsigned r = 0;
        if (l > 0) {
            float2 v = *(const float2*)(x + ((size_t)b * 511 + l - 1) * 64 + 2 * c2);
            r = cvt_pk_bf16(v.x, v.y);
        }
        *(unsigned*)(xb + (size_t)tok * 64 + 2 * c2) = r;
    } else {  // sinusoid table
        int p = (blk - 4452) * 256 + t;
        int l = p >> 7, k = p & 127;
        float div = expf((float)(2 * k) * -0.035977892078032f);
        float a = (float)l * div;
        *(unsigned*)(S + l * 256 + 2 * k) = cvt_pk_bf16(sinf(a), cosf(a));
    }
}

// ---------------------------------------------------------------------------
// prep_lite: arrays for ALL tokens; h/u only for live 8-row groups.
__global__ __launch_bounds__(256) void prep_lite_kernel(
    const float* __restrict__ c_local, const float* __restrict__ c_sink,
    const float* __restrict__ bb, const float* __restrict__ cls_tok,
    const float* __restrict__ PEpos, const float* __restrict__ W20t,
    const float* __restrict__ pe_g, const float* __restrict__ pe_bb,
    const float* __restrict__ pe_gain_p, const float* __restrict__ corr_floor_p,
    const int* __restrict__ lengths, const float* __restrict__ ln1g,
    const float* __restrict__ ln1b,
    float* __restrict__ h, float* __restrict__ clb, float* __restrict__ csfb,
    float* __restrict__ padfb, unsigned short* __restrict__ u)
{
    __shared__ float zs[8][20];
    __shared__ __align__(16) float pes[8][256];
    __shared__ float mn[8], rsd[8];
    const int t = threadIdx.x;
    const int tok0 = blockIdx.x * 8;
    const int b = tok0 >> 9;
    const int len_b = lengths[b];
    const float cf = *corr_floor_p;
    const float gain = *pe_gain_p;

    float clv[8], csv[8];
    bool mk[8];
#pragma unroll
    for (int k = 0; k < 8; ++k) {
        int l = (tok0 + k) & 511;
        if (l == 0) { clv[k] = 1.f; csv[k] = 1.f; mk[k] = false; }
        else {
            float a = c_local[b * 511 + l - 1];
            float s = c_sink[b * 511 + l - 1];
            clv[k] = fminf(fmaxf(a, 0.f), 1.f);
            csv[k] = fminf(fmaxf(s, 0.f), 1.f);
            mk[k] = (l - 1) >= len_b;
        }
    }
    if (t < 8) {
        int tok = tok0 + t;
        clb[tok] = clv[t];
        csfb[tok] = cf + (1.f - cf) * csv[t];
        padfb[tok] = mk[t] ? 1.f : 0.f;
    }
    // dead group: mask arrays written above are all that's needed
    if ((tok0 & 511) > len_b) return;
    if (t < 20) {
#pragma unroll
        for (int k = 0; k < 8; ++k) {
            float cl = clv[k], cs = csv[k];
            float v;
            if (t == 0) v = cl;
            else if (t == 1) v = cs;
            else if (t == 2) v = cl * cs;
            else if (t == 3) v = fabsf(cl - cs);
            else if (t < 12) {
                float c = (float)(t - 4) * (1.f / 7.f);
                float dd = (cl - c) / 0.200001f;
                v = expf(-0.5f * dd * dd);
            } else {
                float c = (float)(t - 12) * (1.f / 7.f);
                float dd = (cs - c) / 0.200001f;
                v = expf(-0.5f * dd * dd);
            }
            zs[k][t] = v;
        }
    }
    __syncthreads();

    float acc[8];
#pragma unroll
    for (int k = 0; k < 8; ++k)
        acc[k] = PEpos[((tok0 + k) & 511) * 256 + t];
    for (int f = 0; f < 20; ++f) {
        float wv = W20t[f * 256 + t];
#pragma unroll
        for (int k = 0; k < 8; ++k) acc[k] += zs[k][f] * wv;
    }
#pragma unroll
    for (int k = 0; k < 8; ++k) pes[k][t] = acc[k];
    __syncthreads();

    {
        int w = t >> 6, lane = t & 63;
#pragma unroll
        for (int p = 0; p < 2; ++p) {
            int k = w + p * 4;
            float4 v = *(const float4*)&pes[k][lane * 4];
            float s = v.x + v.y + v.z + v.w;
            float sq = v.x * v.x + v.y * v.y + v.z * v.z + v.w * v.w;
#pragma unroll
            for (int off = 32; off; off >>= 1) {
                s += __shfl_xor(s, off);
                sq += __shfl_xor(sq, off);
            }
            if (lane == 0) {
                float mean = s * (1.f / 256.f);
                mn[k] = mean;
                rsd[k] = rsqrtf(sq * (1.f / 256.f) - mean * mean + 1e-5f);
            }
        }
    }
    __syncthreads();
    float gv = pe_g[t], bv = pe_bb[t];
    float hv[8];
#pragma unroll
    for (int k = 0; k < 8; ++k) {
        int l = (tok0 + k) & 511;
        float base = (l == 0) ? cls_tok[t] : bb[(size_t)(tok0 + k) * 256 + t];
        float pe = (pes[k][t] - mn[k]) * rsd[k] * gv + bv;
        pe *= gain;
        if (mk[k]) pe = 0.f;
        hv[k] = base + pe;
        h[(size_t)(tok0 + k) * 256 + t] = hv[k];
    }
    __syncthreads();
#pragma unroll
    for (int k = 0; k < 8; ++k) pes[k][t] = hv[k];
    __syncthreads();
    {
        int w = t >> 6, lane = t & 63;
#pragma unroll
        for (int p = 0; p < 2; ++p) {
            int k = w + p * 4;
            float4 v = *(const float4*)&pes[k][lane * 4];
            float s = v.x + v.y + v.z + v.w;
            float sq = v.x * v.x + v.y * v.y + v.z * v.z + v.w * v.w;
#pragma unroll
            for (int off = 32; off; off >>= 1) {
                s += __shfl_xor(s, off);
                sq += __shfl_xor(sq, off);
            }
            if (lane == 0) {
                float mean = s * (1.f / 256.f);
                mn[k] = mean;
                rsd[k] = rsqrtf(sq * (1.f / 256.f) - mean * mean + 1e-5f);
            }
        }
    }
    __syncthreads();
    float g1 = ln1g[t], b1 = ln1b[t];
#pragma unroll
    for (int k = 0; k < 8; ++k)
        u[(size_t)(tok0 + k) * 256 + t] = f2bf((hv[k] - mn[k]) * rsd[k] * g1 + b1);
}

// ---------------------------------------------------------------------------
// bf16 MFMA GEMM, 128x64 tile (proven): C[M,N] = A @ W^T + bias (f32 store).
// Optional length-skip (lengths != nullptr, 128-aligned M tiles).
__global__ __launch_bounds__(256) void gemm_bf16_kernel(
    const unsigned short* __restrict__ A, const unsigned short* __restrict__ W,
    const float* __restrict__ bias, float* __restrict__ hres,
    const int* __restrict__ lengths, int M, int N, int K)
{
    __shared__ __align__(16) unsigned short As[128 * 64];
    __shared__ __align__(16) unsigned short Bs[64 * 64];
    const int m0 = blockIdx.y * 128, n0 = blockIdx.x * 64;
    if (lengths && (m0 & 511) > lengths[m0 >> 9]) return;
    const int t = threadIdx.x;
    const int wid = t >> 6, lane = t & 63;
    const int lo = lane & 15, hi = lane >> 4;
    const int wm = wid >> 1, wn = wid & 1;
    const int lrow = lane >> 3, lc = lane & 7;
    f32x4 acc[4][2] = {};
    for (int k0 = 0; k0 < K; k0 += 64) {
        __syncthreads();
#pragma unroll
        for (int is = 0; is < 4; ++is) {
            int r = wid * 32 + is * 8 + lrow;
            const unsigned short* g = A + (size_t)(m0 + r) * K + k0 + ((lc ^ (r & 7)) * 8);
            gload16(g, &As[(wid * 32 + is * 8) * 64]);
        }
#pragma unroll
        for (int is = 0; is < 2; ++is) {
            int r = wid * 16 + is * 8 + lrow;
            const unsigned short* g = W + (size_t)(n0 + r) * K + k0 + ((lc ^ (r & 7)) * 8);
            gload16(g, &Bs[(wid * 16 + is * 8) * 64]);
        }
        __syncthreads();
#pragma unroll
        for (int kh = 0; kh < 2; ++kh) {
            bf16x8 bfr[2];
#pragma unroll
            for (int nf = 0; nf < 2; ++nf) {
                int r = wn * 32 + nf * 16 + lo;
                bfr[nf] = *(const bf16x8*)&Bs[r * 64 + (((kh * 4 + hi) ^ (r & 7)) * 8)];
            }
#pragma unroll
            for (int mf = 0; mf < 4; ++mf) {
                int r = wm * 64 + mf * 16 + lo;
                bf16x8 afr = *(const bf16x8*)&As[r * 64 + (((kh * 4 + hi) ^ (r & 7)) * 8)];
                acc[mf][0] = __builtin_amdgcn_mfma_f32_16x16x32_bf16(afr, bfr[0], acc[mf][0], 0, 0, 0);
                acc[mf][1] = __builtin_amdgcn_mfma_f32_16x16x32_bf16(afr, bfr[1], acc[mf][1], 0, 0, 0);
            }
        }
    }
#pragma unroll
    for (int mf = 0; mf < 4; ++mf) {
        const int mbase = m0 + wm * 64 + mf * 16 + hi * 4;
#pragma unroll
        for (int nf = 0; nf < 2; ++nf) {
            const int n = n0 + wn * 32 + nf * 16 + lo;
            const float bv = bias[n];
            f32x4 v = acc[mf][nf];
#pragma unroll
            for (int rg = 0; rg < 4; ++rg)
                hres[(size_t)(mbase + rg) * N + n] = v[rg] + bv;
        }
    }
}

// ---------------------------------------------------------------------------
// bf16 MFMA GEMM, 64x128 tile (4 waves 2x2, each 32x64): QKV (EPI=0),
// FF1 GELU (EPI=2). 64-aligned length-skip; LDS 24 KB -> better residency.
template <int EPI>
__global__ __launch_bounds__(256) void gemm64_kernel(
    const unsigned short* __restrict__ A, const unsigned short* __restrict__ W,
    const float* __restrict__ bias, const int* __restrict__ lengths,
    unsigned short* __restrict__ o0, unsigned short* __restrict__ o1,
    unsigned short* __restrict__ o2, int M, int N, int K)
{
    __shared__ __align__(16) unsigned short As[64 * 64];
    __shared__ __align__(16) unsigned short Bs[128 * 64];
    const int m0 = blockIdx.y * 64, n0 = blockIdx.x * 128;
    if ((m0 & 511) > lengths[m0 >> 9]) return;   // dead tile
    const int t = threadIdx.x;
    const int wid = t >> 6, lane = t & 63;
    const int lo = lane & 15, hi = lane >> 4;
    const int wm = wid >> 1, wn = wid & 1;
    const int lrow = lane >> 3, lc = lane & 7;
    f32x4 acc[2][4] = {};
    for (int k0 = 0; k0 < K; k0 += 64) {
        __syncthreads();
#pragma unroll
        for (int is = 0; is < 2; ++is) {
            int r = wid * 16 + is * 8 + lrow;
            const unsigned short* g = A + (size_t)(m0 + r) * K + k0 + ((lc ^ (r & 7)) * 8);
            gload16(g, &As[(wid * 16 + is * 8) * 64]);
        }
#pragma unroll
        for (int is = 0; is < 4; ++is) {
            int r = wid * 32 + is * 8 + lrow;
            const unsigned short* g = W + (size_t)(n0 + r) * K + k0 + ((lc ^ (r & 7)) * 8);
            gload16(g, &Bs[(wid * 32 + is * 8) * 64]);
        }
        __syncthreads();
#pragma unroll
        for (int kh = 0; kh < 2; ++kh) {
            bf16x8 bfr[4];
#pragma unroll
            for (int nf = 0; nf < 4; ++nf) {
                int r = wn * 64 + nf * 16 + lo;
                bfr[nf] = *(const bf16x8*)&Bs[r * 64 + (((kh * 4 + hi) ^ (r & 7)) * 8)];
            }
#pragma unroll
            for (int mf = 0; mf < 2; ++mf) {
                int r = wm * 32 + mf * 16 + lo;
                bf16x8 afr = *(const bf16x8*)&As[r * 64 + (((kh * 4 + hi) ^ (r & 7)) * 8)];
#pragma unroll
                for (int nf = 0; nf < 4; ++nf)
                    acc[mf][nf] = __builtin_amdgcn_mfma_f32_16x16x32_bf16(afr, bfr[nf], acc[mf][nf], 0, 0, 0);
            }
        }
    }
#pragma unroll
    for (int mf = 0; mf < 2; ++mf) {
        const int mbase = m0 + wm * 32 + mf * 16 + hi * 4;
#pragma unroll
        for (int nf = 0; nf < 4; ++nf) {
            const int n = n0 + wn * 64 + nf * 16 + lo;
            const float bv = bias[n];
            f32x4 v = acc[mf][nf];
            if constexpr (EPI == 0) {
                unsigned short* dst = (n < 256) ? o0 : ((n < 512) ? o1 : o2);
                const float qsc = (n < 256)
                    ? (0.17677669529663687f * 1.4426950408889634f) : 1.f;
                const int c = n & 255;
#pragma unroll
                for (int rg = 0; rg < 4; ++rg)
                    dst[(size_t)(mbase + rg) * 256 + c] = f2bf((v[rg] + bv) * qsc);
            } else {
#pragma unroll
                for (int rg = 0; rg < 4; ++rg)
                    o0[(size_t)(mbase + rg) * N + n] = f2bf(gelu_f(v[rg] + bv));
            }
        }
    }
}

// ---------------------------------------------------------------------------
// Fused residual-GEMM + LayerNorm (proven 32x256 tile), length-aware.
// OUT=0: h += GEMM; u = LN(h).  OUT=1: final FF2 -> out-LN CLS rows only.
template <int OUT>
__global__ __launch_bounds__(512) void gemm_res_ln_kernel(
    const unsigned short* __restrict__ A, const unsigned short* __restrict__ W,
    const float* __restrict__ bias, float* __restrict__ hres,
    const float* __restrict__ g, const float* __restrict__ bvec,
    const int* __restrict__ lengths,
    unsigned short* __restrict__ u, float* __restrict__ outp, int K)
{
    __shared__ __align__(16) unsigned short As[32 * 64];
    __shared__ __align__(16) unsigned short Bs[256 * 64];
    __shared__ float red[32][4][2];
    const int m0 = blockIdx.x * 32;
    if ((m0 & 511) > lengths[m0 >> 9]) return;   // dead tile
    const int t = threadIdx.x;
    const int wid = t >> 6, lane = t & 63;
    const int lo = lane & 15, hi = lane >> 4;
    const int wm = wid >> 2, wn = wid & 3;
    const int lrow = lane >> 3, lc = lane & 7;
    f32x4 acc[4] = {};
    for (int k0 = 0; k0 < K; k0 += 64) {
        __syncthreads();
        if (wid < 4) {
            int r = wid * 8 + lrow;
            gload16(A + (size_t)(m0 + r) * K + k0 + ((lc ^ (r & 7)) * 8),
                    &As[(wid * 8) * 64]);
        }
#pragma unroll
        for (int is = 0; is < 4; ++is) {
            int r = wid * 32 + is * 8 + lrow;
            gload16(W + (size_t)r * K + k0 + ((lc ^ (r & 7)) * 8),
                    &Bs[(wid * 32 + is * 8) * 64]);
        }
        __syncthreads();
#pragma unroll
        for (int kh = 0; kh < 2; ++kh) {
            bf16x8 bfr[4];
#pragma unroll
            for (int nf = 0; nf < 4; ++nf) {
                int r = wn * 64 + nf * 16 + lo;
                bfr[nf] = *(const bf16x8*)&Bs[r * 64 + (((kh * 4 + hi) ^ (r & 7)) * 8)];
            }
            {
                int r = wm * 16 + lo;
                bf16x8 afr = *(const bf16x8*)&As[r * 64 + (((kh * 4 + hi) ^ (r & 7)) * 8)];
#pragma unroll
                for (int nf = 0; nf < 4; ++nf)
                    acc[nf] = __builtin_amdgcn_mfma_f32_16x16x32_bf16(afr, bfr[nf], acc[nf], 0, 0, 0);
            }
        }
    }
#pragma unroll
    for (int nf = 0; nf < 4; ++nf) {
        const int n = wn * 64 + nf * 16 + lo;
        const float bv = bias[n];
        const int rbase = m0 + wm * 16 + hi * 4;
#pragma unroll
        for (int rg = 0; rg < 4; ++rg) {
            size_t idx = (size_t)(rbase + rg) * 256 + n;
            float hv = acc[nf][rg] + bv + hres[idx];
            if constexpr (OUT == 0) hres[idx] = hv;
            acc[nf][rg] = hv;
        }
    }
#pragma unroll
    for (int rg = 0; rg < 4; ++rg) {
        float s = ((acc[0][rg] + acc[1][rg]) + (acc[2][rg] + acc[3][rg]));
        float sq = ((acc[0][rg] * acc[0][rg] + acc[1][rg] * acc[1][rg]) +
                    (acc[2][rg] * acc[2][rg] + acc[3][rg] * acc[3][rg]));
#pragma unroll
        for (int off = 1; off < 16; off <<= 1) {
            s += __shfl_xor(s, off);
            sq += __shfl_xor(sq, off);
        }
        if (lo == 0) {
            int rl = wm * 16 + hi * 4 + rg;
            red[rl][wn][0] = s;
            red[rl][wn][1] = sq;
        }
    }
    __syncthreads();
#pragma unroll
    for (int rg = 0; rg < 4; ++rg) {
        const int rl = wm * 16 + hi * 4 + rg;
        float s = (red[rl][0][0] + red[rl][1][0]) + (red[rl][2][0] + red[rl][3][0]);
        float sq = (red[rl][0][1] + red[rl][1][1]) + (red[rl][2][1] + red[rl][3][1]);
        float mean = s * (1.f / 256.f);
        float rs = rsqrtf(sq * (1.f / 256.f) - mean * mean + 1e-5f);
        if constexpr (OUT == 1) {
            const int row = m0 + rl;
            if ((row & 511) == 0) {
#pragma unroll
                for (int nf = 0; nf < 4; ++nf) {
                    const int n = wn * 64 + nf * 16 + lo;
                    outp[(size_t)(row >> 9) * 256 + n] =
                        (acc[nf][rg] - mean) * rs * g[n] + bvec[n];
                }
            }
        } else {
#pragma unroll
            for (int nf = 0; nf < 4; ++nf) {
                const int n = wn * 64 + nf * 16 + lo;
                u[(size_t)(m0 + rl) * 256 + n] =
                    f2bf((acc[nf][rg] - mean) * rs * g[n] + bvec[n]);
            }
        }
    }
}

// ---------------------------------------------------------------------------
// MFMA flash attention v11 = proven v9 (round-15, grid 2048) + dual PV
// accumulator banks split by ktp parity (2x ILP on the latency-bound MFMA
// accumulate chain; f32 add reorder only).
__global__ __launch_bounds__(256) void attn_mfma_kernel(
    const unsigned short* __restrict__ Qb, const unsigned short* __restrict__ Kb,
    const unsigned short* __restrict__ Vb, const float* __restrict__ clb,
    const float* __restrict__ csfb, const float* __restrict__ padfb,
    const float* __restrict__ alpha_p, const float* __restrict__ beta_p,
    const int* __restrict__ lengths, unsigned short* __restrict__ Ob)
{
    __shared__ __align__(16) unsigned short Kl[128 * 40];   // 10240 B
    __shared__ __align__(16) unsigned short Vt[32 * 132];   // 8448 B
    __shared__ __align__(16) float csfj[128];               // 512 B
    const int t = threadIdx.x;
    const int swz = ((blockIdx.x & 7) << 8) | (blockIdx.x >> 3);  // XCD chunking
    const int bh = swz >> 3, hf = swz & 7;
    const int b = bh >> 3, hd = bh & 7;
    const int len_b = lengths[b];
    if (hf * 64 > len_b) return;                 // dead q-tile
    const int njt = (len_b + 128) >> 7;          // ceil((len_b+1)/128)
    const size_t base = ((size_t)b * 512) * 256 + hd * 32;
    const int w = t >> 6, lane = t & 63, lo = lane & 15, hi = lane >> 4;
    const float L2E = 1.4426950408889634f;
    const float kb = L2E * (*beta_p);
    const float ka = L2E * (*alpha_p);
    const float* clg = clb + b * 512;

    const int i0 = (hf * 4 + w) * 16;
    const int iq = i0 + lo;
    const bf16x8 qf = *(const bf16x8*)(Qb + base + (size_t)iq * 256 + hi * 8);
    const float csb = fmaxf(kb * csfb[b * 512 + iq], 1e-3f);
    f32x4 acc0a = {0.f, 0.f, 0.f, 0.f}, acc1a = {0.f, 0.f, 0.f, 0.f};
    f32x4 acc0b = {0.f, 0.f, 0.f, 0.f}, acc1b = {0.f, 0.f, 0.f, 0.f};
    float lsum = 0.f;

    for (int jt = 0; jt < njt; ++jt) {
        __syncthreads();
        for (int idx = t; idx < 512; idx += 256) {       // K tile: 128 rows
            int row = idx >> 2, c4 = idx & 3;
            *(uint4*)&Kl[row * 40 + c4 * 8] =
                *(const uint4*)(Kb + base + (size_t)(jt * 128 + row) * 256 + c4 * 8);
        }
        for (int idx = t; idx < 512; idx += 256) {       // V^T via v_perm
            int pr = idx & 63, c4 = idx >> 6;
            const unsigned* vp0 = (const unsigned*)
                (Vb + base + (size_t)(jt * 128 + 2 * pr) * 256 + c4 * 4);
            const unsigned* vp1 = (const unsigned*)
                (Vb + base + (size_t)(jt * 128 + 2 * pr + 1) * 256 + c4 * 4);
            unsigned v0lo = vp0[0], v0hi = vp0[1];
            unsigned v1lo = vp1[0], v1hi = vp1[1];
            *(unsigned*)&Vt[(c4 * 4 + 0) * 132 + 2 * pr] =
                __builtin_amdgcn_perm(v1lo, v0lo, 0x05040100u);
            *(unsigned*)&Vt[(c4 * 4 + 1) * 132 + 2 * pr] =
                __builtin_amdgcn_perm(v1lo, v0lo, 0x07060302u);
            *(unsigned*)&Vt[(c4 * 4 + 2) * 132 + 2 * pr] =
                __builtin_amdgcn_perm(v1hi, v0hi, 0x05040100u);
            *(unsigned*)&Vt[(c4 * 4 + 3) * 132 + 2 * pr] =
                __builtin_amdgcn_perm(v1hi, v0hi, 0x07060302u);
        }
        if (t < 128) {                                   // csf with pad folded
            int j = jt * 128 + t;
            float cv = csfb[b * 512 + j];
            csfj[t] = (padfb[b * 512 + j] > 0.5f) ? -100000.f : cv;
        }
        __syncthreads();
#pragma unroll
        for (int ktp = 0; ktp < 4; ++ktp) {
            const int k16 = ktp * 32;             // local j base
            const int gj = jt * 128 + k16;        // global j base
            bf16x8 kf0 = *(const bf16x8*)&Kl[(k16 + lo) * 40 + hi * 8];
            bf16x8 kf1 = *(const bf16x8*)&Kl[(k16 + 16 + lo) * 40 + hi * 8];
            union U16 { unsigned long long q[2]; unsigned wd[4]; bf16x8 v; } vu0, vu1, pu;
            vu0.q[0] = *(const unsigned long long*)&Vt[lo * 132 + k16 + hi * 4];
            vu0.q[1] = *(const unsigned long long*)&Vt[lo * 132 + k16 + 16 + hi * 4];
            vu1.q[0] = *(const unsigned long long*)&Vt[(16 + lo) * 132 + k16 + hi * 4];
            vu1.q[1] = *(const unsigned long long*)&Vt[(16 + lo) * 132 + k16 + 16 + hi * 4];
            f32x4 csf0 = *(const f32x4*)&csfj[k16 + hi * 4];
            f32x4 csf1 = *(const f32x4*)&csfj[k16 + 16 + hi * 4];
            f32x4 c0, c1;
#pragma unroll
            for (int e = 0; e < 4; ++e) {
                c0[e] = csb * csf0[e];
                c1[e] = csb * csf1[e];
            }
            f32x4 s0 = __builtin_amdgcn_mfma_f32_16x16x32_bf16(kf0, qf, c0, 0, 0, 0);
            f32x4 s1 = __builtin_amdgcn_mfma_f32_16x16x32_bf16(kf1, qf, c1, 0, 0, 0);
            float p[8];
#pragma unroll
            for (int r = 0; r < 4; ++r) p[r] = exp2f(s0[r]);
#pragma unroll
            for (int r = 0; r < 4; ++r) p[4 + r] = exp2f(s1[r]);
            if (gj <= i0 + 16 && gj + 32 >= i0) {
#pragma unroll
                for (int r = 0; r < 8; ++r) {
                    int jr = gj + ((r & 4) ? 16 : 0) + hi * 4 + (r & 3);
                    int dij = jr - iq;
                    if (dij == 1 || dij == -1) {
                        float ce = (jr >= 1 && iq <= 510) ? clg[jr] : clg[iq];
                        p[r] *= exp2f(ka * ce);
                    }
                }
            }
            lsum += ((p[0] + p[1]) + (p[2] + p[3])) + ((p[4] + p[5]) + (p[6] + p[7]));
            pu.wd[0] = cvt_pk_bf16(p[0], p[1]);
            pu.wd[1] = cvt_pk_bf16(p[2], p[3]);
            pu.wd[2] = cvt_pk_bf16(p[4], p[5]);
            pu.wd[3] = cvt_pk_bf16(p[6], p[7]);
            if (ktp & 1) {
                acc0b = __builtin_amdgcn_mfma_f32_16x16x32_bf16(vu0.v, pu.v, acc0b, 0, 0, 0);
                acc1b = __builtin_amdgcn_mfma_f32_16x16x32_bf16(vu1.v, pu.v, acc1b, 0, 0, 0);
            } else {
                acc0a = __builtin_amdgcn_mfma_f32_16x16x32_bf16(vu0.v, pu.v, acc0a, 0, 0, 0);
                acc1a = __builtin_amdgcn_mfma_f32_16x16x32_bf16(vu1.v, pu.v, acc1a, 0, 0, 0);
            }
        }
    }
    {
        f32x4 acc0, acc1;
#pragma unroll
        for (int c = 0; c < 4; ++c) {
            acc0[c] = acc0a[c] + acc0b[c];
            acc1[c] = acc1a[c] + acc1b[c];
        }
        float ls = lsum;
        ls += __shfl_xor(ls, 16);
        ls += __shfl_xor(ls, 32);
        const float inv = 1.f / fmaxf(ls, 1e-35f);
        unsigned long long oa =
              (unsigned long long)cvt_pk_bf16(acc0[0] * inv, acc0[1] * inv)
            | ((unsigned long long)cvt_pk_bf16(acc0[2] * inv, acc0[3] * inv) << 32);
        unsigned long long ob2 =
              (unsigned long long)cvt_pk_bf16(acc1[0] * inv, acc1[1] * inv)
            | ((unsigned long long)cvt_pk_bf16(acc1[2] * inv, acc1[3] * inv) << 32);
        *(unsigned long long*)(Ob + base + (size_t)iq * 256 + hi * 4) = oa;
        *(unsigned long long*)(Ob + base + (size_t)iq * 256 + 16 + hi * 4) = ob2;
    }
}

// ---------------------------------------------------------------------------
extern "C" void kernel_launch(void* const* d_in, const int* in_sizes, int n_in,
                              void* d_out, int out_size, void* d_ws, size_t ws_size,
                              hipStream_t stream) {
    const float* x         = (const float*)d_in[0];
    const float* c_local   = (const float*)d_in[1];
    const float* c_sink    = (const float*)d_in[2];
    const float* W_in      = (const float*)d_in[3];
    const float* b_in      = (const float*)d_in[4];
    const float* cls_token = (const float*)d_in[5];
    const float* pe_proj_W = (const float*)d_in[6];
    const float* pe_proj_b = (const float*)d_in[7];
    const float* pe_ln_g   = (const float*)d_in[8];
    const float* pe_ln_b   = (const float*)d_in[9];
    const float* pe_gain   = (const float*)d_in[10];
    const float* attn_Wqkv = (const float*)d_in[11];
    const float* attn_bqkv = (const float*)d_in[12];
    const float* attn_Wo   = (const float*)d_in[13];
    const float* attn_bo   = (const float*)d_in[14];
    const float* ff_W1     = (const float*)d_in[15];
    const float* ff_b1     = (const float*)d_in[16];
    const float* ff_W2     = (const float*)d_in[17];
    const float* ff_b2     = (const float*)d_in[18];
    const float* ln1_g     = (const float*)d_in[19];
    const float* ln1_b     = (const float*)d_in[20];
    const float* ln2_g     = (const float*)d_in[21];
    const float* ln2_b     = (const float*)d_in[22];
    const float* alpha     = (const float*)d_in[23];
    const float* beta      = (const float*)d_in[24];
    const float* corr_fl   = (const float*)d_in[25];
    const float* out_ln_g  = (const float*)d_in[26];
    const float* out_ln_b  = (const float*)d_in[27];
    const int*   lengths   = (const int*)d_in[28];
    float* out = (float*)d_out;

    // float region (same slots as round-15 passing layout)
    float* h     = (float*)d_ws;              // 4,194,304
    float* clb   = h + 4194304;               // 16384
    float* csfb  = clb + 16384;
    float* padfb = csfb + 16384;
    float* W20t  = padfb + 16384;             // 5120 (in old peWt slot)
    float* PEpos = W20t + 70656;              // 131072
    float* bbf   = PEpos + 131072;            // old 8,388,608-float region
    // bf16 region — weights AFTER the full 16,777,216-short f-span at Q_bf
    unsigned short* u_bf = (unsigned short*)(bbf + 8388608);
    unsigned short* xb_bf = u_bf;             // alias: xb dead before layer loop
    unsigned short* Q_bf = u_bf + 4194304;
    unsigned short* K_bf = Q_bf + 4194304;
    unsigned short* V_bf = K_bf + 4194304;
    unsigned short* f_bf = Q_bf;              // alias: spans Q..Q+16777216
    unsigned short* o_bf = u_bf;              // alias (lifetimes disjoint)
    unsigned short* wq_bf = Q_bf + 16777216;  // after f's span
    unsigned short* wo_bf = wq_bf + 589824;
    unsigned short* w1_bf = wo_bf + 196608;
    unsigned short* w2_bf = w1_bf + 786432;
    unsigned short* win_bf = w2_bf + 786432;  // 16384
    unsigned short* S_bf   = win_bf + 16384;  // 131072 (sinusoid table)
    unsigned short* w256_bf = S_bf + 131072;  // 65536

    setup_kernel<<<4708, 256, 0, stream>>>(
        attn_Wqkv, wq_bf, attn_Wo, wo_bf, ff_W1, w1_bf, ff_W2, w2_bf,
        W_in, win_bf, pe_proj_W, w256_bf, W20t, x, xb_bf, S_bf);
    gemm_bf16_kernel<<<dim3(4, 4), 256, 0, stream>>>(
        S_bf, w256_bf, pe_proj_b, PEpos, nullptr, 512, 256, 256);
    gemm_bf16_kernel<<<dim3(4, 128), 256, 0, stream>>>(
        xb_bf, win_bf, b_in, bbf, lengths, 16384, 256, 64);
    prep_lite_kernel<<<2048, 256, 0, stream>>>(
        c_local, c_sink, bbf, cls_token, PEpos, W20t,
        pe_ln_g, pe_ln_b, pe_gain, corr_fl, lengths, ln1_g, ln1_b,
        h, clb, csfb, padfb, u_bf);

    for (int l = 0; l < 3; ++l) {
        gemm64_kernel<0><<<dim3(6, 256), 256, 0, stream>>>(
            u_bf, wq_bf + (size_t)l * 196608, attn_bqkv + 768 * l, lengths,
            Q_bf, K_bf, V_bf, 16384, 768, 256);
        attn_mfma_kernel<<<2048, 256, 0, stream>>>(Q_bf, K_bf, V_bf, clb, csfb,
                                                   padfb, alpha, beta, lengths, o_bf);
        gemm_res_ln_kernel<0><<<512, 512, 0, stream>>>(
            o_bf, wo_bf + (size_t)l * 65536, attn_bo + 256 * l, h,
            ln2_g + 256 * l, ln2_b + 256 * l, lengths, u_bf, nullptr, 256);
        gemm64_kernel<2><<<dim3(8, 256), 256, 0, stream>>>(
            u_bf, w1_bf + (size_t)l * 262144, ff_b1 + 1024 * l, lengths,
            f_bf, nullptr, nullptr, 16384, 1024, 256);
        if (l < 2) {
            gemm_res_ln_kernel<0><<<512, 512, 0, stream>>>(
                f_bf, w2_bf + (size_t)l * 262144, ff_b2 + 256 * l, h,
                ln1_g + 256 * (l + 1), ln1_b + 256 * (l + 1), lengths, u_bf, nullptr, 1024);
        } else {
            gemm_res_ln_kernel<1><<<512, 512, 0, stream>>>(
                f_bf, w2_bf + (size_t)l * 262144, ff_b2 + 256 * l, h,
                out_ln_g, out_ln_b, lengths, nullptr, out, 1024);
        }
    }
}

// Round 18
// 320.791 us; speedup vs baseline: 1.2391x; 1.0590x over previous
//
#include <hip/hip_runtime.h>
#include <math.h>

// B=32, L=512 (incl CLS), D=256, H=8, dh=32, N_LAYERS=3, D_FF=1024, tokens=16384
// Length-aware + layer-2 liveness-trimmed: output is CLS-only, so layer-2
// work is back-propagated to the tiles that can reach it (qlim predicate).

typedef __attribute__((ext_vector_type(4))) float f32x4;
typedef __attribute__((ext_vector_type(8))) short bf16x8;

__device__ __forceinline__ unsigned short f2bf(float f) {
    unsigned u = __builtin_bit_cast(unsigned, f);
    u += 0x7fff + ((u >> 16) & 1);
    return (unsigned short)(u >> 16);
}
__device__ __forceinline__ unsigned cvt_pk_bf16(float a, float b) {
    unsigned r;
    asm("v_cvt_pk_bf16_f32 %0, %1, %2" : "=v"(r) : "v"(a), "v"(b));
    return r;
}
__device__ __forceinline__ float gelu_f(float v) {
    return v * 0.5f * (1.0f + erff(v * 0.70710678118654752f));
}
__device__ __forceinline__ void gload16(const void* g, void* l) {
    __builtin_amdgcn_global_load_lds(
        (const __attribute__((address_space(1))) unsigned int*)g,
        (__attribute__((address_space(3))) unsigned int*)l, 16, 0, 0);
}

// ---------------------------------------------------------------------------
// Mega setup kernel: all weight cvts + pe transposes + sinusoid + xb.
__global__ __launch_bounds__(256) void setup_kernel(
    const float* __restrict__ wq, unsigned short* __restrict__ wq_o,   // 576
    const float* __restrict__ wo, unsigned short* __restrict__ wo_o,   // 192
    const float* __restrict__ w1, unsigned short* __restrict__ w1_o,   // 768
    const float* __restrict__ w2, unsigned short* __restrict__ w2_o,   // 768
    const float* __restrict__ win, unsigned short* __restrict__ win_o, // 16
    const float* __restrict__ peW, unsigned short* __restrict__ w256,  // 64
    float* __restrict__ W20t,                                          // 20
    const float* __restrict__ x, unsigned short* __restrict__ xb,      // 2048
    unsigned short* __restrict__ S)                                    // 256
{
    int blk = blockIdx.x, t = threadIdx.x;
    if (blk < 2304) {  // plain f32->bf16 cvts
        const float* s; unsigned short* d; int base;
        if (blk < 576)       { s = wq; d = wq_o; base = blk; }
        else if (blk < 768)  { s = wo; d = wo_o; base = blk - 576; }
        else if (blk < 1536) { s = w1; d = w1_o; base = blk - 768; }
        else                 { s = w2; d = w2_o; base = blk - 1536; }
        int i = (base * 256 + t) * 4;
        float4 v = *(const float4*)(s + i);
        unsigned long long pk = (unsigned long long)f2bf(v.x)
            | ((unsigned long long)f2bf(v.y) << 16)
            | ((unsigned long long)f2bf(v.z) << 32)
            | ((unsigned long long)f2bf(v.w) << 48);
        *(unsigned long long*)(d + i) = pk;
    } else if (blk < 2320) {  // win
        int i = ((blk - 2304) * 256 + t) * 4;
        float4 v = *(const float4*)(win + i);
        unsigned long long pk = (unsigned long long)f2bf(v.x)
            | ((unsigned long long)f2bf(v.y) << 16)
            | ((unsigned long long)f2bf(v.z) << 32)
            | ((unsigned long long)f2bf(v.w) << 48);
        *(unsigned long long*)(win_o + i) = pk;
    } else if (blk < 2384) {  // peW first-256 feats -> bf16 [256][256]
        int i = ((blk - 2320) * 256 + t) * 4;
        int d = i >> 8, f = i & 255;
        float4 v = *(const float4*)(peW + d * 276 + f);
        unsigned long long pk = (unsigned long long)f2bf(v.x)
            | ((unsigned long long)f2bf(v.y) << 16)
            | ((unsigned long long)f2bf(v.z) << 32)
            | ((unsigned long long)f2bf(v.w) << 48);
        *(unsigned long long*)(w256 + i) = pk;
    } else if (blk < 2404) {  // W20t[f][d] = peW[d][256+f]
        int j = (blk - 2384) * 256 + t;
        int f = j >> 8, dd = j & 255;
        W20t[j] = peW[dd * 276 + 256 + f];
    } else if (blk < 4452) {  // xb
        int idx = (blk - 2404) * 256 + t;
        int tok = idx >> 5, c2 = idx & 31;
        int b = tok >> 9, l = tok & 511;
        unsigned r = 0;
        if (l > 0) {
            float2 v = *(const float2*)(x + ((size_t)b * 511 + l - 1) * 64 + 2 * c2);
            r = cvt_pk_bf16(v.x, v.y);
        }
        *(unsigned*)(xb + (size_t)tok * 64 + 2 * c2) = r;
    } else {  // sinusoid table
        int p = (blk - 4452) * 256 + t;
        int l = p >> 7, k = p & 127;
        float div = expf((float)(2 * k) * -0.035977892078032f);
        float a = (float)l * div;
        *(unsigned*)(S + l * 256 + 2 * k) = cvt_pk_bf16(sinf(a), cosf(a));
    }
}

// ---------------------------------------------------------------------------
// prep_lite: arrays for ALL tokens; h/u only for live 8-row groups.
__global__ __launch_bounds__(256) void prep_lite_kernel(
    const float* __restrict__ c_local, const float* __restrict__ c_sink,
    const float* __restrict__ bb, const float* __restrict__ cls_tok,
    const float* __restrict__ PEpos, const float* __restrict__ W20t,
    const float* __restrict__ pe_g, const float* __restrict__ pe_bb,
    const float* __restrict__ pe_gain_p, const float* __restrict__ corr_floor_p,
    const int* __restrict__ lengths, const float* __restrict__ ln1g,
    const float* __restrict__ ln1b,
    float* __restrict__ h, float* __restrict__ clb, float* __restrict__ csfb,
    float* __restrict__ padfb, unsigned short* __restrict__ u)
{
    __shared__ float zs[8][20];
    __shared__ __align__(16) float pes[8][256];
    __shared__ float mn[8], rsd[8];
    const int t = threadIdx.x;
    const int tok0 = blockIdx.x * 8;
    const int b = tok0 >> 9;
    const int len_b = lengths[b];
    const float cf = *corr_floor_p;
    const float gain = *pe_gain_p;

    float clv[8], csv[8];
    bool mk[8];
#pragma unroll
    for (int k = 0; k < 8; ++k) {
        int l = (tok0 + k) & 511;
        if (l == 0) { clv[k] = 1.f; csv[k] = 1.f; mk[k] = false; }
        else {
            float a = c_local[b * 511 + l - 1];
            float s = c_sink[b * 511 + l - 1];
            clv[k] = fminf(fmaxf(a, 0.f), 1.f);
            csv[k] = fminf(fmaxf(s, 0.f), 1.f);
            mk[k] = (l - 1) >= len_b;
        }
    }
    if (t < 8) {
        int tok = tok0 + t;
        clb[tok] = clv[t];
        csfb[tok] = cf + (1.f - cf) * csv[t];
        padfb[tok] = mk[t] ? 1.f : 0.f;
    }
    // dead group: mask arrays written above are all that's needed
    if ((tok0 & 511) > len_b) return;
    if (t < 20) {
#pragma unroll
        for (int k = 0; k < 8; ++k) {
            float cl = clv[k], cs = csv[k];
            float v;
            if (t == 0) v = cl;
            else if (t == 1) v = cs;
            else if (t == 2) v = cl * cs;
            else if (t == 3) v = fabsf(cl - cs);
            else if (t < 12) {
                float c = (float)(t - 4) * (1.f / 7.f);
                float dd = (cl - c) / 0.200001f;
                v = expf(-0.5f * dd * dd);
            } else {
                float c = (float)(t - 12) * (1.f / 7.f);
                float dd = (cs - c) / 0.200001f;
                v = expf(-0.5f * dd * dd);
            }
            zs[k][t] = v;
        }
    }
    __syncthreads();

    float acc[8];
#pragma unroll
    for (int k = 0; k < 8; ++k)
        acc[k] = PEpos[((tok0 + k) & 511) * 256 + t];
    for (int f = 0; f < 20; ++f) {
        float wv = W20t[f * 256 + t];
#pragma unroll
        for (int k = 0; k < 8; ++k) acc[k] += zs[k][f] * wv;
    }
#pragma unroll
    for (int k = 0; k < 8; ++k) pes[k][t] = acc[k];
    __syncthreads();

    {
        int w = t >> 6, lane = t & 63;
#pragma unroll
        for (int p = 0; p < 2; ++p) {
            int k = w + p * 4;
            float4 v = *(const float4*)&pes[k][lane * 4];
            float s = v.x + v.y + v.z + v.w;
            float sq = v.x * v.x + v.y * v.y + v.z * v.z + v.w * v.w;
#pragma unroll
            for (int off = 32; off; off >>= 1) {
                s += __shfl_xor(s, off);
                sq += __shfl_xor(sq, off);
            }
            if (lane == 0) {
                float mean = s * (1.f / 256.f);
                mn[k] = mean;
                rsd[k] = rsqrtf(sq * (1.f / 256.f) - mean * mean + 1e-5f);
            }
        }
    }
    __syncthreads();
    float gv = pe_g[t], bv = pe_bb[t];
    float hv[8];
#pragma unroll
    for (int k = 0; k < 8; ++k) {
        int l = (tok0 + k) & 511;
        float base = (l == 0) ? cls_tok[t] : bb[(size_t)(tok0 + k) * 256 + t];
        float pe = (pes[k][t] - mn[k]) * rsd[k] * gv + bv;
        pe *= gain;
        if (mk[k]) pe = 0.f;
        hv[k] = base + pe;
        h[(size_t)(tok0 + k) * 256 + t] = hv[k];
    }
    __syncthreads();
#pragma unroll
    for (int k = 0; k < 8; ++k) pes[k][t] = hv[k];
    __syncthreads();
    {
        int w = t >> 6, lane = t & 63;
#pragma unroll
        for (int p = 0; p < 2; ++p) {
            int k = w + p * 4;
            float4 v = *(const float4*)&pes[k][lane * 4];
            float s = v.x + v.y + v.z + v.w;
            float sq = v.x * v.x + v.y * v.y + v.z * v.z + v.w * v.w;
#pragma unroll
            for (int off = 32; off; off >>= 1) {
                s += __shfl_xor(s, off);
                sq += __shfl_xor(sq, off);
            }
            if (lane == 0) {
                float mean = s * (1.f / 256.f);
                mn[k] = mean;
                rsd[k] = rsqrtf(sq * (1.f / 256.f) - mean * mean + 1e-5f);
            }
        }
    }
    __syncthreads();
    float g1 = ln1g[t], b1 = ln1b[t];
#pragma unroll
    for (int k = 0; k < 8; ++k)
        u[(size_t)(tok0 + k) * 256 + t] = f2bf((hv[k] - mn[k]) * rsd[k] * g1 + b1);
}

// ---------------------------------------------------------------------------
// bf16 MFMA GEMM, 128x64 tile (proven): C[M,N] = A @ W^T + bias (f32 store).
// Optional length-skip (lengths != nullptr, 128-aligned M tiles).
__global__ __launch_bounds__(256) void gemm_bf16_kernel(
    const unsigned short* __restrict__ A, const unsigned short* __restrict__ W,
    const float* __restrict__ bias, float* __restrict__ hres,
    const int* __restrict__ lengths, int M, int N, int K)
{
    __shared__ __align__(16) unsigned short As[128 * 64];
    __shared__ __align__(16) unsigned short Bs[64 * 64];
    const int m0 = blockIdx.y * 128, n0 = blockIdx.x * 64;
    if (lengths && (m0 & 511) > lengths[m0 >> 9]) return;
    const int t = threadIdx.x;
    const int wid = t >> 6, lane = t & 63;
    const int lo = lane & 15, hi = lane >> 4;
    const int wm = wid >> 1, wn = wid & 1;
    const int lrow = lane >> 3, lc = lane & 7;
    f32x4 acc[4][2] = {};
    for (int k0 = 0; k0 < K; k0 += 64) {
        __syncthreads();
#pragma unroll
        for (int is = 0; is < 4; ++is) {
            int r = wid * 32 + is * 8 + lrow;
            const unsigned short* g = A + (size_t)(m0 + r) * K + k0 + ((lc ^ (r & 7)) * 8);
            gload16(g, &As[(wid * 32 + is * 8) * 64]);
        }
#pragma unroll
        for (int is = 0; is < 2; ++is) {
            int r = wid * 16 + is * 8 + lrow;
            const unsigned short* g = W + (size_t)(n0 + r) * K + k0 + ((lc ^ (r & 7)) * 8);
            gload16(g, &Bs[(wid * 16 + is * 8) * 64]);
        }
        __syncthreads();
#pragma unroll
        for (int kh = 0; kh < 2; ++kh) {
            bf16x8 bfr[2];
#pragma unroll
            for (int nf = 0; nf < 2; ++nf) {
                int r = wn * 32 + nf * 16 + lo;
                bfr[nf] = *(const bf16x8*)&Bs[r * 64 + (((kh * 4 + hi) ^ (r & 7)) * 8)];
            }
#pragma unroll
            for (int mf = 0; mf < 4; ++mf) {
                int r = wm * 64 + mf * 16 + lo;
                bf16x8 afr = *(const bf16x8*)&As[r * 64 + (((kh * 4 + hi) ^ (r & 7)) * 8)];
                acc[mf][0] = __builtin_amdgcn_mfma_f32_16x16x32_bf16(afr, bfr[0], acc[mf][0], 0, 0, 0);
                acc[mf][1] = __builtin_amdgcn_mfma_f32_16x16x32_bf16(afr, bfr[1], acc[mf][1], 0, 0, 0);
            }
        }
    }
#pragma unroll
    for (int mf = 0; mf < 4; ++mf) {
        const int mbase = m0 + wm * 64 + mf * 16 + hi * 4;
#pragma unroll
        for (int nf = 0; nf < 2; ++nf) {
            const int n = n0 + wn * 32 + nf * 16 + lo;
            const float bv = bias[n];
            f32x4 v = acc[mf][nf];
#pragma unroll
            for (int rg = 0; rg < 4; ++rg)
                hres[(size_t)(mbase + rg) * N + n] = v[rg] + bv;
        }
    }
}

// ---------------------------------------------------------------------------
// bf16 MFMA GEMM, 64x128 tile: QKV (EPI=0), FF1 GELU (EPI=2).
// Skip when (m0&511) > min(lengths[b], qlim).
template <int EPI>
__global__ __launch_bounds__(256) void gemm64_kernel(
    const unsigned short* __restrict__ A, const unsigned short* __restrict__ W,
    const float* __restrict__ bias, const int* __restrict__ lengths, int qlim,
    unsigned short* __restrict__ o0, unsigned short* __restrict__ o1,
    unsigned short* __restrict__ o2, int M, int N, int K)
{
    __shared__ __align__(16) unsigned short As[64 * 64];
    __shared__ __align__(16) unsigned short Bs[128 * 64];
    const int m0 = blockIdx.y * 64, n0 = blockIdx.x * 128;
    if ((m0 & 511) > min(lengths[m0 >> 9], qlim)) return;   // dead tile
    const int t = threadIdx.x;
    const int wid = t >> 6, lane = t & 63;
    const int lo = lane & 15, hi = lane >> 4;
    const int wm = wid >> 1, wn = wid & 1;
    const int lrow = lane >> 3, lc = lane & 7;
    f32x4 acc[2][4] = {};
    for (int k0 = 0; k0 < K; k0 += 64) {
        __syncthreads();
#pragma unroll
        for (int is = 0; is < 2; ++is) {
            int r = wid * 16 + is * 8 + lrow;
            const unsigned short* g = A + (size_t)(m0 + r) * K + k0 + ((lc ^ (r & 7)) * 8);
            gload16(g, &As[(wid * 16 + is * 8) * 64]);
        }
#pragma unroll
        for (int is = 0; is < 4; ++is) {
            int r = wid * 32 + is * 8 + lrow;
            const unsigned short* g = W + (size_t)(n0 + r) * K + k0 + ((lc ^ (r & 7)) * 8);
            gload16(g, &Bs[(wid * 32 + is * 8) * 64]);
        }
        __syncthreads();
#pragma unroll
        for (int kh = 0; kh < 2; ++kh) {
            bf16x8 bfr[4];
#pragma unroll
            for (int nf = 0; nf < 4; ++nf) {
                int r = wn * 64 + nf * 16 + lo;
                bfr[nf] = *(const bf16x8*)&Bs[r * 64 + (((kh * 4 + hi) ^ (r & 7)) * 8)];
            }
#pragma unroll
            for (int mf = 0; mf < 2; ++mf) {
                int r = wm * 32 + mf * 16 + lo;
                bf16x8 afr = *(const bf16x8*)&As[r * 64 + (((kh * 4 + hi) ^ (r & 7)) * 8)];
#pragma unroll
                for (int nf = 0; nf < 4; ++nf)
                    acc[mf][nf] = __builtin_amdgcn_mfma_f32_16x16x32_bf16(afr, bfr[nf], acc[mf][nf], 0, 0, 0);
            }
        }
    }
#pragma unroll
    for (int mf = 0; mf < 2; ++mf) {
        const int mbase = m0 + wm * 32 + mf * 16 + hi * 4;
#pragma unroll
        for (int nf = 0; nf < 4; ++nf) {
            const int n = n0 + wn * 64 + nf * 16 + lo;
            const float bv = bias[n];
            f32x4 v = acc[mf][nf];
            if constexpr (EPI == 0) {
                unsigned short* dst = (n < 256) ? o0 : ((n < 512) ? o1 : o2);
                const float qsc = (n < 256)
                    ? (0.17677669529663687f * 1.4426950408889634f) : 1.f;
                const int c = n & 255;
#pragma unroll
                for (int rg = 0; rg < 4; ++rg)
                    dst[(size_t)(mbase + rg) * 256 + c] = f2bf((v[rg] + bv) * qsc);
            } else {
#pragma unroll
                for (int rg = 0; rg < 4; ++rg)
                    o0[(size_t)(mbase + rg) * N + n] = f2bf(gelu_f(v[rg] + bv));
            }
        }
    }
}

// ---------------------------------------------------------------------------
// Fused residual-GEMM + LayerNorm (proven 32x256 tile), length+qlim aware.
// OUT=0: h += GEMM; u = LN(h).  OUT=1: final FF2 -> out-LN CLS rows only.
template <int OUT>
__global__ __launch_bounds__(512) void gemm_res_ln_kernel(
    const unsigned short* __restrict__ A, const unsigned short* __restrict__ W,
    const float* __restrict__ bias, float* __restrict__ hres,
    const float* __restrict__ g, const float* __restrict__ bvec,
    const int* __restrict__ lengths, int qlim,
    unsigned short* __restrict__ u, float* __restrict__ outp, int K)
{
    __shared__ __align__(16) unsigned short As[32 * 64];
    __shared__ __align__(16) unsigned short Bs[256 * 64];
    __shared__ float red[32][4][2];
    const int m0 = blockIdx.x * 32;
    if ((m0 & 511) > min(lengths[m0 >> 9], qlim)) return;   // dead tile
    const int t = threadIdx.x;
    const int wid = t >> 6, lane = t & 63;
    const int lo = lane & 15, hi = lane >> 4;
    const int wm = wid >> 2, wn = wid & 3;
    const int lrow = lane >> 3, lc = lane & 7;
    f32x4 acc[4] = {};
    for (int k0 = 0; k0 < K; k0 += 64) {
        __syncthreads();
        if (wid < 4) {
            int r = wid * 8 + lrow;
            gload16(A + (size_t)(m0 + r) * K + k0 + ((lc ^ (r & 7)) * 8),
                    &As[(wid * 8) * 64]);
        }
#pragma unroll
        for (int is = 0; is < 4; ++is) {
            int r = wid * 32 + is * 8 + lrow;
            gload16(W + (size_t)r * K + k0 + ((lc ^ (r & 7)) * 8),
                    &Bs[(wid * 32 + is * 8) * 64]);
        }
        __syncthreads();
#pragma unroll
        for (int kh = 0; kh < 2; ++kh) {
            bf16x8 bfr[4];
#pragma unroll
            for (int nf = 0; nf < 4; ++nf) {
                int r = wn * 64 + nf * 16 + lo;
                bfr[nf] = *(const bf16x8*)&Bs[r * 64 + (((kh * 4 + hi) ^ (r & 7)) * 8)];
            }
            {
                int r = wm * 16 + lo;
                bf16x8 afr = *(const bf16x8*)&As[r * 64 + (((kh * 4 + hi) ^ (r & 7)) * 8)];
#pragma unroll
                for (int nf = 0; nf < 4; ++nf)
                    acc[nf] = __builtin_amdgcn_mfma_f32_16x16x32_bf16(afr, bfr[nf], acc[nf], 0, 0, 0);
            }
        }
    }
#pragma unroll
    for (int nf = 0; nf < 4; ++nf) {
        const int n = wn * 64 + nf * 16 + lo;
        const float bv = bias[n];
        const int rbase = m0 + wm * 16 + hi * 4;
#pragma unroll
        for (int rg = 0; rg < 4; ++rg) {
            size_t idx = (size_t)(rbase + rg) * 256 + n;
            float hv = acc[nf][rg] + bv + hres[idx];
            if constexpr (OUT == 0) hres[idx] = hv;
            acc[nf][rg] = hv;
        }
    }
#pragma unroll
    for (int rg = 0; rg < 4; ++rg) {
        float s = ((acc[0][rg] + acc[1][rg]) + (acc[2][rg] + acc[3][rg]));
        float sq = ((acc[0][rg] * acc[0][rg] + acc[1][rg] * acc[1][rg]) +
                    (acc[2][rg] * acc[2][rg] + acc[3][rg] * acc[3][rg]));
#pragma unroll
        for (int off = 1; off < 16; off <<= 1) {
            s += __shfl_xor(s, off);
            sq += __shfl_xor(sq, off);
        }
        if (lo == 0) {
            int rl = wm * 16 + hi * 4 + rg;
            red[rl][wn][0] = s;
            red[rl][wn][1] = sq;
        }
    }
    __syncthreads();
#pragma unroll
    for (int rg = 0; rg < 4; ++rg) {
        const int rl = wm * 16 + hi * 4 + rg;
        float s = (red[rl][0][0] + red[rl][1][0]) + (red[rl][2][0] + red[rl][3][0]);
        float sq = (red[rl][0][1] + red[rl][1][1]) + (red[rl][2][1] + red[rl][3][1]);
        float mean = s * (1.f / 256.f);
        float rs = rsqrtf(sq * (1.f / 256.f) - mean * mean + 1e-5f);
        if constexpr (OUT == 1) {
            const int row = m0 + rl;
            if ((row & 511) == 0) {
#pragma unroll
                for (int nf = 0; nf < 4; ++nf) {
                    const int n = wn * 64 + nf * 16 + lo;
                    outp[(size_t)(row >> 9) * 256 + n] =
                        (acc[nf][rg] - mean) * rs * g[n] + bvec[n];
                }
            }
        } else {
#pragma unroll
            for (int nf = 0; nf < 4; ++nf) {
                const int n = wn * 64 + nf * 16 + lo;
                u[(size_t)(m0 + rl) * 256 + n] =
                    f2bf((acc[nf][rg] - mean) * rs * g[n] + bvec[n]);
            }
        }
    }
}

// ---------------------------------------------------------------------------
// MFMA flash attention (proven round-15/17 structure) + qlim q-tile trim.
__global__ __launch_bounds__(256) void attn_mfma_kernel(
    const unsigned short* __restrict__ Qb, const unsigned short* __restrict__ Kb,
    const unsigned short* __restrict__ Vb, const float* __restrict__ clb,
    const float* __restrict__ csfb, const float* __restrict__ padfb,
    const float* __restrict__ alpha_p, const float* __restrict__ beta_p,
    const int* __restrict__ lengths, int qlim, unsigned short* __restrict__ Ob)
{
    __shared__ __align__(16) unsigned short Kl[128 * 40];   // 10240 B
    __shared__ __align__(16) unsigned short Vt[32 * 132];   // 8448 B
    __shared__ __align__(16) float csfj[128];               // 512 B
    const int t = threadIdx.x;
    const int swz = ((blockIdx.x & 7) << 8) | (blockIdx.x >> 3);  // XCD chunking
    const int bh = swz >> 3, hf = swz & 7;
    const int b = bh >> 3, hd = bh & 7;
    const int len_b = lengths[b];
    if (hf * 64 > min(len_b, qlim)) return;      // dead q-tile
    const int njt = (len_b + 128) >> 7;          // ceil((len_b+1)/128)
    const size_t base = ((size_t)b * 512) * 256 + hd * 32;
    const int w = t >> 6, lane = t & 63, lo = lane & 15, hi = lane >> 4;
    const float L2E = 1.4426950408889634f;
    const float kb = L2E * (*beta_p);
    const float ka = L2E * (*alpha_p);
    const float* clg = clb + b * 512;

    const int i0 = (hf * 4 + w) * 16;
    const int iq = i0 + lo;
    const bf16x8 qf = *(const bf16x8*)(Qb + base + (size_t)iq * 256 + hi * 8);
    const float csb = fmaxf(kb * csfb[b * 512 + iq], 1e-3f);
    f32x4 acc0 = {0.f, 0.f, 0.f, 0.f}, acc1 = {0.f, 0.f, 0.f, 0.f};
    float lsum = 0.f;

    for (int jt = 0; jt < njt; ++jt) {
        __syncthreads();
        for (int idx = t; idx < 512; idx += 256) {       // K tile: 128 rows
            int row = idx >> 2, c4 = idx & 3;
            *(uint4*)&Kl[row * 40 + c4 * 8] =
                *(const uint4*)(Kb + base + (size_t)(jt * 128 + row) * 256 + c4 * 8);
        }
        for (int idx = t; idx < 512; idx += 256) {       // V^T via v_perm
            int pr = idx & 63, c4 = idx >> 6;
            const unsigned* vp0 = (const unsigned*)
                (Vb + base + (size_t)(jt * 128 + 2 * pr) * 256 + c4 * 4);
            const unsigned* vp1 = (const unsigned*)
                (Vb + base + (size_t)(jt * 128 + 2 * pr + 1) * 256 + c4 * 4);
            unsigned v0lo = vp0[0], v0hi = vp0[1];
            unsigned v1lo = vp1[0], v1hi = vp1[1];
            *(unsigned*)&Vt[(c4 * 4 + 0) * 132 + 2 * pr] =
                __builtin_amdgcn_perm(v1lo, v0lo, 0x05040100u);
            *(unsigned*)&Vt[(c4 * 4 + 1) * 132 + 2 * pr] =
                __builtin_amdgcn_perm(v1lo, v0lo, 0x07060302u);
            *(unsigned*)&Vt[(c4 * 4 + 2) * 132 + 2 * pr] =
                __builtin_amdgcn_perm(v1hi, v0hi, 0x05040100u);
            *(unsigned*)&Vt[(c4 * 4 + 3) * 132 + 2 * pr] =
                __builtin_amdgcn_perm(v1hi, v0hi, 0x07060302u);
        }
        if (t < 128) {                                   // csf with pad folded
            int j = jt * 128 + t;
            float cv = csfb[b * 512 + j];
            csfj[t] = (padfb[b * 512 + j] > 0.5f) ? -100000.f : cv;
        }
        __syncthreads();
#pragma unroll
        for (int ktp = 0; ktp < 4; ++ktp) {
            const int k16 = ktp * 32;             // local j base
            const int gj = jt * 128 + k16;        // global j base
            bf16x8 kf0 = *(const bf16x8*)&Kl[(k16 + lo) * 40 + hi * 8];
            bf16x8 kf1 = *(const bf16x8*)&Kl[(k16 + 16 + lo) * 40 + hi * 8];
            union U16 { unsigned long long q[2]; unsigned wd[4]; bf16x8 v; } vu0, vu1, pu;
            vu0.q[0] = *(const unsigned long long*)&Vt[lo * 132 + k16 + hi * 4];
            vu0.q[1] = *(const unsigned long long*)&Vt[lo * 132 + k16 + 16 + hi * 4];
            vu1.q[0] = *(const unsigned long long*)&Vt[(16 + lo) * 132 + k16 + hi * 4];
            vu1.q[1] = *(const unsigned long long*)&Vt[(16 + lo) * 132 + k16 + 16 + hi * 4];
            f32x4 csf0 = *(const f32x4*)&csfj[k16 + hi * 4];
            f32x4 csf1 = *(const f32x4*)&csfj[k16 + 16 + hi * 4];
            f32x4 c0, c1;
#pragma unroll
            for (int e = 0; e < 4; ++e) {
                c0[e] = csb * csf0[e];
                c1[e] = csb * csf1[e];
            }
            f32x4 s0 = __builtin_amdgcn_mfma_f32_16x16x32_bf16(kf0, qf, c0, 0, 0, 0);
            f32x4 s1 = __builtin_amdgcn_mfma_f32_16x16x32_bf16(kf1, qf, c1, 0, 0, 0);
            float p[8];
#pragma unroll
            for (int r = 0; r < 4; ++r) p[r] = exp2f(s0[r]);
#pragma unroll
            for (int r = 0; r < 4; ++r) p[4 + r] = exp2f(s1[r]);
            if (gj <= i0 + 16 && gj + 32 >= i0) {
#pragma unroll
                for (int r = 0; r < 8; ++r) {
                    int jr = gj + ((r & 4) ? 16 : 0) + hi * 4 + (r & 3);
                    int dij = jr - iq;
                    if (dij == 1 || dij == -1) {
                        float ce = (jr >= 1 && iq <= 510) ? clg[jr] : clg[iq];
                        p[r] *= exp2f(ka * ce);
                    }
                }
            }
            lsum += ((p[0] + p[1]) + (p[2] + p[3])) + ((p[4] + p[5]) + (p[6] + p[7]));
            pu.wd[0] = cvt_pk_bf16(p[0], p[1]);
            pu.wd[1] = cvt_pk_bf16(p[2], p[3]);
            pu.wd[2] = cvt_pk_bf16(p[4], p[5]);
            pu.wd[3] = cvt_pk_bf16(p[6], p[7]);
            acc0 = __builtin_amdgcn_mfma_f32_16x16x32_bf16(vu0.v, pu.v, acc0, 0, 0, 0);
            acc1 = __builtin_amdgcn_mfma_f32_16x16x32_bf16(vu1.v, pu.v, acc1, 0, 0, 0);
        }
    }
    {
        float ls = lsum;
        ls += __shfl_xor(ls, 16);
        ls += __shfl_xor(ls, 32);
        const float inv = 1.f / fmaxf(ls, 1e-35f);
        unsigned long long oa =
              (unsigned long long)cvt_pk_bf16(acc0[0] * inv, acc0[1] * inv)
            | ((unsigned long long)cvt_pk_bf16(acc0[2] * inv, acc0[3] * inv) << 32);
        unsigned long long ob2 =
              (unsigned long long)cvt_pk_bf16(acc1[0] * inv, acc1[1] * inv)
            | ((unsigned long long)cvt_pk_bf16(acc1[2] * inv, acc1[3] * inv) << 32);
        *(unsigned long long*)(Ob + base + (size_t)iq * 256 + hi * 4) = oa;
        *(unsigned long long*)(Ob + base + (size_t)iq * 256 + 16 + hi * 4) = ob2;
    }
}

// ---------------------------------------------------------------------------
extern "C" void kernel_launch(void* const* d_in, const int* in_sizes, int n_in,
                              void* d_out, int out_size, void* d_ws, size_t ws_size,
                              hipStream_t stream) {
    const float* x         = (const float*)d_in[0];
    const float* c_local   = (const float*)d_in[1];
    const float* c_sink    = (const float*)d_in[2];
    const float* W_in      = (const float*)d_in[3];
    const float* b_in      = (const float*)d_in[4];
    const float* cls_token = (const float*)d_in[5];
    const float* pe_proj_W = (const float*)d_in[6];
    const float* pe_proj_b = (const float*)d_in[7];
    const float* pe_ln_g   = (const float*)d_in[8];
    const float* pe_ln_b   = (const float*)d_in[9];
    const float* pe_gain   = (const float*)d_in[10];
    const float* attn_Wqkv = (const float*)d_in[11];
    const float* attn_bqkv = (const float*)d_in[12];
    const float* attn_Wo   = (const float*)d_in[13];
    const float* attn_bo   = (const float*)d_in[14];
    const float* ff_W1     = (const float*)d_in[15];
    const float* ff_b1     = (const float*)d_in[16];
    const float* ff_W2     = (const float*)d_in[17];
    const float* ff_b2     = (const float*)d_in[18];
    const float* ln1_g     = (const float*)d_in[19];
    const float* ln1_b     = (const float*)d_in[20];
    const float* ln2_g     = (const float*)d_in[21];
    const float* ln2_b     = (const float*)d_in[22];
    const float* alpha     = (const float*)d_in[23];
    const float* beta      = (const float*)d_in[24];
    const float* corr_fl   = (const float*)d_in[25];
    const float* out_ln_g  = (const float*)d_in[26];
    const float* out_ln_b  = (const float*)d_in[27];
    const int*   lengths   = (const int*)d_in[28];
    float* out = (float*)d_out;

    // float region (same slots as round-17 passing layout)
    float* h     = (float*)d_ws;              // 4,194,304
    float* clb   = h + 4194304;               // 16384
    float* csfb  = clb + 16384;
    float* padfb = csfb + 16384;
    float* W20t  = padfb + 16384;             // 5120 (in old peWt slot)
    float* PEpos = W20t + 70656;              // 131072
    float* bbf   = PEpos + 131072;            // old 8,388,608-float region
    // bf16 region — weights AFTER the full 16,777,216-short f-span at Q_bf
    unsigned short* u_bf = (unsigned short*)(bbf + 8388608);
    unsigned short* xb_bf = u_bf;             // alias: xb dead before layer loop
    unsigned short* Q_bf = u_bf + 4194304;
    unsigned short* K_bf = Q_bf + 4194304;
    unsigned short* V_bf = K_bf + 4194304;
    unsigned short* f_bf = Q_bf;              // alias: spans Q..Q+16777216
    unsigned short* o_bf = u_bf;              // alias (lifetimes disjoint)
    unsigned short* wq_bf = Q_bf + 16777216;  // after f's span
    unsigned short* wo_bf = wq_bf + 589824;
    unsigned short* w1_bf = wo_bf + 196608;
    unsigned short* w2_bf = w1_bf + 786432;
    unsigned short* win_bf = w2_bf + 786432;  // 16384
    unsigned short* S_bf   = win_bf + 16384;  // 131072 (sinusoid table)
    unsigned short* w256_bf = S_bf + 131072;  // 65536

    setup_kernel<<<4708, 256, 0, stream>>>(
        attn_Wqkv, wq_bf, attn_Wo, wo_bf, ff_W1, w1_bf, ff_W2, w2_bf,
        W_in, win_bf, pe_proj_W, w256_bf, W20t, x, xb_bf, S_bf);
    gemm_bf16_kernel<<<dim3(4, 4), 256, 0, stream>>>(
        S_bf, w256_bf, pe_proj_b, PEpos, nullptr, 512, 256, 256);
    gemm_bf16_kernel<<<dim3(4, 128), 256, 0, stream>>>(
        xb_bf, win_bf, b_in, bbf, lengths, 16384, 256, 64);
    prep_lite_kernel<<<2048, 256, 0, stream>>>(
        c_local, c_sink, bbf, cls_token, PEpos, W20t,
        pe_ln_g, pe_ln_b, pe_gain, corr_fl, lengths, ln1_g, ln1_b,
        h, clb, csfb, padfb, u_bf);

    for (int l = 0; l < 3; ++l) {
        const bool last = (l == 2);
        gemm64_kernel<0><<<dim3(6, 256), 256, 0, stream>>>(
            u_bf, wq_bf + (size_t)l * 196608, attn_bqkv + 768 * l, lengths, 511,
            Q_bf, K_bf, V_bf, 16384, 768, 256);
        attn_mfma_kernel<<<2048, 256, 0, stream>>>(
            Q_bf, K_bf, V_bf, clb, csfb, padfb, alpha, beta, lengths,
            last ? 63 : 511, o_bf);
        gemm_res_ln_kernel<0><<<512, 512, 0, stream>>>(
            o_bf, wo_bf + (size_t)l * 65536, attn_bo + 256 * l, h,
            ln2_g + 256 * l, ln2_b + 256 * l, lengths, last ? 63 : 511,
            u_bf, nullptr, 256);
        gemm64_kernel<2><<<dim3(8, 256), 256, 0, stream>>>(
            u_bf, w1_bf + (size_t)l * 262144, ff_b1 + 1024 * l, lengths,
            last ? 63 : 511, f_bf, nullptr, nullptr, 16384, 1024, 256);
        if (l < 2) {
            gemm_res_ln_kernel<0><<<512, 512, 0, stream>>>(
                f_bf, w2_bf + (size_t)l * 262144, ff_b2 + 256 * l, h,
                ln1_g + 256 * (l + 1), ln1_b + 256 * (l + 1), lengths, 511,
                u_bf, nullptr, 1024);
        } else {
            gemm_res_ln_kernel<1><<<512, 512, 0, stream>>>(
                f_bf, w2_bf + (size_t)l * 262144, ff_b2 + 256 * l, h,
                out_ln_g, out_ln_b, lengths, 0, nullptr, out, 1024);
        }
    }
}

// Round 19
// 320.382 us; speedup vs baseline: 1.2407x; 1.0013x over previous
//
#include <hip/hip_runtime.h>
#include <math.h>

// B=32, L=512 (incl CLS), D=256, H=8, dh=32, N_LAYERS=3, D_FF=1024, tokens=16384
// Length-aware + layer-2 liveness-trimmed: output is CLS-only, so layer-2
// work is back-propagated to the tiles that can reach it (qlim predicates).

typedef __attribute__((ext_vector_type(4))) float f32x4;
typedef __attribute__((ext_vector_type(8))) short bf16x8;

__device__ __forceinline__ unsigned short f2bf(float f) {
    unsigned u = __builtin_bit_cast(unsigned, f);
    u += 0x7fff + ((u >> 16) & 1);
    return (unsigned short)(u >> 16);
}
__device__ __forceinline__ unsigned cvt_pk_bf16(float a, float b) {
    unsigned r;
    asm("v_cvt_pk_bf16_f32 %0, %1, %2" : "=v"(r) : "v"(a), "v"(b));
    return r;
}
__device__ __forceinline__ float gelu_f(float v) {
    return v * 0.5f * (1.0f + erff(v * 0.70710678118654752f));
}
__device__ __forceinline__ void gload16(const void* g, void* l) {
    __builtin_amdgcn_global_load_lds(
        (const __attribute__((address_space(1))) unsigned int*)g,
        (__attribute__((address_space(3))) unsigned int*)l, 16, 0, 0);
}

// ---------------------------------------------------------------------------
// Mega setup kernel: all weight cvts + pe transposes + sinusoid + xb.
__global__ __launch_bounds__(256) void setup_kernel(
    const float* __restrict__ wq, unsigned short* __restrict__ wq_o,   // 576
    const float* __restrict__ wo, unsigned short* __restrict__ wo_o,   // 192
    const float* __restrict__ w1, unsigned short* __restrict__ w1_o,   // 768
    const float* __restrict__ w2, unsigned short* __restrict__ w2_o,   // 768
    const float* __restrict__ win, unsigned short* __restrict__ win_o, // 16
    const float* __restrict__ peW, unsigned short* __restrict__ w256,  // 64
    float* __restrict__ W20t,                                          // 20
    const float* __restrict__ x, unsigned short* __restrict__ xb,      // 2048
    unsigned short* __restrict__ S)                                    // 256
{
    int blk = blockIdx.x, t = threadIdx.x;
    if (blk < 2304) {  // plain f32->bf16 cvts
        const float* s; unsigned short* d; int base;
        if (blk < 576)       { s = wq; d = wq_o; base = blk; }
        else if (blk < 768)  { s = wo; d = wo_o; base = blk - 576; }
        else if (blk < 1536) { s = w1; d = w1_o; base = blk - 768; }
        else                 { s = w2; d = w2_o; base = blk - 1536; }
        int i = (base * 256 + t) * 4;
        float4 v = *(const float4*)(s + i);
        unsigned long long pk = (unsigned long long)f2bf(v.x)
            | ((unsigned long long)f2bf(v.y) << 16)
            | ((unsigned long long)f2bf(v.z) << 32)
            | ((unsigned long long)f2bf(v.w) << 48);
        *(unsigned long long*)(d + i) = pk;
    } else if (blk < 2320) {  // win
        int i = ((blk - 2304) * 256 + t) * 4;
        float4 v = *(const float4*)(win + i);
        unsigned long long pk = (unsigned long long)f2bf(v.x)
            | ((unsigned long long)f2bf(v.y) << 16)
            | ((unsigned long long)f2bf(v.z) << 32)
            | ((unsigned long long)f2bf(v.w) << 48);
        *(unsigned long long*)(win_o + i) = pk;
    } else if (blk < 2384) {  // peW first-256 feats -> bf16 [256][256]
        int i = ((blk - 2320) * 256 + t) * 4;
        int d = i >> 8, f = i & 255;
        float4 v = *(const float4*)(peW + d * 276 + f);
        unsigned long long pk = (unsigned long long)f2bf(v.x)
            | ((unsigned long long)f2bf(v.y) << 16)
            | ((unsigned long long)f2bf(v.z) << 32)
            | ((unsigned long long)f2bf(v.w) << 48);
        *(unsigned long long*)(w256 + i) = pk;
    } else if (blk < 2404) {  // W20t[f][d] = peW[d][256+f]
        int j = (blk - 2384) * 256 + t;
        int f = j >> 8, dd = j & 255;
        W20t[j] = peW[dd * 276 + 256 + f];
    } else if (blk < 4452) {  // xb
        int idx = (blk - 2404) * 256 + t;
        int tok = idx >> 5, c2 = idx & 31;
        int b = tok >> 9, l = tok & 511;
        unsigned r = 0;
        if (l > 0) {
            float2 v = *(const float2*)(x + ((size_t)b * 511 + l - 1) * 64 + 2 * c2);
            r = cvt_pk_bf16(v.x, v.y);
        }
        *(unsigned*)(xb + (size_t)tok * 64 + 2 * c2) = r;
    } else {  // sinusoid table
        int p = (blk - 4452) * 256 + t;
        int l = p >> 7, k = p & 127;
        float div = expf((float)(2 * k) * -0.035977892078032f);
        float a = (float)l * div;
        *(unsigned*)(S + l * 256 + 2 * k) = cvt_pk_bf16(sinf(a), cosf(a));
    }
}

// ---------------------------------------------------------------------------
// prep_lite: arrays for ALL tokens; h/u only for live 8-row groups.
__global__ __launch_bounds__(256) void prep_lite_kernel(
    const float* __restrict__ c_local, const float* __restrict__ c_sink,
    const float* __restrict__ bb, const float* __restrict__ cls_tok,
    const float* __restrict__ PEpos, const float* __restrict__ W20t,
    const float* __restrict__ pe_g, const float* __restrict__ pe_bb,
    const float* __restrict__ pe_gain_p, const float* __restrict__ corr_floor_p,
    const int* __restrict__ lengths, const float* __restrict__ ln1g,
    const float* __restrict__ ln1b,
    float* __restrict__ h, float* __restrict__ clb, float* __restrict__ csfb,
    float* __restrict__ padfb, unsigned short* __restrict__ u)
{
    __shared__ float zs[8][20];
    __shared__ __align__(16) float pes[8][256];
    __shared__ float mn[8], rsd[8];
    const int t = threadIdx.x;
    const int tok0 = blockIdx.x * 8;
    const int b = tok0 >> 9;
    const int len_b = lengths[b];
    const float cf = *corr_floor_p;
    const float gain = *pe_gain_p;

    float clv[8], csv[8];
    bool mk[8];
#pragma unroll
    for (int k = 0; k < 8; ++k) {
        int l = (tok0 + k) & 511;
        if (l == 0) { clv[k] = 1.f; csv[k] = 1.f; mk[k] = false; }
        else {
            float a = c_local[b * 511 + l - 1];
            float s = c_sink[b * 511 + l - 1];
            clv[k] = fminf(fmaxf(a, 0.f), 1.f);
            csv[k] = fminf(fmaxf(s, 0.f), 1.f);
            mk[k] = (l - 1) >= len_b;
        }
    }
    if (t < 8) {
        int tok = tok0 + t;
        clb[tok] = clv[t];
        csfb[tok] = cf + (1.f - cf) * csv[t];
        padfb[tok] = mk[t] ? 1.f : 0.f;
    }
    // dead group: mask arrays written above are all that's needed
    if ((tok0 & 511) > len_b) return;
    if (t < 20) {
#pragma unroll
        for (int k = 0; k < 8; ++k) {
            float cl = clv[k], cs = csv[k];
            float v;
            if (t == 0) v = cl;
            else if (t == 1) v = cs;
            else if (t == 2) v = cl * cs;
            else if (t == 3) v = fabsf(cl - cs);
            else if (t < 12) {
                float c = (float)(t - 4) * (1.f / 7.f);
                float dd = (cl - c) / 0.200001f;
                v = expf(-0.5f * dd * dd);
            } else {
                float c = (float)(t - 12) * (1.f / 7.f);
                float dd = (cs - c) / 0.200001f;
                v = expf(-0.5f * dd * dd);
            }
            zs[k][t] = v;
        }
    }
    __syncthreads();

    float acc[8];
#pragma unroll
    for (int k = 0; k < 8; ++k)
        acc[k] = PEpos[((tok0 + k) & 511) * 256 + t];
    for (int f = 0; f < 20; ++f) {
        float wv = W20t[f * 256 + t];
#pragma unroll
        for (int k = 0; k < 8; ++k) acc[k] += zs[k][f] * wv;
    }
#pragma unroll
    for (int k = 0; k < 8; ++k) pes[k][t] = acc[k];
    __syncthreads();

    {
        int w = t >> 6, lane = t & 63;
#pragma unroll
        for (int p = 0; p < 2; ++p) {
            int k = w + p * 4;
            float4 v = *(const float4*)&pes[k][lane * 4];
            float s = v.x + v.y + v.z + v.w;
            float sq = v.x * v.x + v.y * v.y + v.z * v.z + v.w * v.w;
#pragma unroll
            for (int off = 32; off; off >>= 1) {
                s += __shfl_xor(s, off);
                sq += __shfl_xor(sq, off);
            }
            if (lane == 0) {
                float mean = s * (1.f / 256.f);
                mn[k] = mean;
                rsd[k] = rsqrtf(sq * (1.f / 256.f) - mean * mean + 1e-5f);
            }
        }
    }
    __syncthreads();
    float gv = pe_g[t], bv = pe_bb[t];
    float hv[8];
#pragma unroll
    for (int k = 0; k < 8; ++k) {
        int l = (tok0 + k) & 511;
        float base = (l == 0) ? cls_tok[t] : bb[(size_t)(tok0 + k) * 256 + t];
        float pe = (pes[k][t] - mn[k]) * rsd[k] * gv + bv;
        pe *= gain;
        if (mk[k]) pe = 0.f;
        hv[k] = base + pe;
        h[(size_t)(tok0 + k) * 256 + t] = hv[k];
    }
    __syncthreads();
#pragma unroll
    for (int k = 0; k < 8; ++k) pes[k][t] = hv[k];
    __syncthreads();
    {
        int w = t >> 6, lane = t & 63;
#pragma unroll
        for (int p = 0; p < 2; ++p) {
            int k = w + p * 4;
            float4 v = *(const float4*)&pes[k][lane * 4];
            float s = v.x + v.y + v.z + v.w;
            float sq = v.x * v.x + v.y * v.y + v.z * v.z + v.w * v.w;
#pragma unroll
            for (int off = 32; off; off >>= 1) {
                s += __shfl_xor(s, off);
                sq += __shfl_xor(sq, off);
            }
            if (lane == 0) {
                float mean = s * (1.f / 256.f);
                mn[k] = mean;
                rsd[k] = rsqrtf(sq * (1.f / 256.f) - mean * mean + 1e-5f);
            }
        }
    }
    __syncthreads();
    float g1 = ln1g[t], b1 = ln1b[t];
#pragma unroll
    for (int k = 0; k < 8; ++k)
        u[(size_t)(tok0 + k) * 256 + t] = f2bf((hv[k] - mn[k]) * rsd[k] * g1 + b1);
}

// ---------------------------------------------------------------------------
// bf16 MFMA GEMM, 128x64 tile (proven): C[M,N] = A @ W^T + bias (f32 store).
// Optional length-skip (lengths != nullptr, 128-aligned M tiles).
__global__ __launch_bounds__(256) void gemm_bf16_kernel(
    const unsigned short* __restrict__ A, const unsigned short* __restrict__ W,
    const float* __restrict__ bias, float* __restrict__ hres,
    const int* __restrict__ lengths, int M, int N, int K)
{
    __shared__ __align__(16) unsigned short As[128 * 64];
    __shared__ __align__(16) unsigned short Bs[64 * 64];
    const int m0 = blockIdx.y * 128, n0 = blockIdx.x * 64;
    if (lengths && (m0 & 511) > lengths[m0 >> 9]) return;
    const int t = threadIdx.x;
    const int wid = t >> 6, lane = t & 63;
    const int lo = lane & 15, hi = lane >> 4;
    const int wm = wid >> 1, wn = wid & 1;
    const int lrow = lane >> 3, lc = lane & 7;
    f32x4 acc[4][2] = {};
    for (int k0 = 0; k0 < K; k0 += 64) {
        __syncthreads();
#pragma unroll
        for (int is = 0; is < 4; ++is) {
            int r = wid * 32 + is * 8 + lrow;
            const unsigned short* g = A + (size_t)(m0 + r) * K + k0 + ((lc ^ (r & 7)) * 8);
            gload16(g, &As[(wid * 32 + is * 8) * 64]);
        }
#pragma unroll
        for (int is = 0; is < 2; ++is) {
            int r = wid * 16 + is * 8 + lrow;
            const unsigned short* g = W + (size_t)(n0 + r) * K + k0 + ((lc ^ (r & 7)) * 8);
            gload16(g, &Bs[(wid * 16 + is * 8) * 64]);
        }
        __syncthreads();
#pragma unroll
        for (int kh = 0; kh < 2; ++kh) {
            bf16x8 bfr[2];
#pragma unroll
            for (int nf = 0; nf < 2; ++nf) {
                int r = wn * 32 + nf * 16 + lo;
                bfr[nf] = *(const bf16x8*)&Bs[r * 64 + (((kh * 4 + hi) ^ (r & 7)) * 8)];
            }
#pragma unroll
            for (int mf = 0; mf < 4; ++mf) {
                int r = wm * 64 + mf * 16 + lo;
                bf16x8 afr = *(const bf16x8*)&As[r * 64 + (((kh * 4 + hi) ^ (r & 7)) * 8)];
                acc[mf][0] = __builtin_amdgcn_mfma_f32_16x16x32_bf16(afr, bfr[0], acc[mf][0], 0, 0, 0);
                acc[mf][1] = __builtin_amdgcn_mfma_f32_16x16x32_bf16(afr, bfr[1], acc[mf][1], 0, 0, 0);
            }
        }
    }
#pragma unroll
    for (int mf = 0; mf < 4; ++mf) {
        const int mbase = m0 + wm * 64 + mf * 16 + hi * 4;
#pragma unroll
        for (int nf = 0; nf < 2; ++nf) {
            const int n = n0 + wn * 32 + nf * 16 + lo;
            const float bv = bias[n];
            f32x4 v = acc[mf][nf];
#pragma unroll
            for (int rg = 0; rg < 4; ++rg)
                hres[(size_t)(mbase + rg) * N + n] = v[rg] + bv;
        }
    }
}

// ---------------------------------------------------------------------------
// bf16 MFMA GEMM, 64x128 tile: QKV (EPI=0), FF1 GELU (EPI=2).
// Skip when (m0&511) > min(lengths[b], lim), where lim is qlimQ for Q-column
// tiles (n0<256, EPI=0 only) and qlim otherwise.
template <int EPI>
__global__ __launch_bounds__(256) void gemm64_kernel(
    const unsigned short* __restrict__ A, const unsigned short* __restrict__ W,
    const float* __restrict__ bias, const int* __restrict__ lengths,
    int qlim, int qlimQ,
    unsigned short* __restrict__ o0, unsigned short* __restrict__ o1,
    unsigned short* __restrict__ o2, int M, int N, int K)
{
    __shared__ __align__(16) unsigned short As[64 * 64];
    __shared__ __align__(16) unsigned short Bs[128 * 64];
    const int m0 = blockIdx.y * 64, n0 = blockIdx.x * 128;
    const int lim = (EPI == 0 && n0 < 256) ? qlimQ : qlim;
    if ((m0 & 511) > min(lengths[m0 >> 9], lim)) return;   // dead tile
    const int t = threadIdx.x;
    const int wid = t >> 6, lane = t & 63;
    const int lo = lane & 15, hi = lane >> 4;
    const int wm = wid >> 1, wn = wid & 1;
    const int lrow = lane >> 3, lc = lane & 7;
    f32x4 acc[2][4] = {};
    for (int k0 = 0; k0 < K; k0 += 64) {
        __syncthreads();
#pragma unroll
        for (int is = 0; is < 2; ++is) {
            int r = wid * 16 + is * 8 + lrow;
            const unsigned short* g = A + (size_t)(m0 + r) * K + k0 + ((lc ^ (r & 7)) * 8);
            gload16(g, &As[(wid * 16 + is * 8) * 64]);
        }
#pragma unroll
        for (int is = 0; is < 4; ++is) {
            int r = wid * 32 + is * 8 + lrow;
            const unsigned short* g = W + (size_t)(n0 + r) * K + k0 + ((lc ^ (r & 7)) * 8);
            gload16(g, &Bs[(wid * 32 + is * 8) * 64]);
        }
        __syncthreads();
#pragma unroll
        for (int kh = 0; kh < 2; ++kh) {
            bf16x8 bfr[4];
#pragma unroll
            for (int nf = 0; nf < 4; ++nf) {
                int r = wn * 64 + nf * 16 + lo;
                bfr[nf] = *(const bf16x8*)&Bs[r * 64 + (((kh * 4 + hi) ^ (r & 7)) * 8)];
            }
#pragma unroll
            for (int mf = 0; mf < 2; ++mf) {
                int r = wm * 32 + mf * 16 + lo;
                bf16x8 afr = *(const bf16x8*)&As[r * 64 + (((kh * 4 + hi) ^ (r & 7)) * 8)];
#pragma unroll
                for (int nf = 0; nf < 4; ++nf)
                    acc[mf][nf] = __builtin_amdgcn_mfma_f32_16x16x32_bf16(afr, bfr[nf], acc[mf][nf], 0, 0, 0);
            }
        }
    }
#pragma unroll
    for (int mf = 0; mf < 2; ++mf) {
        const int mbase = m0 + wm * 32 + mf * 16 + hi * 4;
#pragma unroll
        for (int nf = 0; nf < 4; ++nf) {
            const int n = n0 + wn * 64 + nf * 16 + lo;
            const float bv = bias[n];
            f32x4 v = acc[mf][nf];
            if constexpr (EPI == 0) {
                unsigned short* dst = (n < 256) ? o0 : ((n < 512) ? o1 : o2);
                const float qsc = (n < 256)
                    ? (0.17677669529663687f * 1.4426950408889634f) : 1.f;
                const int c = n & 255;
#pragma unroll
                for (int rg = 0; rg < 4; ++rg)
                    dst[(size_t)(mbase + rg) * 256 + c] = f2bf((v[rg] + bv) * qsc);
            } else {
#pragma unroll
                for (int rg = 0; rg < 4; ++rg)
                    o0[(size_t)(mbase + rg) * N + n] = f2bf(gelu_f(v[rg] + bv));
            }
        }
    }
}

// ---------------------------------------------------------------------------
// Fused residual-GEMM + LayerNorm (proven 32x256 tile), length+qlim aware.
// OUT=0: h += GEMM; u = LN(h).  OUT=1: final FF2 -> out-LN CLS rows only.
template <int OUT>
__global__ __launch_bounds__(512) void gemm_res_ln_kernel(
    const unsigned short* __restrict__ A, const unsigned short* __restrict__ W,
    const float* __restrict__ bias, float* __restrict__ hres,
    const float* __restrict__ g, const float* __restrict__ bvec,
    const int* __restrict__ lengths, int qlim,
    unsigned short* __restrict__ u, float* __restrict__ outp, int K)
{
    __shared__ __align__(16) unsigned short As[32 * 64];
    __shared__ __align__(16) unsigned short Bs[256 * 64];
    __shared__ float red[32][4][2];
    const int m0 = blockIdx.x * 32;
    if ((m0 & 511) > min(lengths[m0 >> 9], qlim)) return;   // dead tile
    const int t = threadIdx.x;
    const int wid = t >> 6, lane = t & 63;
    const int lo = lane & 15, hi = lane >> 4;
    const int wm = wid >> 2, wn = wid & 3;
    const int lrow = lane >> 3, lc = lane & 7;
    f32x4 acc[4] = {};
    for (int k0 = 0; k0 < K; k0 += 64) {
        __syncthreads();
        if (wid < 4) {
            int r = wid * 8 + lrow;
            gload16(A + (size_t)(m0 + r) * K + k0 + ((lc ^ (r & 7)) * 8),
                    &As[(wid * 8) * 64]);
        }
#pragma unroll
        for (int is = 0; is < 4; ++is) {
            int r = wid * 32 + is * 8 + lrow;
            gload16(W + (size_t)r * K + k0 + ((lc ^ (r & 7)) * 8),
                    &Bs[(wid * 32 + is * 8) * 64]);
        }
        __syncthreads();
#pragma unroll
        for (int kh = 0; kh < 2; ++kh) {
            bf16x8 bfr[4];
#pragma unroll
            for (int nf = 0; nf < 4; ++nf) {
                int r = wn * 64 + nf * 16 + lo;
                bfr[nf] = *(const bf16x8*)&Bs[r * 64 + (((kh * 4 + hi) ^ (r & 7)) * 8)];
            }
            {
                int r = wm * 16 + lo;
                bf16x8 afr = *(const bf16x8*)&As[r * 64 + (((kh * 4 + hi) ^ (r & 7)) * 8)];
#pragma unroll
                for (int nf = 0; nf < 4; ++nf)
                    acc[nf] = __builtin_amdgcn_mfma_f32_16x16x32_bf16(afr, bfr[nf], acc[nf], 0, 0, 0);
            }
        }
    }
#pragma unroll
    for (int nf = 0; nf < 4; ++nf) {
        const int n = wn * 64 + nf * 16 + lo;
        const float bv = bias[n];
        const int rbase = m0 + wm * 16 + hi * 4;
#pragma unroll
        for (int rg = 0; rg < 4; ++rg) {
            size_t idx = (size_t)(rbase + rg) * 256 + n;
            float hv = acc[nf][rg] + bv + hres[idx];
            if constexpr (OUT == 0) hres[idx] = hv;
            acc[nf][rg] = hv;
        }
    }
#pragma unroll
    for (int rg = 0; rg < 4; ++rg) {
        float s = ((acc[0][rg] + acc[1][rg]) + (acc[2][rg] + acc[3][rg]));
        float sq = ((acc[0][rg] * acc[0][rg] + acc[1][rg] * acc[1][rg]) +
                    (acc[2][rg] * acc[2][rg] + acc[3][rg] * acc[3][rg]));
#pragma unroll
        for (int off = 1; off < 16; off <<= 1) {
            s += __shfl_xor(s, off);
            sq += __shfl_xor(sq, off);
        }
        if (lo == 0) {
            int rl = wm * 16 + hi * 4 + rg;
            red[rl][wn][0] = s;
            red[rl][wn][1] = sq;
        }
    }
    __syncthreads();
#pragma unroll
    for (int rg = 0; rg < 4; ++rg) {
        const int rl = wm * 16 + hi * 4 + rg;
        float s = (red[rl][0][0] + red[rl][1][0]) + (red[rl][2][0] + red[rl][3][0]);
        float sq = (red[rl][0][1] + red[rl][1][1]) + (red[rl][2][1] + red[rl][3][1]);
        float mean = s * (1.f / 256.f);
        float rs = rsqrtf(sq * (1.f / 256.f) - mean * mean + 1e-5f);
        if constexpr (OUT == 1) {
            const int row = m0 + rl;
            if ((row & 511) == 0) {
#pragma unroll
                for (int nf = 0; nf < 4; ++nf) {
                    const int n = wn * 64 + nf * 16 + lo;
                    outp[(size_t)(row >> 9) * 256 + n] =
                        (acc[nf][rg] - mean) * rs * g[n] + bvec[n];
                }
            }
        } else {
#pragma unroll
            for (int nf = 0; nf < 4; ++nf) {
                const int n = wn * 64 + nf * 16 + lo;
                u[(size_t)(m0 + rl) * 256 + n] =
                    f2bf((acc[nf][rg] - mean) * rs * g[n] + bvec[n]);
            }
        }
    }
}

// ---------------------------------------------------------------------------
// MFMA flash attention (proven round-15/17 structure) + qlim q-tile trim.
__global__ __launch_bounds__(256) void attn_mfma_kernel(
    const unsigned short* __restrict__ Qb, const unsigned short* __restrict__ Kb,
    const unsigned short* __restrict__ Vb, const float* __restrict__ clb,
    const float* __restrict__ csfb, const float* __restrict__ padfb,
    const float* __restrict__ alpha_p, const float* __restrict__ beta_p,
    const int* __restrict__ lengths, int qlim, unsigned short* __restrict__ Ob)
{
    __shared__ __align__(16) unsigned short Kl[128 * 40];   // 10240 B
    __shared__ __align__(16) unsigned short Vt[32 * 132];   // 8448 B
    __shared__ __align__(16) float csfj[128];               // 512 B
    const int t = threadIdx.x;
    const int swz = ((blockIdx.x & 7) << 8) | (blockIdx.x >> 3);  // XCD chunking
    const int bh = swz >> 3, hf = swz & 7;
    const int b = bh >> 3, hd = bh & 7;
    const int len_b = lengths[b];
    if (hf * 64 > min(len_b, qlim)) return;      // dead q-tile
    const int njt = (len_b + 128) >> 7;          // ceil((len_b+1)/128)
    const size_t base = ((size_t)b * 512) * 256 + hd * 32;
    const int w = t >> 6, lane = t & 63, lo = lane & 15, hi = lane >> 4;
    const float L2E = 1.4426950408889634f;
    const float kb = L2E * (*beta_p);
    const float ka = L2E * (*alpha_p);
    const float* clg = clb + b * 512;

    const int i0 = (hf * 4 + w) * 16;
    const int iq = i0 + lo;
    const bf16x8 qf = *(const bf16x8*)(Qb + base + (size_t)iq * 256 + hi * 8);
    const float csb = fmaxf(kb * csfb[b * 512 + iq], 1e-3f);
    f32x4 acc0 = {0.f, 0.f, 0.f, 0.f}, acc1 = {0.f, 0.f, 0.f, 0.f};
    float lsum = 0.f;

    for (int jt = 0; jt < njt; ++jt) {
        __syncthreads();
        for (int idx = t; idx < 512; idx += 256) {       // K tile: 128 rows
            int row = idx >> 2, c4 = idx & 3;
            *(uint4*)&Kl[row * 40 + c4 * 8] =
                *(const uint4*)(Kb + base + (size_t)(jt * 128 + row) * 256 + c4 * 8);
        }
        for (int idx = t; idx < 512; idx += 256) {       // V^T via v_perm
            int pr = idx & 63, c4 = idx >> 6;
            const unsigned* vp0 = (const unsigned*)
                (Vb + base + (size_t)(jt * 128 + 2 * pr) * 256 + c4 * 4);
            const unsigned* vp1 = (const unsigned*)
                (Vb + base + (size_t)(jt * 128 + 2 * pr + 1) * 256 + c4 * 4);
            unsigned v0lo = vp0[0], v0hi = vp0[1];
            unsigned v1lo = vp1[0], v1hi = vp1[1];
            *(unsigned*)&Vt[(c4 * 4 + 0) * 132 + 2 * pr] =
                __builtin_amdgcn_perm(v1lo, v0lo, 0x05040100u);
            *(unsigned*)&Vt[(c4 * 4 + 1) * 132 + 2 * pr] =
                __builtin_amdgcn_perm(v1lo, v0lo, 0x07060302u);
            *(unsigned*)&Vt[(c4 * 4 + 2) * 132 + 2 * pr] =
                __builtin_amdgcn_perm(v1hi, v0hi, 0x05040100u);
            *(unsigned*)&Vt[(c4 * 4 + 3) * 132 + 2 * pr] =
                __builtin_amdgcn_perm(v1hi, v0hi, 0x07060302u);
        }
        if (t < 128) {                                   // csf with pad folded
            int j = jt * 128 + t;
            float cv = csfb[b * 512 + j];
            csfj[t] = (padfb[b * 512 + j] > 0.5f) ? -100000.f : cv;
        }
        __syncthreads();
#pragma unroll
        for (int ktp = 0; ktp < 4; ++ktp) {
            const int k16 = ktp * 32;             // local j base
            const int gj = jt * 128 + k16;        // global j base
            bf16x8 kf0 = *(const bf16x8*)&Kl[(k16 + lo) * 40 + hi * 8];
            bf16x8 kf1 = *(const bf16x8*)&Kl[(k16 + 16 + lo) * 40 + hi * 8];
            union U16 { unsigned long long q[2]; unsigned wd[4]; bf16x8 v; } vu0, vu1, pu;
            vu0.q[0] = *(const unsigned long long*)&Vt[lo * 132 + k16 + hi * 4];
            vu0.q[1] = *(const unsigned long long*)&Vt[lo * 132 + k16 + 16 + hi * 4];
            vu1.q[0] = *(const unsigned long long*)&Vt[(16 + lo) * 132 + k16 + hi * 4];
            vu1.q[1] = *(const unsigned long long*)&Vt[(16 + lo) * 132 + k16 + 16 + hi * 4];
            f32x4 csf0 = *(const f32x4*)&csfj[k16 + hi * 4];
            f32x4 csf1 = *(const f32x4*)&csfj[k16 + 16 + hi * 4];
            f32x4 c0, c1;
#pragma unroll
            for (int e = 0; e < 4; ++e) {
                c0[e] = csb * csf0[e];
                c1[e] = csb * csf1[e];
            }
            f32x4 s0 = __builtin_amdgcn_mfma_f32_16x16x32_bf16(kf0, qf, c0, 0, 0, 0);
            f32x4 s1 = __builtin_amdgcn_mfma_f32_16x16x32_bf16(kf1, qf, c1, 0, 0, 0);
            float p[8];
#pragma unroll
            for (int r = 0; r < 4; ++r) p[r] = exp2f(s0[r]);
#pragma unroll
            for (int r = 0; r < 4; ++r) p[4 + r] = exp2f(s1[r]);
            if (gj <= i0 + 16 && gj + 32 >= i0) {
#pragma unroll
                for (int r = 0; r < 8; ++r) {
                    int jr = gj + ((r & 4) ? 16 : 0) + hi * 4 + (r & 3);
                    int dij = jr - iq;
                    if (dij == 1 || dij == -1) {
                        float ce = (jr >= 1 && iq <= 510) ? clg[jr] : clg[iq];
                        p[r] *= exp2f(ka * ce);
                    }
                }
            }
            lsum += ((p[0] + p[1]) + (p[2] + p[3])) + ((p[4] + p[5]) + (p[6] + p[7]));
            pu.wd[0] = cvt_pk_bf16(p[0], p[1]);
            pu.wd[1] = cvt_pk_bf16(p[2], p[3]);
            pu.wd[2] = cvt_pk_bf16(p[4], p[5]);
            pu.wd[3] = cvt_pk_bf16(p[6], p[7]);
            acc0 = __builtin_amdgcn_mfma_f32_16x16x32_bf16(vu0.v, pu.v, acc0, 0, 0, 0);
            acc1 = __builtin_amdgcn_mfma_f32_16x16x32_bf16(vu1.v, pu.v, acc1, 0, 0, 0);
        }
    }
    {
        float ls = lsum;
        ls += __shfl_xor(ls, 16);
        ls += __shfl_xor(ls, 32);
        const float inv = 1.f / fmaxf(ls, 1e-35f);
        unsigned long long oa =
              (unsigned long long)cvt_pk_bf16(acc0[0] * inv, acc0[1] * inv)
            | ((unsigned long long)cvt_pk_bf16(acc0[2] * inv, acc0[3] * inv) << 32);
        unsigned long long ob2 =
              (unsigned long long)cvt_pk_bf16(acc1[0] * inv, acc1[1] * inv)
            | ((unsigned long long)cvt_pk_bf16(acc1[2] * inv, acc1[3] * inv) << 32);
        *(unsigned long long*)(Ob + base + (size_t)iq * 256 + hi * 4) = oa;
        *(unsigned long long*)(Ob + base + (size_t)iq * 256 + 16 + hi * 4) = ob2;
    }
}

// ---------------------------------------------------------------------------
extern "C" void kernel_launch(void* const* d_in, const int* in_sizes, int n_in,
                              void* d_out, int out_size, void* d_ws, size_t ws_size,
                              hipStream_t stream) {
    const float* x         = (const float*)d_in[0];
    const float* c_local   = (const float*)d_in[1];
    const float* c_sink    = (const float*)d_in[2];
    const float* W_in      = (const float*)d_in[3];
    const float* b_in      = (const float*)d_in[4];
    const float* cls_token = (const float*)d_in[5];
    const float* pe_proj_W = (const float*)d_in[6];
    const float* pe_proj_b = (const float*)d_in[7];
    const float* pe_ln_g   = (const float*)d_in[8];
    const float* pe_ln_b   = (const float*)d_in[9];
    const float* pe_gain   = (const float*)d_in[10];
    const float* attn_Wqkv = (const float*)d_in[11];
    const float* attn_bqkv = (const float*)d_in[12];
    const float* attn_Wo   = (const float*)d_in[13];
    const float* attn_bo   = (const float*)d_in[14];
    const float* ff_W1     = (const float*)d_in[15];
    const float* ff_b1     = (const float*)d_in[16];
    const float* ff_W2     = (const float*)d_in[17];
    const float* ff_b2     = (const float*)d_in[18];
    const float* ln1_g     = (const float*)d_in[19];
    const float* ln1_b     = (const float*)d_in[20];
    const float* ln2_g     = (const float*)d_in[21];
    const float* ln2_b     = (const float*)d_in[22];
    const float* alpha     = (const float*)d_in[23];
    const float* beta      = (const float*)d_in[24];
    const float* corr_fl   = (const float*)d_in[25];
    const float* out_ln_g  = (const float*)d_in[26];
    const float* out_ln_b  = (const float*)d_in[27];
    const int*   lengths   = (const int*)d_in[28];
    float* out = (float*)d_out;

    // float region (same slots as round-18 passing layout)
    float* h     = (float*)d_ws;              // 4,194,304
    float* clb   = h + 4194304;               // 16384
    float* csfb  = clb + 16384;
    float* padfb = csfb + 16384;
    float* W20t  = padfb + 16384;             // 5120 (in old peWt slot)
    float* PEpos = W20t + 70656;              // 131072
    float* bbf   = PEpos + 131072;            // old 8,388,608-float region
    // bf16 region — weights AFTER the full 16,777,216-short f-span at Q_bf
    unsigned short* u_bf = (unsigned short*)(bbf + 8388608);
    unsigned short* xb_bf = u_bf;             // alias: xb dead before layer loop
    unsigned short* Q_bf = u_bf + 4194304;
    unsigned short* K_bf = Q_bf + 4194304;
    unsigned short* V_bf = K_bf + 4194304;
    unsigned short* f_bf = Q_bf;              // alias: spans Q..Q+16777216
    unsigned short* o_bf = u_bf;              // alias (lifetimes disjoint)
    unsigned short* wq_bf = Q_bf + 16777216;  // after f's span
    unsigned short* wo_bf = wq_bf + 589824;
    unsigned short* w1_bf = wo_bf + 196608;
    unsigned short* w2_bf = w1_bf + 786432;
    unsigned short* win_bf = w2_bf + 786432;  // 16384
    unsigned short* S_bf   = win_bf + 16384;  // 131072 (sinusoid table)
    unsigned short* w256_bf = S_bf + 131072;  // 65536

    setup_kernel<<<4708, 256, 0, stream>>>(
        attn_Wqkv, wq_bf, attn_Wo, wo_bf, ff_W1, w1_bf, ff_W2, w2_bf,
        W_in, win_bf, pe_proj_W, w256_bf, W20t, x, xb_bf, S_bf);
    gemm_bf16_kernel<<<dim3(4, 4), 256, 0, stream>>>(
        S_bf, w256_bf, pe_proj_b, PEpos, nullptr, 512, 256, 256);
    gemm_bf16_kernel<<<dim3(4, 128), 256, 0, stream>>>(
        xb_bf, win_bf, b_in, bbf, lengths, 16384, 256, 64);
    prep_lite_kernel<<<2048, 256, 0, stream>>>(
        c_local, c_sink, bbf, cls_token, PEpos, W20t,
        pe_ln_g, pe_ln_b, pe_gain, corr_fl, lengths, ln1_g, ln1_b,
        h, clb, csfb, padfb, u_bf);

    for (int l = 0; l < 3; ++l) {
        const bool last = (l == 2);
        gemm64_kernel<0><<<dim3(6, 256), 256, 0, stream>>>(
            u_bf, wq_bf + (size_t)l * 196608, attn_bqkv + 768 * l, lengths,
            511, last ? 63 : 511, Q_bf, K_bf, V_bf, 16384, 768, 256);
        attn_mfma_kernel<<<2048, 256, 0, stream>>>(
            Q_bf, K_bf, V_bf, clb, csfb, padfb, alpha, beta, lengths,
            last ? 63 : 511, o_bf);
        gemm_res_ln_kernel<0><<<512, 512, 0, stream>>>(
            o_bf, wo_bf + (size_t)l * 65536, attn_bo + 256 * l, h,
            ln2_g + 256 * l, ln2_b + 256 * l, lengths, last ? 63 : 511,
            u_bf, nullptr, 256);
        gemm64_kernel<2><<<dim3(8, 256), 256, 0, stream>>>(
            u_bf, w1_bf + (size_t)l * 262144, ff_b1 + 1024 * l, lengths,
            last ? 63 : 511, 511, f_bf, nullptr, nullptr, 16384, 1024, 256);
        if (l < 2) {
            gemm_res_ln_kernel<0><<<512, 512, 0, stream>>>(
                f_bf, w2_bf + (size_t)l * 262144, ff_b2 + 256 * l, h,
                ln1_g + 256 * (l + 1), ln1_b + 256 * (l + 1), lengths, 511,
                u_bf, nullptr, 1024);
        } else {
            gemm_res_ln_kernel<1><<<512, 512, 0, stream>>>(
                f_bf, w2_bf + (size_t)l * 262144, ff_b2 + 256 * l, h,
                out_ln_g, out_ln_b, lengths, 0, nullptr, out, 1024);
        }
    }
}

// Round 20
// 314.034 us; speedup vs baseline: 1.2657x; 1.0202x over previous
//
#include <hip/hip_runtime.h>
#include <math.h>

// B=32, L=512 (incl CLS), D=256, H=8, dh=32, N_LAYERS=3, D_FF=1024, tokens=16384
// Length-aware + layer-2 liveness-trimmed + attn kv-chunk trim (32-granular).

typedef __attribute__((ext_vector_type(4))) float f32x4;
typedef __attribute__((ext_vector_type(8))) short bf16x8;

__device__ __forceinline__ unsigned short f2bf(float f) {
    unsigned u = __builtin_bit_cast(unsigned, f);
    u += 0x7fff + ((u >> 16) & 1);
    return (unsigned short)(u >> 16);
}
__device__ __forceinline__ unsigned cvt_pk_bf16(float a, float b) {
    unsigned r;
    asm("v_cvt_pk_bf16_f32 %0, %1, %2" : "=v"(r) : "v"(a), "v"(b));
    return r;
}
__device__ __forceinline__ float gelu_f(float v) {
    return v * 0.5f * (1.0f + erff(v * 0.70710678118654752f));
}
__device__ __forceinline__ void gload16(const void* g, void* l) {
    __builtin_amdgcn_global_load_lds(
        (const __attribute__((address_space(1))) unsigned int*)g,
        (__attribute__((address_space(3))) unsigned int*)l, 16, 0, 0);
}

// ---------------------------------------------------------------------------
// Mega setup kernel: all weight cvts + pe transposes + sinusoid + xb.
__global__ __launch_bounds__(256) void setup_kernel(
    const float* __restrict__ wq, unsigned short* __restrict__ wq_o,   // 576
    const float* __restrict__ wo, unsigned short* __restrict__ wo_o,   // 192
    const float* __restrict__ w1, unsigned short* __restrict__ w1_o,   // 768
    const float* __restrict__ w2, unsigned short* __restrict__ w2_o,   // 768
    const float* __restrict__ win, unsigned short* __restrict__ win_o, // 16
    const float* __restrict__ peW, unsigned short* __restrict__ w256,  // 64
    float* __restrict__ W20t,                                          // 20
    const float* __restrict__ x, unsigned short* __restrict__ xb,      // 2048
    unsigned short* __restrict__ S)                                    // 256
{
    int blk = blockIdx.x, t = threadIdx.x;
    if (blk < 2304) {  // plain f32->bf16 cvts
        const float* s; unsigned short* d; int base;
        if (blk < 576)       { s = wq; d = wq_o; base = blk; }
        else if (blk < 768)  { s = wo; d = wo_o; base = blk - 576; }
        else if (blk < 1536) { s = w1; d = w1_o; base = blk - 768; }
        else                 { s = w2; d = w2_o; base = blk - 1536; }
        int i = (base * 256 + t) * 4;
        float4 v = *(const float4*)(s + i);
        unsigned long long pk = (unsigned long long)f2bf(v.x)
            | ((unsigned long long)f2bf(v.y) << 16)
            | ((unsigned long long)f2bf(v.z) << 32)
            | ((unsigned long long)f2bf(v.w) << 48);
        *(unsigned long long*)(d + i) = pk;
    } else if (blk < 2320) {  // win
        int i = ((blk - 2304) * 256 + t) * 4;
        float4 v = *(const float4*)(win + i);
        unsigned long long pk = (unsigned long long)f2bf(v.x)
            | ((unsigned long long)f2bf(v.y) << 16)
            | ((unsigned long long)f2bf(v.z) << 32)
            | ((unsigned long long)f2bf(v.w) << 48);
        *(unsigned long long*)(win_o + i) = pk;
    } else if (blk < 2384) {  // peW first-256 feats -> bf16 [256][256]
        int i = ((blk - 2320) * 256 + t) * 4;
        int d = i >> 8, f = i & 255;
        float4 v = *(const float4*)(peW + d * 276 + f);
        unsigned long long pk = (unsigned long long)f2bf(v.x)
            | ((unsigned long long)f2bf(v.y) << 16)
            | ((unsigned long long)f2bf(v.z) << 32)
            | ((unsigned long long)f2bf(v.w) << 48);
        *(unsigned long long*)(w256 + i) = pk;
    } else if (blk < 2404) {  // W20t[f][d] = peW[d][256+f]
        int j = (blk - 2384) * 256 + t;
        int f = j >> 8, dd = j & 255;
        W20t[j] = peW[dd * 276 + 256 + f];
    } else if (blk < 4452) {  // xb
        int idx = (blk - 2404) * 256 + t;
        int tok = idx >> 5, c2 = idx & 31;
        int b = tok >> 9, l = tok & 511;
        unsigned r = 0;
        if (l > 0) {
            float2 v = *(const float2*)(x + ((size_t)b * 511 + l - 1) * 64 + 2 * c2);
            r = cvt_pk_bf16(v.x, v.y);
        }
        *(unsigned*)(xb + (size_t)tok * 64 + 2 * c2) = r;
    } else {  // sinusoid table
        int p = (blk - 4452) * 256 + t;
        int l = p >> 7, k = p & 127;
        float div = expf((float)(2 * k) * -0.035977892078032f);
        float a = (float)l * div;
        *(unsigned*)(S + l * 256 + 2 * k) = cvt_pk_bf16(sinf(a), cosf(a));
    }
}

// ---------------------------------------------------------------------------
// prep_lite: arrays for ALL tokens; h/u only for live 8-row groups.
__global__ __launch_bounds__(256) void prep_lite_kernel(
    const float* __restrict__ c_local, const float* __restrict__ c_sink,
    const float* __restrict__ bb, const float* __restrict__ cls_tok,
    const float* __restrict__ PEpos, const float* __restrict__ W20t,
    const float* __restrict__ pe_g, const float* __restrict__ pe_bb,
    const float* __restrict__ pe_gain_p, const float* __restrict__ corr_floor_p,
    const int* __restrict__ lengths, const float* __restrict__ ln1g,
    const float* __restrict__ ln1b,
    float* __restrict__ h, float* __restrict__ clb, float* __restrict__ csfb,
    float* __restrict__ padfb, unsigned short* __restrict__ u)
{
    __shared__ float zs[8][20];
    __shared__ __align__(16) float pes[8][256];
    __shared__ float mn[8], rsd[8];
    const int t = threadIdx.x;
    const int tok0 = blockIdx.x * 8;
    const int b = tok0 >> 9;
    const int len_b = lengths[b];
    const float cf = *corr_floor_p;
    const float gain = *pe_gain_p;

    float clv[8], csv[8];
    bool mk[8];
#pragma unroll
    for (int k = 0; k < 8; ++k) {
        int l = (tok0 + k) & 511;
        if (l == 0) { clv[k] = 1.f; csv[k] = 1.f; mk[k] = false; }
        else {
            float a = c_local[b * 511 + l - 1];
            float s = c_sink[b * 511 + l - 1];
            clv[k] = fminf(fmaxf(a, 0.f), 1.f);
            csv[k] = fminf(fmaxf(s, 0.f), 1.f);
            mk[k] = (l - 1) >= len_b;
        }
    }
    if (t < 8) {
        int tok = tok0 + t;
        clb[tok] = clv[t];
        csfb[tok] = cf + (1.f - cf) * csv[t];
        padfb[tok] = mk[t] ? 1.f : 0.f;
    }
    // dead group: mask arrays written above are all that's needed
    if ((tok0 & 511) > len_b) return;
    if (t < 20) {
#pragma unroll
        for (int k = 0; k < 8; ++k) {
            float cl = clv[k], cs = csv[k];
            float v;
            if (t == 0) v = cl;
            else if (t == 1) v = cs;
            else if (t == 2) v = cl * cs;
            else if (t == 3) v = fabsf(cl - cs);
            else if (t < 12) {
                float c = (float)(t - 4) * (1.f / 7.f);
                float dd = (cl - c) / 0.200001f;
                v = expf(-0.5f * dd * dd);
            } else {
                float c = (float)(t - 12) * (1.f / 7.f);
                float dd = (cs - c) / 0.200001f;
                v = expf(-0.5f * dd * dd);
            }
            zs[k][t] = v;
        }
    }
    __syncthreads();

    float acc[8];
#pragma unroll
    for (int k = 0; k < 8; ++k)
        acc[k] = PEpos[((tok0 + k) & 511) * 256 + t];
    for (int f = 0; f < 20; ++f) {
        float wv = W20t[f * 256 + t];
#pragma unroll
        for (int k = 0; k < 8; ++k) acc[k] += zs[k][f] * wv;
    }
#pragma unroll
    for (int k = 0; k < 8; ++k) pes[k][t] = acc[k];
    __syncthreads();

    {
        int w = t >> 6, lane = t & 63;
#pragma unroll
        for (int p = 0; p < 2; ++p) {
            int k = w + p * 4;
            float4 v = *(const float4*)&pes[k][lane * 4];
            float s = v.x + v.y + v.z + v.w;
            float sq = v.x * v.x + v.y * v.y + v.z * v.z + v.w * v.w;
#pragma unroll
            for (int off = 32; off; off >>= 1) {
                s += __shfl_xor(s, off);
                sq += __shfl_xor(sq, off);
            }
            if (lane == 0) {
                float mean = s * (1.f / 256.f);
                mn[k] = mean;
                rsd[k] = rsqrtf(sq * (1.f / 256.f) - mean * mean + 1e-5f);
            }
        }
    }
    __syncthreads();
    float gv = pe_g[t], bv = pe_bb[t];
    float hv[8];
#pragma unroll
    for (int k = 0; k < 8; ++k) {
        int l = (tok0 + k) & 511;
        float base = (l == 0) ? cls_tok[t] : bb[(size_t)(tok0 + k) * 256 + t];
        float pe = (pes[k][t] - mn[k]) * rsd[k] * gv + bv;
        pe *= gain;
        if (mk[k]) pe = 0.f;
        hv[k] = base + pe;
        h[(size_t)(tok0 + k) * 256 + t] = hv[k];
    }
    __syncthreads();
#pragma unroll
    for (int k = 0; k < 8; ++k) pes[k][t] = hv[k];
    __syncthreads();
    {
        int w = t >> 6, lane = t & 63;
#pragma unroll
        for (int p = 0; p < 2; ++p) {
            int k = w + p * 4;
            float4 v = *(const float4*)&pes[k][lane * 4];
            float s = v.x + v.y + v.z + v.w;
            float sq = v.x * v.x + v.y * v.y + v.z * v.z + v.w * v.w;
#pragma unroll
            for (int off = 32; off; off >>= 1) {
                s += __shfl_xor(s, off);
                sq += __shfl_xor(sq, off);
            }
            if (lane == 0) {
                float mean = s * (1.f / 256.f);
                mn[k] = mean;
                rsd[k] = rsqrtf(sq * (1.f / 256.f) - mean * mean + 1e-5f);
            }
        }
    }
    __syncthreads();
    float g1 = ln1g[t], b1 = ln1b[t];
#pragma unroll
    for (int k = 0; k < 8; ++k)
        u[(size_t)(tok0 + k) * 256 + t] = f2bf((hv[k] - mn[k]) * rsd[k] * g1 + b1);
}

// ---------------------------------------------------------------------------
// bf16 MFMA GEMM, 128x64 tile (proven): C[M,N] = A @ W^T + bias (f32 store).
// Optional length-skip (lengths != nullptr, 128-aligned M tiles).
__global__ __launch_bounds__(256) void gemm_bf16_kernel(
    const unsigned short* __restrict__ A, const unsigned short* __restrict__ W,
    const float* __restrict__ bias, float* __restrict__ hres,
    const int* __restrict__ lengths, int M, int N, int K)
{
    __shared__ __align__(16) unsigned short As[128 * 64];
    __shared__ __align__(16) unsigned short Bs[64 * 64];
    const int m0 = blockIdx.y * 128, n0 = blockIdx.x * 64;
    if (lengths && (m0 & 511) > lengths[m0 >> 9]) return;
    const int t = threadIdx.x;
    const int wid = t >> 6, lane = t & 63;
    const int lo = lane & 15, hi = lane >> 4;
    const int wm = wid >> 1, wn = wid & 1;
    const int lrow = lane >> 3, lc = lane & 7;
    f32x4 acc[4][2] = {};
    for (int k0 = 0; k0 < K; k0 += 64) {
        __syncthreads();
#pragma unroll
        for (int is = 0; is < 4; ++is) {
            int r = wid * 32 + is * 8 + lrow;
            const unsigned short* g = A + (size_t)(m0 + r) * K + k0 + ((lc ^ (r & 7)) * 8);
            gload16(g, &As[(wid * 32 + is * 8) * 64]);
        }
#pragma unroll
        for (int is = 0; is < 2; ++is) {
            int r = wid * 16 + is * 8 + lrow;
            const unsigned short* g = W + (size_t)(n0 + r) * K + k0 + ((lc ^ (r & 7)) * 8);
            gload16(g, &Bs[(wid * 16 + is * 8) * 64]);
        }
        __syncthreads();
#pragma unroll
        for (int kh = 0; kh < 2; ++kh) {
            bf16x8 bfr[2];
#pragma unroll
            for (int nf = 0; nf < 2; ++nf) {
                int r = wn * 32 + nf * 16 + lo;
                bfr[nf] = *(const bf16x8*)&Bs[r * 64 + (((kh * 4 + hi) ^ (r & 7)) * 8)];
            }
#pragma unroll
            for (int mf = 0; mf < 4; ++mf) {
                int r = wm * 64 + mf * 16 + lo;
                bf16x8 afr = *(const bf16x8*)&As[r * 64 + (((kh * 4 + hi) ^ (r & 7)) * 8)];
                acc[mf][0] = __builtin_amdgcn_mfma_f32_16x16x32_bf16(afr, bfr[0], acc[mf][0], 0, 0, 0);
                acc[mf][1] = __builtin_amdgcn_mfma_f32_16x16x32_bf16(afr, bfr[1], acc[mf][1], 0, 0, 0);
            }
        }
    }
#pragma unroll
    for (int mf = 0; mf < 4; ++mf) {
        const int mbase = m0 + wm * 64 + mf * 16 + hi * 4;
#pragma unroll
        for (int nf = 0; nf < 2; ++nf) {
            const int n = n0 + wn * 32 + nf * 16 + lo;
            const float bv = bias[n];
            f32x4 v = acc[mf][nf];
#pragma unroll
            for (int rg = 0; rg < 4; ++rg)
                hres[(size_t)(mbase + rg) * N + n] = v[rg] + bv;
        }
    }
}

// ---------------------------------------------------------------------------
// bf16 MFMA GEMM, 64x128 tile: QKV (EPI=0), FF1 GELU (EPI=2).
// Skip when (m0&511) > min(lengths[b], lim), lim = qlimQ for Q-column tiles.
template <int EPI>
__global__ __launch_bounds__(256) void gemm64_kernel(
    const unsigned short* __restrict__ A, const unsigned short* __restrict__ W,
    const float* __restrict__ bias, const int* __restrict__ lengths,
    int qlim, int qlimQ,
    unsigned short* __restrict__ o0, unsigned short* __restrict__ o1,
    unsigned short* __restrict__ o2, int M, int N, int K)
{
    __shared__ __align__(16) unsigned short As[64 * 64];
    __shared__ __align__(16) unsigned short Bs[128 * 64];
    const int m0 = blockIdx.y * 64, n0 = blockIdx.x * 128;
    const int lim = (EPI == 0 && n0 < 256) ? qlimQ : qlim;
    if ((m0 & 511) > min(lengths[m0 >> 9], lim)) return;   // dead tile
    const int t = threadIdx.x;
    const int wid = t >> 6, lane = t & 63;
    const int lo = lane & 15, hi = lane >> 4;
    const int wm = wid >> 1, wn = wid & 1;
    const int lrow = lane >> 3, lc = lane & 7;
    f32x4 acc[2][4] = {};
    for (int k0 = 0; k0 < K; k0 += 64) {
        __syncthreads();
#pragma unroll
        for (int is = 0; is < 2; ++is) {
            int r = wid * 16 + is * 8 + lrow;
            const unsigned short* g = A + (size_t)(m0 + r) * K + k0 + ((lc ^ (r & 7)) * 8);
            gload16(g, &As[(wid * 16 + is * 8) * 64]);
        }
#pragma unroll
        for (int is = 0; is < 4; ++is) {
            int r = wid * 32 + is * 8 + lrow;
            const unsigned short* g = W + (size_t)(n0 + r) * K + k0 + ((lc ^ (r & 7)) * 8);
            gload16(g, &Bs[(wid * 32 + is * 8) * 64]);
        }
        __syncthreads();
#pragma unroll
        for (int kh = 0; kh < 2; ++kh) {
            bf16x8 bfr[4];
#pragma unroll
            for (int nf = 0; nf < 4; ++nf) {
                int r = wn * 64 + nf * 16 + lo;
                bfr[nf] = *(const bf16x8*)&Bs[r * 64 + (((kh * 4 + hi) ^ (r & 7)) * 8)];
            }
#pragma unroll
            for (int mf = 0; mf < 2; ++mf) {
                int r = wm * 32 + mf * 16 + lo;
                bf16x8 afr = *(const bf16x8*)&As[r * 64 + (((kh * 4 + hi) ^ (r & 7)) * 8)];
#pragma unroll
                for (int nf = 0; nf < 4; ++nf)
                    acc[mf][nf] = __builtin_amdgcn_mfma_f32_16x16x32_bf16(afr, bfr[nf], acc[mf][nf], 0, 0, 0);
            }
        }
    }
#pragma unroll
    for (int mf = 0; mf < 2; ++mf) {
        const int mbase = m0 + wm * 32 + mf * 16 + hi * 4;
#pragma unroll
        for (int nf = 0; nf < 4; ++nf) {
            const int n = n0 + wn * 64 + nf * 16 + lo;
            const float bv = bias[n];
            f32x4 v = acc[mf][nf];
            if constexpr (EPI == 0) {
                unsigned short* dst = (n < 256) ? o0 : ((n < 512) ? o1 : o2);
                const float qsc = (n < 256)
                    ? (0.17677669529663687f * 1.4426950408889634f) : 1.f;
                const int c = n & 255;
#pragma unroll
                for (int rg = 0; rg < 4; ++rg)
                    dst[(size_t)(mbase + rg) * 256 + c] = f2bf((v[rg] + bv) * qsc);
            } else {
#pragma unroll
                for (int rg = 0; rg < 4; ++rg)
                    o0[(size_t)(mbase + rg) * N + n] = f2bf(gelu_f(v[rg] + bv));
            }
        }
    }
}

// ---------------------------------------------------------------------------
// Fused residual-GEMM + LayerNorm (proven 32x256 tile), length+qlim aware.
// OUT=0: h += GEMM; u = LN(h).  OUT=1: final FF2 -> out-LN CLS rows only.
template <int OUT>
__global__ __launch_bounds__(512) void gemm_res_ln_kernel(
    const unsigned short* __restrict__ A, const unsigned short* __restrict__ W,
    const float* __restrict__ bias, float* __restrict__ hres,
    const float* __restrict__ g, const float* __restrict__ bvec,
    const int* __restrict__ lengths, int qlim,
    unsigned short* __restrict__ u, float* __restrict__ outp, int K)
{
    __shared__ __align__(16) unsigned short As[32 * 64];
    __shared__ __align__(16) unsigned short Bs[256 * 64];
    __shared__ float red[32][4][2];
    const int m0 = blockIdx.x * 32;
    if ((m0 & 511) > min(lengths[m0 >> 9], qlim)) return;   // dead tile
    const int t = threadIdx.x;
    const int wid = t >> 6, lane = t & 63;
    const int lo = lane & 15, hi = lane >> 4;
    const int wm = wid >> 2, wn = wid & 3;
    const int lrow = lane >> 3, lc = lane & 7;
    f32x4 acc[4] = {};
    for (int k0 = 0; k0 < K; k0 += 64) {
        __syncthreads();
        if (wid < 4) {
            int r = wid * 8 + lrow;
            gload16(A + (size_t)(m0 + r) * K + k0 + ((lc ^ (r & 7)) * 8),
                    &As[(wid * 8) * 64]);
        }
#pragma unroll
        for (int is = 0; is < 4; ++is) {
            int r = wid * 32 + is * 8 + lrow;
            gload16(W + (size_t)r * K + k0 + ((lc ^ (r & 7)) * 8),
                    &Bs[(wid * 32 + is * 8) * 64]);
        }
        __syncthreads();
#pragma unroll
        for (int kh = 0; kh < 2; ++kh) {
            bf16x8 bfr[4];
#pragma unroll
            for (int nf = 0; nf < 4; ++nf) {
                int r = wn * 64 + nf * 16 + lo;
                bfr[nf] = *(const bf16x8*)&Bs[r * 64 + (((kh * 4 + hi) ^ (r & 7)) * 8)];
            }
            {
                int r = wm * 16 + lo;
                bf16x8 afr = *(const bf16x8*)&As[r * 64 + (((kh * 4 + hi) ^ (r & 7)) * 8)];
#pragma unroll
                for (int nf = 0; nf < 4; ++nf)
                    acc[nf] = __builtin_amdgcn_mfma_f32_16x16x32_bf16(afr, bfr[nf], acc[nf], 0, 0, 0);
            }
        }
    }
#pragma unroll
    for (int nf = 0; nf < 4; ++nf) {
        const int n = wn * 64 + nf * 16 + lo;
        const float bv = bias[n];
        const int rbase = m0 + wm * 16 + hi * 4;
#pragma unroll
        for (int rg = 0; rg < 4; ++rg) {
            size_t idx = (size_t)(rbase + rg) * 256 + n;
            float hv = acc[nf][rg] + bv + hres[idx];
            if constexpr (OUT == 0) hres[idx] = hv;
            acc[nf][rg] = hv;
        }
    }
#pragma unroll
    for (int rg = 0; rg < 4; ++rg) {
        float s = ((acc[0][rg] + acc[1][rg]) + (acc[2][rg] + acc[3][rg]));
        float sq = ((acc[0][rg] * acc[0][rg] + acc[1][rg] * acc[1][rg]) +
                    (acc[2][rg] * acc[2][rg] + acc[3][rg] * acc[3][rg]));
#pragma unroll
        for (int off = 1; off < 16; off <<= 1) {
            s += __shfl_xor(s, off);
            sq += __shfl_xor(sq, off);
        }
        if (lo == 0) {
            int rl = wm * 16 + hi * 4 + rg;
            red[rl][wn][0] = s;
            red[rl][wn][1] = sq;
        }
    }
    __syncthreads();
#pragma unroll
    for (int rg = 0; rg < 4; ++rg) {
        const int rl = wm * 16 + hi * 4 + rg;
        float s = (red[rl][0][0] + red[rl][1][0]) + (red[rl][2][0] + red[rl][3][0]);
        float sq = (red[rl][0][1] + red[rl][1][1]) + (red[rl][2][1] + red[rl][3][1]);
        float mean = s * (1.f / 256.f);
        float rs = rsqrtf(sq * (1.f / 256.f) - mean * mean + 1e-5f);
        if constexpr (OUT == 1) {
            const int row = m0 + rl;
            if ((row & 511) == 0) {
#pragma unroll
                for (int nf = 0; nf < 4; ++nf) {
                    const int n = wn * 64 + nf * 16 + lo;
                    outp[(size_t)(row >> 9) * 256 + n] =
                        (acc[nf][rg] - mean) * rs * g[n] + bvec[n];
                }
            }
        } else {
#pragma unroll
            for (int nf = 0; nf < 4; ++nf) {
                const int n = wn * 64 + nf * 16 + lo;
                u[(size_t)(m0 + rl) * 256 + n] =
                    f2bf((acc[nf][rg] - mean) * rs * g[n] + bvec[n]);
            }
        }
    }
}

// ---------------------------------------------------------------------------
// MFMA flash attention (proven structure) + qlim q-tile trim + 32-granular
// kv-chunk trim (skipped chunks were exact zeros -> bit-identical output).
__global__ __launch_bounds__(256) void attn_mfma_kernel(
    const unsigned short* __restrict__ Qb, const unsigned short* __restrict__ Kb,
    const unsigned short* __restrict__ Vb, const float* __restrict__ clb,
    const float* __restrict__ csfb, const float* __restrict__ padfb,
    const float* __restrict__ alpha_p, const float* __restrict__ beta_p,
    const int* __restrict__ lengths, int qlim, unsigned short* __restrict__ Ob)
{
    __shared__ __align__(16) unsigned short Kl[128 * 40];   // 10240 B
    __shared__ __align__(16) unsigned short Vt[32 * 132];   // 8448 B
    __shared__ __align__(16) float csfj[128];               // 512 B
    const int t = threadIdx.x;
    const int swz = ((blockIdx.x & 7) << 8) | (blockIdx.x >> 3);  // XCD chunking
    const int bh = swz >> 3, hf = swz & 7;
    const int b = bh >> 3, hd = bh & 7;
    const int len_b = lengths[b];
    if (hf * 64 > min(len_b, qlim)) return;      // dead q-tile
    const int njt = (len_b + 128) >> 7;          // ceil((len_b+1)/128)
    const size_t base = ((size_t)b * 512) * 256 + hd * 32;
    const int w = t >> 6, lane = t & 63, lo = lane & 15, hi = lane >> 4;
    const float L2E = 1.4426950408889634f;
    const float kb = L2E * (*beta_p);
    const float ka = L2E * (*alpha_p);
    const float* clg = clb + b * 512;

    const int i0 = (hf * 4 + w) * 16;
    const int iq = i0 + lo;
    const bf16x8 qf = *(const bf16x8*)(Qb + base + (size_t)iq * 256 + hi * 8);
    const float csb = fmaxf(kb * csfb[b * 512 + iq], 1e-3f);
    f32x4 acc0 = {0.f, 0.f, 0.f, 0.f}, acc1 = {0.f, 0.f, 0.f, 0.f};
    float lsum = 0.f;

    for (int jt = 0; jt < njt; ++jt) {
        __syncthreads();
        for (int idx = t; idx < 512; idx += 256) {       // K tile: 128 rows
            int row = idx >> 2, c4 = idx & 3;
            *(uint4*)&Kl[row * 40 + c4 * 8] =
                *(const uint4*)(Kb + base + (size_t)(jt * 128 + row) * 256 + c4 * 8);
        }
        for (int idx = t; idx < 512; idx += 256) {       // V^T via v_perm
            int pr = idx & 63, c4 = idx >> 6;
            const unsigned* vp0 = (const unsigned*)
                (Vb + base + (size_t)(jt * 128 + 2 * pr) * 256 + c4 * 4);
            const unsigned* vp1 = (const unsigned*)
                (Vb + base + (size_t)(jt * 128 + 2 * pr + 1) * 256 + c4 * 4);
            unsigned v0lo = vp0[0], v0hi = vp0[1];
            unsigned v1lo = vp1[0], v1hi = vp1[1];
            *(unsigned*)&Vt[(c4 * 4 + 0) * 132 + 2 * pr] =
                __builtin_amdgcn_perm(v1lo, v0lo, 0x05040100u);
            *(unsigned*)&Vt[(c4 * 4 + 1) * 132 + 2 * pr] =
                __builtin_amdgcn_perm(v1lo, v0lo, 0x07060302u);
            *(unsigned*)&Vt[(c4 * 4 + 2) * 132 + 2 * pr] =
                __builtin_amdgcn_perm(v1hi, v0hi, 0x05040100u);
            *(unsigned*)&Vt[(c4 * 4 + 3) * 132 + 2 * pr] =
                __builtin_amdgcn_perm(v1hi, v0hi, 0x07060302u);
        }
        if (t < 128) {                                   // csf with pad folded
            int j = jt * 128 + t;
            float cv = csfb[b * 512 + j];
            csfj[t] = (padfb[b * 512 + j] > 0.5f) ? -100000.f : cv;
        }
        __syncthreads();
        // live 32-col chunks in this tile (cols past len_b are exact zeros)
        const int rem = len_b + 1 - jt * 128;
        const int nktp = (rem >= 128) ? 4 : ((rem + 31) >> 5);
#pragma unroll 4
        for (int ktp = 0; ktp < nktp; ++ktp) {
            const int k16 = ktp * 32;             // local j base
            const int gj = jt * 128 + k16;        // global j base
            bf16x8 kf0 = *(const bf16x8*)&Kl[(k16 + lo) * 40 + hi * 8];
            bf16x8 kf1 = *(const bf16x8*)&Kl[(k16 + 16 + lo) * 40 + hi * 8];
            union U16 { unsigned long long q[2]; unsigned wd[4]; bf16x8 v; } vu0, vu1, pu;
            vu0.q[0] = *(const unsigned long long*)&Vt[lo * 132 + k16 + hi * 4];
            vu0.q[1] = *(const unsigned long long*)&Vt[lo * 132 + k16 + 16 + hi * 4];
            vu1.q[0] = *(const unsigned long long*)&Vt[(16 + lo) * 132 + k16 + hi * 4];
            vu1.q[1] = *(const unsigned long long*)&Vt[(16 + lo) * 132 + k16 + 16 + hi * 4];
            f32x4 csf0 = *(const f32x4*)&csfj[k16 + hi * 4];
            f32x4 csf1 = *(const f32x4*)&csfj[k16 + 16 + hi * 4];
            f32x4 c0, c1;
#pragma unroll
            for (int e = 0; e < 4; ++e) {
                c0[e] = csb * csf0[e];
                c1[e] = csb * csf1[e];
            }
            f32x4 s0 = __builtin_amdgcn_mfma_f32_16x16x32_bf16(kf0, qf, c0, 0, 0, 0);
            f32x4 s1 = __builtin_amdgcn_mfma_f32_16x16x32_bf16(kf1, qf, c1, 0, 0, 0);
            float p[8];
#pragma unroll
            for (int r = 0; r < 4; ++r) p[r] = exp2f(s0[r]);
#pragma unroll
            for (int r = 0; r < 4; ++r) p[4 + r] = exp2f(s1[r]);
            if (gj <= i0 + 16 && gj + 32 >= i0) {
#pragma unroll
                for (int r = 0; r < 8; ++r) {
                    int jr = gj + ((r & 4) ? 16 : 0) + hi * 4 + (r & 3);
                    int dij = jr - iq;
                    if (dij == 1 || dij == -1) {
                        float ce = (jr >= 1 && iq <= 510) ? clg[jr] : clg[iq];
                        p[r] *= exp2f(ka * ce);
                    }
                }
            }
            lsum += ((p[0] + p[1]) + (p[2] + p[3])) + ((p[4] + p[5]) + (p[6] + p[7]));
            pu.wd[0] = cvt_pk_bf16(p[0], p[1]);
            pu.wd[1] = cvt_pk_bf16(p[2], p[3]);
            pu.wd[2] = cvt_pk_bf16(p[4], p[5]);
            pu.wd[3] = cvt_pk_bf16(p[6], p[7]);
            acc0 = __builtin_amdgcn_mfma_f32_16x16x32_bf16(vu0.v, pu.v, acc0, 0, 0, 0);
            acc1 = __builtin_amdgcn_mfma_f32_16x16x32_bf16(vu1.v, pu.v, acc1, 0, 0, 0);
        }
    }
    {
        float ls = lsum;
        ls += __shfl_xor(ls, 16);
        ls += __shfl_xor(ls, 32);
        const float inv = 1.f / fmaxf(ls, 1e-35f);
        unsigned long long oa =
              (unsigned long long)cvt_pk_bf16(acc0[0] * inv, acc0[1] * inv)
            | ((unsigned long long)cvt_pk_bf16(acc0[2] * inv, acc0[3] * inv) << 32);
        unsigned long long ob2 =
              (unsigned long long)cvt_pk_bf16(acc1[0] * inv, acc1[1] * inv)
            | ((unsigned long long)cvt_pk_bf16(acc1[2] * inv, acc1[3] * inv) << 32);
        *(unsigned long long*)(Ob + base + (size_t)iq * 256 + hi * 4) = oa;
        *(unsigned long long*)(Ob + base + (size_t)iq * 256 + 16 + hi * 4) = ob2;
    }
}

// ---------------------------------------------------------------------------
extern "C" void kernel_launch(void* const* d_in, const int* in_sizes, int n_in,
                              void* d_out, int out_size, void* d_ws, size_t ws_size,
                              hipStream_t stream) {
    const float* x         = (const float*)d_in[0];
    const float* c_local   = (const float*)d_in[1];
    const float* c_sink    = (const float*)d_in[2];
    const float* W_in      = (const float*)d_in[3];
    const float* b_in      = (const float*)d_in[4];
    const float* cls_token = (const float*)d_in[5];
    const float* pe_proj_W = (const float*)d_in[6];
    const float* pe_proj_b = (const float*)d_in[7];
    const float* pe_ln_g   = (const float*)d_in[8];
    const float* pe_ln_b   = (const float*)d_in[9];
    const float* pe_gain   = (const float*)d_in[10];
    const float* attn_Wqkv = (const float*)d_in[11];
    const float* attn_bqkv = (const float*)d_in[12];
    const float* attn_Wo   = (const float*)d_in[13];
    const float* attn_bo   = (const float*)d_in[14];
    const float* ff_W1     = (const float*)d_in[15];
    const float* ff_b1     = (const float*)d_in[16];
    const float* ff_W2     = (const float*)d_in[17];
    const float* ff_b2     = (const float*)d_in[18];
    const float* ln1_g     = (const float*)d_in[19];
    const float* ln1_b     = (const float*)d_in[20];
    const float* ln2_g     = (const float*)d_in[21];
    const float* ln2_b     = (const float*)d_in[22];
    const float* alpha     = (const float*)d_in[23];
    const float* beta      = (const float*)d_in[24];
    const float* corr_fl   = (const float*)d_in[25];
    const float* out_ln_g  = (const float*)d_in[26];
    const float* out_ln_b  = (const float*)d_in[27];
    const int*   lengths   = (const int*)d_in[28];
    float* out = (float*)d_out;

    // float region (same slots as round-19 passing layout)
    float* h     = (float*)d_ws;              // 4,194,304
    float* clb   = h + 4194304;               // 16384
    float* csfb  = clb + 16384;
    float* padfb = csfb + 16384;
    float* W20t  = padfb + 16384;             // 5120 (in old peWt slot)
    float* PEpos = W20t + 70656;              // 131072
    float* bbf   = PEpos + 131072;            // old 8,388,608-float region
    // bf16 region — weights AFTER the full 16,777,216-short f-span at Q_bf
    unsigned short* u_bf = (unsigned short*)(bbf + 8388608);
    unsigned short* xb_bf = u_bf;             // alias: xb dead before layer loop
    unsigned short* Q_bf = u_bf + 4194304;
    unsigned short* K_bf = Q_bf + 4194304;
    unsigned short* V_bf = K_bf + 4194304;
    unsigned short* f_bf = Q_bf;              // alias: spans Q..Q+16777216
    unsigned short* o_bf = u_bf;              // alias (lifetimes disjoint)
    unsigned short* wq_bf = Q_bf + 16777216;  // after f's span
    unsigned short* wo_bf = wq_bf + 589824;
    unsigned short* w1_bf = wo_bf + 196608;
    unsigned short* w2_bf = w1_bf + 786432;
    unsigned short* win_bf = w2_bf + 786432;  // 16384
    unsigned short* S_bf   = win_bf + 16384;  // 131072 (sinusoid table)
    unsigned short* w256_bf = S_bf + 131072;  // 65536

    setup_kernel<<<4708, 256, 0, stream>>>(
        attn_Wqkv, wq_bf, attn_Wo, wo_bf, ff_W1, w1_bf, ff_W2, w2_bf,
        W_in, win_bf, pe_proj_W, w256_bf, W20t, x, xb_bf, S_bf);
    gemm_bf16_kernel<<<dim3(4, 4), 256, 0, stream>>>(
        S_bf, w256_bf, pe_proj_b, PEpos, nullptr, 512, 256, 256);
    gemm_bf16_kernel<<<dim3(4, 128), 256, 0, stream>>>(
        xb_bf, win_bf, b_in, bbf, lengths, 16384, 256, 64);
    prep_lite_kernel<<<2048, 256, 0, stream>>>(
        c_local, c_sink, bbf, cls_token, PEpos, W20t,
        pe_ln_g, pe_ln_b, pe_gain, corr_fl, lengths, ln1_g, ln1_b,
        h, clb, csfb, padfb, u_bf);

    for (int l = 0; l < 3; ++l) {
        const bool last = (l == 2);
        gemm64_kernel<0><<<dim3(6, 256), 256, 0, stream>>>(
            u_bf, wq_bf + (size_t)l * 196608, attn_bqkv + 768 * l, lengths,
            511, last ? 63 : 511, Q_bf, K_bf, V_bf, 16384, 768, 256);
        attn_mfma_kernel<<<2048, 256, 0, stream>>>(
            Q_bf, K_bf, V_bf, clb, csfb, padfb, alpha, beta, lengths,
            last ? 63 : 511, o_bf);
        gemm_res_ln_kernel<0><<<512, 512, 0, stream>>>(
            o_bf, wo_bf + (size_t)l * 65536, attn_bo + 256 * l, h,
            ln2_g + 256 * l, ln2_b + 256 * l, lengths, last ? 63 : 511,
            u_bf, nullptr, 256);
        gemm64_kernel<2><<<dim3(8, 256), 256, 0, stream>>>(
            u_bf, w1_bf + (size_t)l * 262144, ff_b1 + 1024 * l, lengths,
            last ? 63 : 511, 511, f_bf, nullptr, nullptr, 16384, 1024, 256);
        if (l < 2) {
            gemm_res_ln_kernel<0><<<512, 512, 0, stream>>>(
                f_bf, w2_bf + (size_t)l * 262144, ff_b2 + 256 * l, h,
                ln1_g + 256 * (l + 1), ln1_b + 256 * (l + 1), lengths, 511,
                u_bf, nullptr, 1024);
        } else {
            gemm_res_ln_kernel<1><<<512, 512, 0, stream>>>(
                f_bf, w2_bf + (size_t)l * 262144, ff_b2 + 256 * l, h,
                out_ln_g, out_ln_b, lengths, 0, nullptr, out, 1024);
        }
    }
}

// Round 21
// 311.213 us; speedup vs baseline: 1.2772x; 1.0091x over previous
//
#include <hip/hip_runtime.h>
#include <math.h>

// B=32, L=512 (incl CLS), D=256, H=8, dh=32, N_LAYERS=3, D_FF=1024, tokens=16384
// Length-aware + layer-2 liveness-trimmed + attn kv-chunk & staging trim.

typedef __attribute__((ext_vector_type(4))) float f32x4;
typedef __attribute__((ext_vector_type(8))) short bf16x8;

__device__ __forceinline__ unsigned short f2bf(float f) {
    unsigned u = __builtin_bit_cast(unsigned, f);
    u += 0x7fff + ((u >> 16) & 1);
    return (unsigned short)(u >> 16);
}
__device__ __forceinline__ unsigned cvt_pk_bf16(float a, float b) {
    unsigned r;
    asm("v_cvt_pk_bf16_f32 %0, %1, %2" : "=v"(r) : "v"(a), "v"(b));
    return r;
}
__device__ __forceinline__ float gelu_f(float v) {
    return v * 0.5f * (1.0f + erff(v * 0.70710678118654752f));
}
__device__ __forceinline__ void gload16(const void* g, void* l) {
    __builtin_amdgcn_global_load_lds(
        (const __attribute__((address_space(1))) unsigned int*)g,
        (__attribute__((address_space(3))) unsigned int*)l, 16, 0, 0);
}

// ---------------------------------------------------------------------------
// Mega setup kernel: all weight cvts + pe transposes + sinusoid + xb.
__global__ __launch_bounds__(256) void setup_kernel(
    const float* __restrict__ wq, unsigned short* __restrict__ wq_o,   // 576
    const float* __restrict__ wo, unsigned short* __restrict__ wo_o,   // 192
    const float* __restrict__ w1, unsigned short* __restrict__ w1_o,   // 768
    const float* __restrict__ w2, unsigned short* __restrict__ w2_o,   // 768
    const float* __restrict__ win, unsigned short* __restrict__ win_o, // 16
    const float* __restrict__ peW, unsigned short* __restrict__ w256,  // 64
    float* __restrict__ W20t,                                          // 20
    const float* __restrict__ x, unsigned short* __restrict__ xb,      // 2048
    unsigned short* __restrict__ S)                                    // 256
{
    int blk = blockIdx.x, t = threadIdx.x;
    if (blk < 2304) {  // plain f32->bf16 cvts
        const float* s; unsigned short* d; int base;
        if (blk < 576)       { s = wq; d = wq_o; base = blk; }
        else if (blk < 768)  { s = wo; d = wo_o; base = blk - 576; }
        else if (blk < 1536) { s = w1; d = w1_o; base = blk - 768; }
        else                 { s = w2; d = w2_o; base = blk - 1536; }
        int i = (base * 256 + t) * 4;
        float4 v = *(const float4*)(s + i);
        unsigned long long pk = (unsigned long long)f2bf(v.x)
            | ((unsigned long long)f2bf(v.y) << 16)
            | ((unsigned long long)f2bf(v.z) << 32)
            | ((unsigned long long)f2bf(v.w) << 48);
        *(unsigned long long*)(d + i) = pk;
    } else if (blk < 2320) {  // win
        int i = ((blk - 2304) * 256 + t) * 4;
        float4 v = *(const float4*)(win + i);
        unsigned long long pk = (unsigned long long)f2bf(v.x)
            | ((unsigned long long)f2bf(v.y) << 16)
            | ((unsigned long long)f2bf(v.z) << 32)
            | ((unsigned long long)f2bf(v.w) << 48);
        *(unsigned long long*)(win_o + i) = pk;
    } else if (blk < 2384) {  // peW first-256 feats -> bf16 [256][256]
        int i = ((blk - 2320) * 256 + t) * 4;
        int d = i >> 8, f = i & 255;
        float4 v = *(const float4*)(peW + d * 276 + f);
        unsigned long long pk = (unsigned long long)f2bf(v.x)
            | ((unsigned long long)f2bf(v.y) << 16)
            | ((unsigned long long)f2bf(v.z) << 32)
            | ((unsigned long long)f2bf(v.w) << 48);
        *(unsigned long long*)(w256 + i) = pk;
    } else if (blk < 2404) {  // W20t[f][d] = peW[d][256+f]
        int j = (blk - 2384) * 256 + t;
        int f = j >> 8, dd = j & 255;
        W20t[j] = peW[dd * 276 + 256 + f];
    } else if (blk < 4452) {  // xb
        int idx = (blk - 2404) * 256 + t;
        int tok = idx >> 5, c2 = idx & 31;
        int b = tok >> 9, l = tok & 511;
        unsigned r = 0;
        if (l > 0) {
            float2 v = *(const float2*)(x + ((size_t)b * 511 + l - 1) * 64 + 2 * c2);
            r = cvt_pk_bf16(v.x, v.y);
        }
        *(unsigned*)(xb + (size_t)tok * 64 + 2 * c2) = r;
    } else {  // sinusoid table
        int p = (blk - 4452) * 256 + t;
        int l = p >> 7, k = p & 127;
        float div = expf((float)(2 * k) * -0.035977892078032f);
        float a = (float)l * div;
        *(unsigned*)(S + l * 256 + 2 * k) = cvt_pk_bf16(sinf(a), cosf(a));
    }
}

// ---------------------------------------------------------------------------
// prep_lite: arrays for ALL tokens; h/u only for live 8-row groups.
__global__ __launch_bounds__(256) void prep_lite_kernel(
    const float* __restrict__ c_local, const float* __restrict__ c_sink,
    const float* __restrict__ bb, const float* __restrict__ cls_tok,
    const float* __restrict__ PEpos, const float* __restrict__ W20t,
    const float* __restrict__ pe_g, const float* __restrict__ pe_bb,
    const float* __restrict__ pe_gain_p, const float* __restrict__ corr_floor_p,
    const int* __restrict__ lengths, const float* __restrict__ ln1g,
    const float* __restrict__ ln1b,
    float* __restrict__ h, float* __restrict__ clb, float* __restrict__ csfb,
    float* __restrict__ padfb, unsigned short* __restrict__ u)
{
    __shared__ float zs[8][20];
    __shared__ __align__(16) float pes[8][256];
    __shared__ float mn[8], rsd[8];
    const int t = threadIdx.x;
    const int tok0 = blockIdx.x * 8;
    const int b = tok0 >> 9;
    const int len_b = lengths[b];
    const float cf = *corr_floor_p;
    const float gain = *pe_gain_p;

    float clv[8], csv[8];
    bool mk[8];
#pragma unroll
    for (int k = 0; k < 8; ++k) {
        int l = (tok0 + k) & 511;
        if (l == 0) { clv[k] = 1.f; csv[k] = 1.f; mk[k] = false; }
        else {
            float a = c_local[b * 511 + l - 1];
            float s = c_sink[b * 511 + l - 1];
            clv[k] = fminf(fmaxf(a, 0.f), 1.f);
            csv[k] = fminf(fmaxf(s, 0.f), 1.f);
            mk[k] = (l - 1) >= len_b;
        }
    }
    if (t < 8) {
        int tok = tok0 + t;
        clb[tok] = clv[t];
        csfb[tok] = cf + (1.f - cf) * csv[t];
        padfb[tok] = mk[t] ? 1.f : 0.f;
    }
    // dead group: mask arrays written above are all that's needed
    if ((tok0 & 511) > len_b) return;
    if (t < 20) {
#pragma unroll
        for (int k = 0; k < 8; ++k) {
            float cl = clv[k], cs = csv[k];
            float v;
            if (t == 0) v = cl;
            else if (t == 1) v = cs;
            else if (t == 2) v = cl * cs;
            else if (t == 3) v = fabsf(cl - cs);
            else if (t < 12) {
                float c = (float)(t - 4) * (1.f / 7.f);
                float dd = (cl - c) / 0.200001f;
                v = expf(-0.5f * dd * dd);
            } else {
                float c = (float)(t - 12) * (1.f / 7.f);
                float dd = (cs - c) / 0.200001f;
                v = expf(-0.5f * dd * dd);
            }
            zs[k][t] = v;
        }
    }
    __syncthreads();

    float acc[8];
#pragma unroll
    for (int k = 0; k < 8; ++k)
        acc[k] = PEpos[((tok0 + k) & 511) * 256 + t];
    for (int f = 0; f < 20; ++f) {
        float wv = W20t[f * 256 + t];
#pragma unroll
        for (int k = 0; k < 8; ++k) acc[k] += zs[k][f] * wv;
    }
#pragma unroll
    for (int k = 0; k < 8; ++k) pes[k][t] = acc[k];
    __syncthreads();

    {
        int w = t >> 6, lane = t & 63;
#pragma unroll
        for (int p = 0; p < 2; ++p) {
            int k = w + p * 4;
            float4 v = *(const float4*)&pes[k][lane * 4];
            float s = v.x + v.y + v.z + v.w;
            float sq = v.x * v.x + v.y * v.y + v.z * v.z + v.w * v.w;
#pragma unroll
            for (int off = 32; off; off >>= 1) {
                s += __shfl_xor(s, off);
                sq += __shfl_xor(sq, off);
            }
            if (lane == 0) {
                float mean = s * (1.f / 256.f);
                mn[k] = mean;
                rsd[k] = rsqrtf(sq * (1.f / 256.f) - mean * mean + 1e-5f);
            }
        }
    }
    __syncthreads();
    float gv = pe_g[t], bv = pe_bb[t];
    float hv[8];
#pragma unroll
    for (int k = 0; k < 8; ++k) {
        int l = (tok0 + k) & 511;
        float base = (l == 0) ? cls_tok[t] : bb[(size_t)(tok0 + k) * 256 + t];
        float pe = (pes[k][t] - mn[k]) * rsd[k] * gv + bv;
        pe *= gain;
        if (mk[k]) pe = 0.f;
        hv[k] = base + pe;
        h[(size_t)(tok0 + k) * 256 + t] = hv[k];
    }
    __syncthreads();
#pragma unroll
    for (int k = 0; k < 8; ++k) pes[k][t] = hv[k];
    __syncthreads();
    {
        int w = t >> 6, lane = t & 63;
#pragma unroll
        for (int p = 0; p < 2; ++p) {
            int k = w + p * 4;
            float4 v = *(const float4*)&pes[k][lane * 4];
            float s = v.x + v.y + v.z + v.w;
            float sq = v.x * v.x + v.y * v.y + v.z * v.z + v.w * v.w;
#pragma unroll
            for (int off = 32; off; off >>= 1) {
                s += __shfl_xor(s, off);
                sq += __shfl_xor(sq, off);
            }
            if (lane == 0) {
                float mean = s * (1.f / 256.f);
                mn[k] = mean;
                rsd[k] = rsqrtf(sq * (1.f / 256.f) - mean * mean + 1e-5f);
            }
        }
    }
    __syncthreads();
    float g1 = ln1g[t], b1 = ln1b[t];
#pragma unroll
    for (int k = 0; k < 8; ++k)
        u[(size_t)(tok0 + k) * 256 + t] = f2bf((hv[k] - mn[k]) * rsd[k] * g1 + b1);
}

// ---------------------------------------------------------------------------
// bf16 MFMA GEMM, 128x64 tile (proven): C[M,N] = A @ W^T + bias (f32 store).
// Optional length-skip (lengths != nullptr, 128-aligned M tiles).
__global__ __launch_bounds__(256) void gemm_bf16_kernel(
    const unsigned short* __restrict__ A, const unsigned short* __restrict__ W,
    const float* __restrict__ bias, float* __restrict__ hres,
    const int* __restrict__ lengths, int M, int N, int K)
{
    __shared__ __align__(16) unsigned short As[128 * 64];
    __shared__ __align__(16) unsigned short Bs[64 * 64];
    const int m0 = blockIdx.y * 128, n0 = blockIdx.x * 64;
    if (lengths && (m0 & 511) > lengths[m0 >> 9]) return;
    const int t = threadIdx.x;
    const int wid = t >> 6, lane = t & 63;
    const int lo = lane & 15, hi = lane >> 4;
    const int wm = wid >> 1, wn = wid & 1;
    const int lrow = lane >> 3, lc = lane & 7;
    f32x4 acc[4][2] = {};
    for (int k0 = 0; k0 < K; k0 += 64) {
        __syncthreads();
#pragma unroll
        for (int is = 0; is < 4; ++is) {
            int r = wid * 32 + is * 8 + lrow;
            const unsigned short* g = A + (size_t)(m0 + r) * K + k0 + ((lc ^ (r & 7)) * 8);
            gload16(g, &As[(wid * 32 + is * 8) * 64]);
        }
#pragma unroll
        for (int is = 0; is < 2; ++is) {
            int r = wid * 16 + is * 8 + lrow;
            const unsigned short* g = W + (size_t)(n0 + r) * K + k0 + ((lc ^ (r & 7)) * 8);
            gload16(g, &Bs[(wid * 16 + is * 8) * 64]);
        }
        __syncthreads();
#pragma unroll
        for (int kh = 0; kh < 2; ++kh) {
            bf16x8 bfr[2];
#pragma unroll
            for (int nf = 0; nf < 2; ++nf) {
                int r = wn * 32 + nf * 16 + lo;
                bfr[nf] = *(const bf16x8*)&Bs[r * 64 + (((kh * 4 + hi) ^ (r & 7)) * 8)];
            }
#pragma unroll
            for (int mf = 0; mf < 4; ++mf) {
                int r = wm * 64 + mf * 16 + lo;
                bf16x8 afr = *(const bf16x8*)&As[r * 64 + (((kh * 4 + hi) ^ (r & 7)) * 8)];
                acc[mf][0] = __builtin_amdgcn_mfma_f32_16x16x32_bf16(afr, bfr[0], acc[mf][0], 0, 0, 0);
                acc[mf][1] = __builtin_amdgcn_mfma_f32_16x16x32_bf16(afr, bfr[1], acc[mf][1], 0, 0, 0);
            }
        }
    }
#pragma unroll
    for (int mf = 0; mf < 4; ++mf) {
        const int mbase = m0 + wm * 64 + mf * 16 + hi * 4;
#pragma unroll
        for (int nf = 0; nf < 2; ++nf) {
            const int n = n0 + wn * 32 + nf * 16 + lo;
            const float bv = bias[n];
            f32x4 v = acc[mf][nf];
#pragma unroll
            for (int rg = 0; rg < 4; ++rg)
                hres[(size_t)(mbase + rg) * N + n] = v[rg] + bv;
        }
    }
}

// ---------------------------------------------------------------------------
// bf16 MFMA GEMM, 64x128 tile: QKV (EPI=0), FF1 GELU (EPI=2).
// Skip when (m0&511) > min(lengths[b], lim), lim = qlimQ for Q-column tiles.
template <int EPI>
__global__ __launch_bounds__(256) void gemm64_kernel(
    const unsigned short* __restrict__ A, const unsigned short* __restrict__ W,
    const float* __restrict__ bias, const int* __restrict__ lengths,
    int qlim, int qlimQ,
    unsigned short* __restrict__ o0, unsigned short* __restrict__ o1,
    unsigned short* __restrict__ o2, int M, int N, int K)
{
    __shared__ __align__(16) unsigned short As[64 * 64];
    __shared__ __align__(16) unsigned short Bs[128 * 64];
    const int m0 = blockIdx.y * 64, n0 = blockIdx.x * 128;
    const int lim = (EPI == 0 && n0 < 256) ? qlimQ : qlim;
    if ((m0 & 511) > min(lengths[m0 >> 9], lim)) return;   // dead tile
    const int t = threadIdx.x;
    const int wid = t >> 6, lane = t & 63;
    const int lo = lane & 15, hi = lane >> 4;
    const int wm = wid >> 1, wn = wid & 1;
    const int lrow = lane >> 3, lc = lane & 7;
    f32x4 acc[2][4] = {};
    for (int k0 = 0; k0 < K; k0 += 64) {
        __syncthreads();
#pragma unroll
        for (int is = 0; is < 2; ++is) {
            int r = wid * 16 + is * 8 + lrow;
            const unsigned short* g = A + (size_t)(m0 + r) * K + k0 + ((lc ^ (r & 7)) * 8);
            gload16(g, &As[(wid * 16 + is * 8) * 64]);
        }
#pragma unroll
        for (int is = 0; is < 4; ++is) {
            int r = wid * 32 + is * 8 + lrow;
            const unsigned short* g = W + (size_t)(n0 + r) * K + k0 + ((lc ^ (r & 7)) * 8);
            gload16(g, &Bs[(wid * 32 + is * 8) * 64]);
        }
        __syncthreads();
#pragma unroll
        for (int kh = 0; kh < 2; ++kh) {
            bf16x8 bfr[4];
#pragma unroll
            for (int nf = 0; nf < 4; ++nf) {
                int r = wn * 64 + nf * 16 + lo;
                bfr[nf] = *(const bf16x8*)&Bs[r * 64 + (((kh * 4 + hi) ^ (r & 7)) * 8)];
            }
#pragma unroll
            for (int mf = 0; mf < 2; ++mf) {
                int r = wm * 32 + mf * 16 + lo;
                bf16x8 afr = *(const bf16x8*)&As[r * 64 + (((kh * 4 + hi) ^ (r & 7)) * 8)];
#pragma unroll
                for (int nf = 0; nf < 4; ++nf)
                    acc[mf][nf] = __builtin_amdgcn_mfma_f32_16x16x32_bf16(afr, bfr[nf], acc[mf][nf], 0, 0, 0);
            }
        }
    }
#pragma unroll
    for (int mf = 0; mf < 2; ++mf) {
        const int mbase = m0 + wm * 32 + mf * 16 + hi * 4;
#pragma unroll
        for (int nf = 0; nf < 4; ++nf) {
            const int n = n0 + wn * 64 + nf * 16 + lo;
            const float bv = bias[n];
            f32x4 v = acc[mf][nf];
            if constexpr (EPI == 0) {
                unsigned short* dst = (n < 256) ? o0 : ((n < 512) ? o1 : o2);
                const float qsc = (n < 256)
                    ? (0.17677669529663687f * 1.4426950408889634f) : 1.f;
                const int c = n & 255;
#pragma unroll
                for (int rg = 0; rg < 4; ++rg)
                    dst[(size_t)(mbase + rg) * 256 + c] = f2bf((v[rg] + bv) * qsc);
            } else {
#pragma unroll
                for (int rg = 0; rg < 4; ++rg)
                    o0[(size_t)(mbase + rg) * N + n] = f2bf(gelu_f(v[rg] + bv));
            }
        }
    }
}

// ---------------------------------------------------------------------------
// Fused residual-GEMM + LayerNorm (proven 32x256 tile), length+qlim aware.
// OUT=0: h += GEMM; u = LN(h).  OUT=1: final FF2 -> out-LN CLS rows only.
template <int OUT>
__global__ __launch_bounds__(512) void gemm_res_ln_kernel(
    const unsigned short* __restrict__ A, const unsigned short* __restrict__ W,
    const float* __restrict__ bias, float* __restrict__ hres,
    const float* __restrict__ g, const float* __restrict__ bvec,
    const int* __restrict__ lengths, int qlim,
    unsigned short* __restrict__ u, float* __restrict__ outp, int K)
{
    __shared__ __align__(16) unsigned short As[32 * 64];
    __shared__ __align__(16) unsigned short Bs[256 * 64];
    __shared__ float red[32][4][2];
    const int m0 = blockIdx.x * 32;
    if ((m0 & 511) > min(lengths[m0 >> 9], qlim)) return;   // dead tile
    const int t = threadIdx.x;
    const int wid = t >> 6, lane = t & 63;
    const int lo = lane & 15, hi = lane >> 4;
    const int wm = wid >> 2, wn = wid & 3;
    const int lrow = lane >> 3, lc = lane & 7;
    f32x4 acc[4] = {};
    for (int k0 = 0; k0 < K; k0 += 64) {
        __syncthreads();
        if (wid < 4) {
            int r = wid * 8 + lrow;
            gload16(A + (size_t)(m0 + r) * K + k0 + ((lc ^ (r & 7)) * 8),
                    &As[(wid * 8) * 64]);
        }
#pragma unroll
        for (int is = 0; is < 4; ++is) {
            int r = wid * 32 + is * 8 + lrow;
            gload16(W + (size_t)r * K + k0 + ((lc ^ (r & 7)) * 8),
                    &Bs[(wid * 32 + is * 8) * 64]);
        }
        __syncthreads();
#pragma unroll
        for (int kh = 0; kh < 2; ++kh) {
            bf16x8 bfr[4];
#pragma unroll
            for (int nf = 0; nf < 4; ++nf) {
                int r = wn * 64 + nf * 16 + lo;
                bfr[nf] = *(const bf16x8*)&Bs[r * 64 + (((kh * 4 + hi) ^ (r & 7)) * 8)];
            }
            {
                int r = wm * 16 + lo;
                bf16x8 afr = *(const bf16x8*)&As[r * 64 + (((kh * 4 + hi) ^ (r & 7)) * 8)];
#pragma unroll
                for (int nf = 0; nf < 4; ++nf)
                    acc[nf] = __builtin_amdgcn_mfma_f32_16x16x32_bf16(afr, bfr[nf], acc[nf], 0, 0, 0);
            }
        }
    }
#pragma unroll
    for (int nf = 0; nf < 4; ++nf) {
        const int n = wn * 64 + nf * 16 + lo;
        const float bv = bias[n];
        const int rbase = m0 + wm * 16 + hi * 4;
#pragma unroll
        for (int rg = 0; rg < 4; ++rg) {
            size_t idx = (size_t)(rbase + rg) * 256 + n;
            float hv = acc[nf][rg] + bv + hres[idx];
            if constexpr (OUT == 0) hres[idx] = hv;
            acc[nf][rg] = hv;
        }
    }
#pragma unroll
    for (int rg = 0; rg < 4; ++rg) {
        float s = ((acc[0][rg] + acc[1][rg]) + (acc[2][rg] + acc[3][rg]));
        float sq = ((acc[0][rg] * acc[0][rg] + acc[1][rg] * acc[1][rg]) +
                    (acc[2][rg] * acc[2][rg] + acc[3][rg] * acc[3][rg]));
#pragma unroll
        for (int off = 1; off < 16; off <<= 1) {
            s += __shfl_xor(s, off);
            sq += __shfl_xor(sq, off);
        }
        if (lo == 0) {
            int rl = wm * 16 + hi * 4 + rg;
            red[rl][wn][0] = s;
            red[rl][wn][1] = sq;
        }
    }
    __syncthreads();
#pragma unroll
    for (int rg = 0; rg < 4; ++rg) {
        const int rl = wm * 16 + hi * 4 + rg;
        float s = (red[rl][0][0] + red[rl][1][0]) + (red[rl][2][0] + red[rl][3][0]);
        float sq = (red[rl][0][1] + red[rl][1][1]) + (red[rl][2][1] + red[rl][3][1]);
        float mean = s * (1.f / 256.f);
        float rs = rsqrtf(sq * (1.f / 256.f) - mean * mean + 1e-5f);
        if constexpr (OUT == 1) {
            const int row = m0 + rl;
            if ((row & 511) == 0) {
#pragma unroll
                for (int nf = 0; nf < 4; ++nf) {
                    const int n = wn * 64 + nf * 16 + lo;
                    outp[(size_t)(row >> 9) * 256 + n] =
                        (acc[nf][rg] - mean) * rs * g[n] + bvec[n];
                }
            }
        } else {
#pragma unroll
            for (int nf = 0; nf < 4; ++nf) {
                const int n = wn * 64 + nf * 16 + lo;
                u[(size_t)(m0 + rl) * 256 + n] =
                    f2bf((acc[nf][rg] - mean) * rs * g[n] + bvec[n]);
            }
        }
    }
}

// ---------------------------------------------------------------------------
// MFMA flash attention (proven structure) + qlim q-tile trim + 32-granular
// kv-chunk trim + staging trimmed to the consumed rlive = nktp*32 rows
// (bit-identical: every LDS row the compute loop reads is staged).
__global__ __launch_bounds__(256) void attn_mfma_kernel(
    const unsigned short* __restrict__ Qb, const unsigned short* __restrict__ Kb,
    const unsigned short* __restrict__ Vb, const float* __restrict__ clb,
    const float* __restrict__ csfb, const float* __restrict__ padfb,
    const float* __restrict__ alpha_p, const float* __restrict__ beta_p,
    const int* __restrict__ lengths, int qlim, unsigned short* __restrict__ Ob)
{
    __shared__ __align__(16) unsigned short Kl[128 * 40];   // 10240 B
    __shared__ __align__(16) unsigned short Vt[32 * 132];   // 8448 B
    __shared__ __align__(16) float csfj[128];               // 512 B
    const int t = threadIdx.x;
    const int swz = ((blockIdx.x & 7) << 8) | (blockIdx.x >> 3);  // XCD chunking
    const int bh = swz >> 3, hf = swz & 7;
    const int b = bh >> 3, hd = bh & 7;
    const int len_b = lengths[b];
    if (hf * 64 > min(len_b, qlim)) return;      // dead q-tile
    const int njt = (len_b + 128) >> 7;          // ceil((len_b+1)/128)
    const size_t base = ((size_t)b * 512) * 256 + hd * 32;
    const int w = t >> 6, lane = t & 63, lo = lane & 15, hi = lane >> 4;
    const float L2E = 1.4426950408889634f;
    const float kb = L2E * (*beta_p);
    const float ka = L2E * (*alpha_p);
    const float* clg = clb + b * 512;

    const int i0 = (hf * 4 + w) * 16;
    const int iq = i0 + lo;
    const bf16x8 qf = *(const bf16x8*)(Qb + base + (size_t)iq * 256 + hi * 8);
    const float csb = fmaxf(kb * csfb[b * 512 + iq], 1e-3f);
    f32x4 acc0 = {0.f, 0.f, 0.f, 0.f}, acc1 = {0.f, 0.f, 0.f, 0.f};
    float lsum = 0.f;

    for (int jt = 0; jt < njt; ++jt) {
        // live 32-col chunks in this tile (cols past len_b are exact zeros)
        const int rem = len_b + 1 - jt * 128;
        const int nktp = (rem >= 128) ? 4 : ((rem + 31) >> 5);
        const int rlive = nktp * 32;              // rows consumed from LDS
        __syncthreads();
        for (int idx = t; idx < 512; idx += 256) {       // K tile: rlive rows
            int row = idx >> 2, c4 = idx & 3;
            if (row < rlive)
                *(uint4*)&Kl[row * 40 + c4 * 8] =
                    *(const uint4*)(Kb + base + (size_t)(jt * 128 + row) * 256 + c4 * 8);
        }
        for (int idx = t; idx < 512; idx += 256) {       // V^T via v_perm
            int pr = idx & 63, c4 = idx >> 6;
            if (2 * pr < rlive) {
                const unsigned* vp0 = (const unsigned*)
                    (Vb + base + (size_t)(jt * 128 + 2 * pr) * 256 + c4 * 4);
                const unsigned* vp1 = (const unsigned*)
                    (Vb + base + (size_t)(jt * 128 + 2 * pr + 1) * 256 + c4 * 4);
                unsigned v0lo = vp0[0], v0hi = vp0[1];
                unsigned v1lo = vp1[0], v1hi = vp1[1];
                *(unsigned*)&Vt[(c4 * 4 + 0) * 132 + 2 * pr] =
                    __builtin_amdgcn_perm(v1lo, v0lo, 0x05040100u);
                *(unsigned*)&Vt[(c4 * 4 + 1) * 132 + 2 * pr] =
                    __builtin_amdgcn_perm(v1lo, v0lo, 0x07060302u);
                *(unsigned*)&Vt[(c4 * 4 + 2) * 132 + 2 * pr] =
                    __builtin_amdgcn_perm(v1hi, v0hi, 0x05040100u);
                *(unsigned*)&Vt[(c4 * 4 + 3) * 132 + 2 * pr] =
                    __builtin_amdgcn_perm(v1hi, v0hi, 0x07060302u);
            }
        }
        if (t < 128) {                                   // csf with pad folded
            int j = jt * 128 + t;
            float cv = csfb[b * 512 + j];
            csfj[t] = (padfb[b * 512 + j] > 0.5f) ? -100000.f : cv;
        }
        __syncthreads();
#pragma unroll 4
        for (int ktp = 0; ktp < nktp; ++ktp) {
            const int k16 = ktp * 32;             // local j base
            const int gj = jt * 128 + k16;        // global j base
            bf16x8 kf0 = *(const bf16x8*)&Kl[(k16 + lo) * 40 + hi * 8];
            bf16x8 kf1 = *(const bf16x8*)&Kl[(k16 + 16 + lo) * 40 + hi * 8];
            union U16 { unsigned long long q[2]; unsigned wd[4]; bf16x8 v; } vu0, vu1, pu;
            vu0.q[0] = *(const unsigned long long*)&Vt[lo * 132 + k16 + hi * 4];
            vu0.q[1] = *(const unsigned long long*)&Vt[lo * 132 + k16 + 16 + hi * 4];
            vu1.q[0] = *(const unsigned long long*)&Vt[(16 + lo) * 132 + k16 + hi * 4];
            vu1.q[1] = *(const unsigned long long*)&Vt[(16 + lo) * 132 + k16 + 16 + hi * 4];
            f32x4 csf0 = *(const f32x4*)&csfj[k16 + hi * 4];
            f32x4 csf1 = *(const f32x4*)&csfj[k16 + 16 + hi * 4];
            f32x4 c0, c1;
#pragma unroll
            for (int e = 0; e < 4; ++e) {
                c0[e] = csb * csf0[e];
                c1[e] = csb * csf1[e];
            }
            f32x4 s0 = __builtin_amdgcn_mfma_f32_16x16x32_bf16(kf0, qf, c0, 0, 0, 0);
            f32x4 s1 = __builtin_amdgcn_mfma_f32_16x16x32_bf16(kf1, qf, c1, 0, 0, 0);
            float p[8];
#pragma unroll
            for (int r = 0; r < 4; ++r) p[r] = exp2f(s0[r]);
#pragma unroll
            for (int r = 0; r < 4; ++r) p[4 + r] = exp2f(s1[r]);
            if (gj <= i0 + 16 && gj + 32 >= i0) {
#pragma unroll
                for (int r = 0; r < 8; ++r) {
                    int jr = gj + ((r & 4) ? 16 : 0) + hi * 4 + (r & 3);
                    int dij = jr - iq;
                    if (dij == 1 || dij == -1) {
                        float ce = (jr >= 1 && iq <= 510) ? clg[jr] : clg[iq];
                        p[r] *= exp2f(ka * ce);
                    }
                }
            }
            lsum += ((p[0] + p[1]) + (p[2] + p[3])) + ((p[4] + p[5]) + (p[6] + p[7]));
            pu.wd[0] = cvt_pk_bf16(p[0], p[1]);
            pu.wd[1] = cvt_pk_bf16(p[2], p[3]);
            pu.wd[2] = cvt_pk_bf16(p[4], p[5]);
            pu.wd[3] = cvt_pk_bf16(p[6], p[7]);
            acc0 = __builtin_amdgcn_mfma_f32_16x16x32_bf16(vu0.v, pu.v, acc0, 0, 0, 0);
            acc1 = __builtin_amdgcn_mfma_f32_16x16x32_bf16(vu1.v, pu.v, acc1, 0, 0, 0);
        }
    }
    {
        float ls = lsum;
        ls += __shfl_xor(ls, 16);
        ls += __shfl_xor(ls, 32);
        const float inv = 1.f / fmaxf(ls, 1e-35f);
        unsigned long long oa =
              (unsigned long long)cvt_pk_bf16(acc0[0] * inv, acc0[1] * inv)
            | ((unsigned long long)cvt_pk_bf16(acc0[2] * inv, acc0[3] * inv) << 32);
        unsigned long long ob2 =
              (unsigned long long)cvt_pk_bf16(acc1[0] * inv, acc1[1] * inv)
            | ((unsigned long long)cvt_pk_bf16(acc1[2] * inv, acc1[3] * inv) << 32);
        *(unsigned long long*)(Ob + base + (size_t)iq * 256 + hi * 4) = oa;
        *(unsigned long long*)(Ob + base + (size_t)iq * 256 + 16 + hi * 4) = ob2;
    }
}

// ---------------------------------------------------------------------------
extern "C" void kernel_launch(void* const* d_in, const int* in_sizes, int n_in,
                              void* d_out, int out_size, void* d_ws, size_t ws_size,
                              hipStream_t stream) {
    const float* x         = (const float*)d_in[0];
    const float* c_local   = (const float*)d_in[1];
    const float* c_sink    = (const float*)d_in[2];
    const float* W_in      = (const float*)d_in[3];
    const float* b_in      = (const float*)d_in[4];
    const float* cls_token = (const float*)d_in[5];
    const float* pe_proj_W = (const float*)d_in[6];
    const float* pe_proj_b = (const float*)d_in[7];
    const float* pe_ln_g   = (const float*)d_in[8];
    const float* pe_ln_b   = (const float*)d_in[9];
    const float* pe_gain   = (const float*)d_in[10];
    const float* attn_Wqkv = (const float*)d_in[11];
    const float* attn_bqkv = (const float*)d_in[12];
    const float* attn_Wo   = (const float*)d_in[13];
    const float* attn_bo   = (const float*)d_in[14];
    const float* ff_W1     = (const float*)d_in[15];
    const float* ff_b1     = (const float*)d_in[16];
    const float* ff_W2     = (const float*)d_in[17];
    const float* ff_b2     = (const float*)d_in[18];
    const float* ln1_g     = (const float*)d_in[19];
    const float* ln1_b     = (const float*)d_in[20];
    const float* ln2_g     = (const float*)d_in[21];
    const float* ln2_b     = (const float*)d_in[22];
    const float* alpha     = (const float*)d_in[23];
    const float* beta      = (const float*)d_in[24];
    const float* corr_fl   = (const float*)d_in[25];
    const float* out_ln_g  = (const float*)d_in[26];
    const float* out_ln_b  = (const float*)d_in[27];
    const int*   lengths   = (const int*)d_in[28];
    float* out = (float*)d_out;

    // float region (same slots as round-20 passing layout)
    float* h     = (float*)d_ws;              // 4,194,304
    float* clb   = h + 4194304;               // 16384
    float* csfb  = clb + 16384;
    float* padfb = csfb + 16384;
    float* W20t  = padfb + 16384;             // 5120 (in old peWt slot)
    float* PEpos = W20t + 70656;              // 131072
    float* bbf   = PEpos + 131072;            // old 8,388,608-float region
    // bf16 region — weights AFTER the full 16,777,216-short f-span at Q_bf
    unsigned short* u_bf = (unsigned short*)(bbf + 8388608);
    unsigned short* xb_bf = u_bf;             // alias: xb dead before layer loop
    unsigned short* Q_bf = u_bf + 4194304;
    unsigned short* K_bf = Q_bf + 4194304;
    unsigned short* V_bf = K_bf + 4194304;
    unsigned short* f_bf = Q_bf;              // alias: spans Q..Q+16777216
    unsigned short* o_bf = u_bf;              // alias (lifetimes disjoint)
    unsigned short* wq_bf = Q_bf + 16777216;  // after f's span
    unsigned short* wo_bf = wq_bf + 589824;
    unsigned short* w1_bf = wo_bf + 196608;
    unsigned short* w2_bf = w1_bf + 786432;
    unsigned short* win_bf = w2_bf + 786432;  // 16384
    unsigned short* S_bf   = win_bf + 16384;  // 131072 (sinusoid table)
    unsigned short* w256_bf = S_bf + 131072;  // 65536

    setup_kernel<<<4708, 256, 0, stream>>>(
        attn_Wqkv, wq_bf, attn_Wo, wo_bf, ff_W1, w1_bf, ff_W2, w2_bf,
        W_in, win_bf, pe_proj_W, w256_bf, W20t, x, xb_bf, S_bf);
    gemm_bf16_kernel<<<dim3(4, 4), 256, 0, stream>>>(
        S_bf, w256_bf, pe_proj_b, PEpos, nullptr, 512, 256, 256);
    gemm_bf16_kernel<<<dim3(4, 128), 256, 0, stream>>>(
        xb_bf, win_bf, b_in, bbf, lengths, 16384, 256, 64);
    prep_lite_kernel<<<2048, 256, 0, stream>>>(
        c_local, c_sink, bbf, cls_token, PEpos, W20t,
        pe_ln_g, pe_ln_b, pe_gain, corr_fl, lengths, ln1_g, ln1_b,
        h, clb, csfb, padfb, u_bf);

    for (int l = 0; l < 3; ++l) {
        const bool last = (l == 2);
        gemm64_kernel<0><<<dim3(6, 256), 256, 0, stream>>>(
            u_bf, wq_bf + (size_t)l * 196608, attn_bqkv + 768 * l, lengths,
            511, last ? 63 : 511, Q_bf, K_bf, V_bf, 16384, 768, 256);
        attn_mfma_kernel<<<2048, 256, 0, stream>>>(
            Q_bf, K_bf, V_bf, clb, csfb, padfb, alpha, beta, lengths,
            last ? 63 : 511, o_bf);
        gemm_res_ln_kernel<0><<<512, 512, 0, stream>>>(
            o_bf, wo_bf + (size_t)l * 65536, attn_bo + 256 * l, h,
            ln2_g + 256 * l, ln2_b + 256 * l, lengths, last ? 63 : 511,
            u_bf, nullptr, 256);
        gemm64_kernel<2><<<dim3(8, 256), 256, 0, stream>>>(
            u_bf, w1_bf + (size_t)l * 262144, ff_b1 + 1024 * l, lengths,
            last ? 63 : 511, 511, f_bf, nullptr, nullptr, 16384, 1024, 256);
        if (l < 2) {
            gemm_res_ln_kernel<0><<<512, 512, 0, stream>>>(
                f_bf, w2_bf + (size_t)l * 262144, ff_b2 + 256 * l, h,
                ln1_g + 256 * (l + 1), ln1_b + 256 * (l + 1), lengths, 511,
                u_bf, nullptr, 1024);
        } else {
            gemm_res_ln_kernel<1><<<512, 512, 0, stream>>>(
                f_bf, w2_bf + (size_t)l * 262144, ff_b2 + 256 * l, h,
                out_ln_g, out_ln_b, lengths, 0, nullptr, out, 1024);
        }
    }
}